// Round 4
// baseline (3516.379 us; speedup 1.0000x reference)
//
#include <hip/hip_runtime.h>
#include <hip/hip_bf16.h>
#include <math.h>

#define N_USERS 2500
#define N_ITEMS 3000
#define N_ENT   2500
#define NTOT    8000
#define D       128
#define NEDGE   256000

typedef unsigned short u16;
typedef __attribute__((ext_vector_type(8))) short short8;
typedef __attribute__((ext_vector_type(4))) float f32x4;

// ---------------------------------------------------------------------------
// Generic 4-rows-per-block linear: out[r][j] = act(sum_k A[r][k]*ks[k]*W[k][j] + b[j])
// block = 128 threads (j = column), grid.x = M/4.
// mode: 0 = none, 1 = relu, 2 = multiply-by-2 (collapsed cross-modal sum)
// ob (optional): bf16 mirror of the f32 output (for MFMA screening).
// ---------------------------------------------------------------------------
__global__ void k_lin4(const float* __restrict__ A, const float* __restrict__ W,
                       const float* __restrict__ b, const float* __restrict__ ks,
                       float* __restrict__ out, u16* __restrict__ ob, int K, int mode) {
  const int r0 = blockIdx.x * 4;
  const int j  = threadIdx.x;
  const float* __restrict__ a0 = A + (size_t)r0 * K;
  const float* __restrict__ a1 = a0 + K;
  const float* __restrict__ a2 = a1 + K;
  const float* __restrict__ a3 = a2 + K;
  float c0 = 0.f, c1 = 0.f, c2 = 0.f, c3 = 0.f;
  if (ks) {
    for (int k = 0; k < K; ++k) {
      const float w = W[(size_t)k * D + j];
      const float s = ks[k];
      c0 = fmaf(a0[k] * s, w, c0);
      c1 = fmaf(a1[k] * s, w, c1);
      c2 = fmaf(a2[k] * s, w, c2);
      c3 = fmaf(a3[k] * s, w, c3);
    }
  } else {
    for (int k = 0; k < K; ++k) {
      const float w = W[(size_t)k * D + j];
      c0 = fmaf(a0[k], w, c0);
      c1 = fmaf(a1[k], w, c1);
      c2 = fmaf(a2[k], w, c2);
      c3 = fmaf(a3[k], w, c3);
    }
  }
  const float bj = b[j];
  c0 += bj; c1 += bj; c2 += bj; c3 += bj;
  if (mode == 1) {
    c0 = fmaxf(c0, 0.f); c1 = fmaxf(c1, 0.f); c2 = fmaxf(c2, 0.f); c3 = fmaxf(c3, 0.f);
  } else if (mode == 2) {
    c0 *= 2.f; c1 *= 2.f; c2 *= 2.f; c3 *= 2.f;
  }
  float* __restrict__ o = out + (size_t)r0 * D + j;
  o[0] = c0; o[D] = c1; o[2 * D] = c2; o[3 * D] = c3;
  if (ob) {
    __hip_bfloat16 h0 = __float2bfloat16(c0), h1 = __float2bfloat16(c1);
    __hip_bfloat16 h2 = __float2bfloat16(c2), h3 = __float2bfloat16(c3);
    u16* __restrict__ p = ob + (size_t)r0 * D + j;
    p[0]     = *reinterpret_cast<u16*>(&h0);
    p[D]     = *reinterpret_cast<u16*>(&h1);
    p[2 * D] = *reinterpret_cast<u16*>(&h2);
    p[3 * D] = *reinterpret_cast<u16*>(&h3);
  }
}

// ---------------------------------------------------------------------------
// Gated fusion
// ---------------------------------------------------------------------------
__global__ void k_gatefuse(const float* __restrict__ base, const float* __restrict__ mm,
                           const float* __restrict__ gw, const float* __restrict__ gb,
                           float* __restrict__ embout) {
  const int r = blockIdx.x;
  const int j = threadIdx.x;
  const float* __restrict__ b0 = base + (size_t)r * D;
  const float* __restrict__ m0 = mm + (size_t)r * D;
  float acc = 0.f;
  for (int k = 0; k < D; ++k) acc = fmaf(b0[k], gw[(size_t)k * D + j], acc);
  for (int k = 0; k < D; ++k) acc = fmaf(m0[k], gw[(size_t)(D + k) * D + j], acc);
  acc += gb[j];
  const float s1 = 1.f / (1.f + expf(-acc));
  const float g  = 1.f / (1.f + expf(-(s1 * 2.f)));
  const float bv = b0[j], mv = m0[j];
  embout[(size_t)r * D + j] = g * bv + (1.f - g) * mv + 0.1f * bv;
}

__global__ void k_relmean(const float* __restrict__ rel, float* __restrict__ out) {
  const int j = threadIdx.x;
  float s = 0.f;
  for (int i = 0; i < 32; ++i) s += rel[i * D + j];
  out[j] = s * (1.f / 32.f);
}

__global__ void k_copy(const float* __restrict__ src, float* __restrict__ dst, int n) {
  const int t = blockIdx.x * blockDim.x + threadIdx.x;
  if (t < n) dst[t] = src[t];
}

// ---------------------------------------------------------------------------
// side[row] += data * e[col]  via f32 atomics. one thread per (edge, d)
// ---------------------------------------------------------------------------
__global__ void k_spmm(const float* __restrict__ dat, const int* __restrict__ rw,
                       const int* __restrict__ cl, const float* __restrict__ e,
                       float* __restrict__ side) {
  const long long t = (long long)blockIdx.x * blockDim.x + threadIdx.x;
  if (t >= (long long)NEDGE * D) return;
  const int ei = (int)(t >> 7);
  const int d  = (int)(t & 127);
  const float v = dat[ei] * e[(size_t)cl[ei] * D + d];
  atomicAdd(side + (size_t)rw[ei] * D + d, v);
}

// ---------------------------------------------------------------------------
// bf16-MFMA score scan with per-row top-32 overselect.
// One wave per 16 rows (grid 500 x 64 threads). C layout (verified m89/m91):
// col = lane&15, row = (lane>>4)*4 + reg. Top-32 = 2 slots/lane within each
// 16-lane row-group. Candidate indices -> first 128B of each enext row.
// ---------------------------------------------------------------------------
__device__ __forceinline__ void insert2(float s, int cbase, int lane, int g16,
                                        float& sA, int& iA, float& sB, int& iB,
                                        float& thr) {
  unsigned long long ball = __ballot(s > thr);
  unsigned m16 = (unsigned)((ball >> g16) & 0xffffULL);
  if (!__any(m16 != 0)) return;
  while (__any(m16 != 0)) {
    const bool active = (m16 != 0);
    // BUGFIX r2->r3: __ffs(m16|1u)-1 was always 0.
    const int src = active ? (__ffs(m16) - 1) : 0;
    m16 &= (m16 - 1u);
    const float sv = __shfl(s, g16 + src);
    const int   scl = cbase + src;
    // group argmin over the 2x16 slots (value asc, tie -> larger idx evicted).
    // BUGFIX r3->r4: the butterfly comparator needs a lane tie-break to give a
    // UNIQUE winner. With all-equal initial slots every lane kept ml=self, so
    // `lane==ml` held on all 16 lanes -> mass duplicate insertion (self-
    // sustaining: duplicated keys keep the comparator tie-ing forever).
    const bool aless = (sA < sB) || (sA == sB && iA > iB);
    float lv = aless ? sA : sB;
    int   li = aless ? iA : iB;
    int   ml = lane;
#pragma unroll
    for (int d2 = 1; d2 < 16; d2 <<= 1) {
      const float ov = __shfl_xor(lv, d2);
      const int   oi = __shfl_xor(li, d2);
      const int   ol = __shfl_xor(ml, d2);
      if (ov < lv || (ov == lv && (oi > li || (oi == li && ol < ml)))) {
        lv = ov; li = oi; ml = ol;
      }
    }
    if (active && sv > lv && lane == ml) {
      if (aless) { sA = sv; iA = scl; } else { sB = sv; iB = scl; }
    }
  }
  float t = fminf(sA, sB);
#pragma unroll
  for (int d2 = 1; d2 < 16; d2 <<= 1) t = fminf(t, __shfl_xor(t, d2));
  thr = t;
}

__global__ __launch_bounds__(64) void k_topk32(const u16* __restrict__ qb,
                                               const u16* __restrict__ kb,
                                               float* __restrict__ enext) {
  const int lane = threadIdx.x;
  const int rbase = blockIdx.x * 16;
  const int g16 = lane & 48;           // row-group base lane
  const int colL = lane & 15;
  const int kofs = (lane >> 4) * 8;

  short8 aF[4];
  {
    const u16* ap = qb + (size_t)(rbase + colL) * D + kofs;
#pragma unroll
    for (int t = 0; t < 4; ++t) aF[t] = *reinterpret_cast<const short8*>(ap + t * 32);
  }

  float sA[4], sB[4]; int iA[4], iB[4]; float thr[4];
#pragma unroll
  for (int r = 0; r < 4; ++r) {
    sA[r] = sB[r] = -3.0e38f;
    iA[r] = 0x40000000 + colL;          // distinct placeholder indices
    iB[r] = 0x40000000 + 16 + colL;
    thr[r] = -3.0e38f;
  }

  const u16* bb = kb + (size_t)colL * D + kofs;
  for (int c = 0; c < NTOT / 16; c += 2) {
    const u16* b0 = bb + (size_t)c * 16 * D;
    const u16* b1 = b0 + 16 * D;
    short8 bF0[4], bF1[4];
#pragma unroll
    for (int t = 0; t < 4; ++t) {
      bF0[t] = *reinterpret_cast<const short8*>(b0 + t * 32);
      bF1[t] = *reinterpret_cast<const short8*>(b1 + t * 32);
    }
    f32x4 acc0 = {0.f, 0.f, 0.f, 0.f}, acc1 = {0.f, 0.f, 0.f, 0.f};
#pragma unroll
    for (int t = 0; t < 4; ++t) {
      acc0 = __builtin_amdgcn_mfma_f32_16x16x32_bf16(aF[t], bF0[t], acc0, 0, 0, 0);
      acc1 = __builtin_amdgcn_mfma_f32_16x16x32_bf16(aF[t], bF1[t], acc1, 0, 0, 0);
    }
#pragma unroll
    for (int r = 0; r < 4; ++r)
      insert2(acc0[r], c * 16, lane, g16, sA[r], iA[r], sB[r], iB[r], thr[r]);
#pragma unroll
    for (int r = 0; r < 4; ++r)
      insert2(acc1[r], (c + 1) * 16, lane, g16, sA[r], iA[r], sB[r], iB[r], thr[r]);
  }
  // stash candidate indices in the first 128B of each output row
#pragma unroll
  for (int r = 0; r < 4; ++r) {
    const int row = rbase + (lane >> 4) * 4 + r;
    int* cr = (int*)(enext + (size_t)row * D);
    cr[colL]      = iA[r];
    cr[16 + colL] = iB[r];
  }
}

// ---------------------------------------------------------------------------
// Exact f32 rescore of the 32 candidates, true top-16, softmax, gather vn.
// One wave per row; reads cand from enext row head, overwrites the row.
// ---------------------------------------------------------------------------
__global__ __launch_bounds__(64) void k_rescore(const float* __restrict__ qn,
                                                const float* __restrict__ kn,
                                                const float* __restrict__ vn,
                                                float* __restrict__ enext) {
  const int row = blockIdx.x;
  const int lane = threadIdx.x;
  const int* cr = (const int*)(enext + (size_t)row * D);
  const int c = cr[lane & 31];

  const float4* __restrict__ q4 = (const float4*)(qn + (size_t)row * D);
  const float4* __restrict__ k4 = (const float4*)(kn + (size_t)c * D);
  float sc = 0.f;
#pragma unroll 8
  for (int j = 0; j < 32; ++j) {
    const float4 qv = q4[j];
    const float4 kv = k4[j];
    sc = fmaf(qv.x, kv.x, sc);
    sc = fmaf(qv.y, kv.y, sc);
    sc = fmaf(qv.z, kv.z, sc);
    sc = fmaf(qv.w, kv.w, sc);
  }
  sc *= 0.088388347648318447f;   // 1/sqrt(128)

  // rank among the 32 candidates (value desc, tie -> lower slot first)
  int rank = 0;
#pragma unroll
  for (int j = 0; j < 32; ++j) {
    const float sv = __shfl(sc, j);
    rank += (sv > sc || (sv == sc && j < lane)) ? 1 : 0;
  }
  const bool sel = (lane < 32) && (rank < 16);

  float v = sel ? sc : -3.0e38f;
  float mx = v;
#pragma unroll
  for (int d2 = 1; d2 < 32; d2 <<= 1) mx = fmaxf(mx, __shfl_xor(mx, d2));
  const float e = sel ? expf(sc - mx) : 0.f;
  float Z = e;
#pragma unroll
  for (int d2 = 1; d2 < 32; d2 <<= 1) Z += __shfl_xor(Z, d2);
  const float w = e / Z;

  float a0 = 0.f, a1 = 0.f;
#pragma unroll 1
  for (int j = 0; j < 32; ++j) {
    const float wj = __shfl(w, j);
    const int   cj = __shfl(c, j);
    if (wj > 0.f) {
      const float* __restrict__ vr = vn + (size_t)cj * D;
      a0 = fmaf(wj, vr[lane], a0);
      a1 = fmaf(wj, vr[64 + lane], a1);
    }
  }
  enext[(size_t)row * D + lane]      = fmaxf(a0, 0.f);
  enext[(size_t)row * D + 64 + lane] = fmaxf(a1, 0.f);
}

// ---------------------------------------------------------------------------
// final = [e0|e1|e2] @ la_w + la_b, row-L2-normalized
// ---------------------------------------------------------------------------
__global__ void k_final_norm(const float* __restrict__ e0, const float* __restrict__ e1,
                             const float* __restrict__ e2, const float* __restrict__ law,
                             const float* __restrict__ lab, float* __restrict__ out) {
  __shared__ float red[128];
  const int r = blockIdx.x;
  const int j = threadIdx.x;
  const float* __restrict__ a0 = e0 + (size_t)r * D;
  const float* __restrict__ a1 = e1 + (size_t)r * D;
  const float* __restrict__ a2 = e2 + (size_t)r * D;
  float acc = lab[j];
  for (int k = 0; k < D; ++k) acc = fmaf(a0[k], law[(size_t)k * D + j], acc);
  for (int k = 0; k < D; ++k) acc = fmaf(a1[k], law[(size_t)(D + k) * D + j], acc);
  for (int k = 0; k < D; ++k) acc = fmaf(a2[k], law[(size_t)(2 * D + k) * D + j], acc);
  red[j] = acc * acc;
  __syncthreads();
  for (int st = 64; st > 0; st >>= 1) {
    if (j < st) red[j] += red[j + st];
    __syncthreads();
  }
  const float nrm = fmaxf(sqrtf(red[0]), 1e-12f);
  const float o = acc / nrm;
  if (r < N_USERS) out[(size_t)r * D + j] = o;
  else             out[(size_t)N_USERS * D + (size_t)(r - N_USERS) * D + j] = o;
}

// ---------------------------------------------------------------------------
extern "C" void kernel_launch(void* const* d_in, const int* in_sizes, int n_in,
                              void* d_out, int out_size, void* d_ws, size_t ws_size,
                              hipStream_t stream) {
  const float* user_w = (const float*)d_in[0];
  const float* item_w = (const float*)d_in[1];
  const float* ent_w  = (const float*)d_in[2];
  const float* rel_w  = (const float*)d_in[3];
  const float* mfeat  = (const float*)d_in[4];
  const float* ufeat  = (const float*)d_in[5];
  const float* me_w1  = (const float*)d_in[6];
  const float* me_b1  = (const float*)d_in[7];
  const float* me_w2  = (const float*)d_in[8];
  const float* me_b2  = (const float*)d_in[9];
  const float* ue_w1  = (const float*)d_in[10];
  const float* ue_b1  = (const float*)d_in[11];
  const float* ue_w2  = (const float*)d_in[12];
  const float* ue_b2  = (const float*)d_in[13];
  const float* cm_vw  = (const float*)d_in[18];
  const float* cm_vb  = (const float*)d_in[19];
  const float* cm_ow  = (const float*)d_in[20];
  const float* cm_ob  = (const float*)d_in[21];
  const float* mg_w   = (const float*)d_in[22];
  const float* mg_b   = (const float*)d_in[23];
  const float* ug_w   = (const float*)d_in[24];
  const float* ug_b   = (const float*)d_in[25];
  const float* gnn_qw = (const float*)d_in[26];
  const float* gnn_qb = (const float*)d_in[27];
  const float* gnn_kw = (const float*)d_in[28];
  const float* gnn_kb = (const float*)d_in[29];
  const float* gnn_vw = (const float*)d_in[30];
  const float* gnn_vb = (const float*)d_in[31];
  const float* la_w   = (const float*)d_in[32];
  const float* la_b   = (const float*)d_in[33];
  const float* adj_d  = (const float*)d_in[34];
  const int*   adj_r  = (const int*)d_in[35];
  const int*   adj_c  = (const int*)d_in[36];
  float* out = (float*)d_out;
  float* ws  = (float*)d_ws;

  // ---- workspace layout (floats) ----
  size_t off = 0;
  float* mm_item = ws + off; off += (size_t)N_ITEMS * D;
  float* mm_user = ws + off; off += (size_t)N_USERS * D;
  float* enc     = ws + off; off += (size_t)N_ITEMS * D;
  float* tmp     = ws + off; off += (size_t)N_ITEMS * D;
  float* emb0    = ws + off; off += (size_t)NTOT * D;
  float* emb1    = ws + off; off += (size_t)NTOT * D;
  float* emb2    = ws + off; off += (size_t)NTOT * D;
  float* side    = ws + off; off += (size_t)NTOT * D;
  float* qn      = ws + off; off += (size_t)NTOT * D;
  float* kn      = ws + off; off += (size_t)NTOT * D;
  float* vn      = ws + off; off += (size_t)NTOT * D;
  float* relmean = ws + off; off += D;
  // bf16 mirrors overlay mm_user/enc/tmp (dead after the fusion stage)
  u16* qb = (u16*)mm_user;
  u16* kb = qb + (size_t)NTOT * D;

  // ---- modality encoders ----
  k_lin4<<<N_ITEMS / 4, D, 0, stream>>>(mfeat, me_w1, me_b1, nullptr, tmp, nullptr, 768, 1);
  k_lin4<<<N_ITEMS / 4, D, 0, stream>>>(tmp, me_w2, me_b2, nullptr, enc, nullptr, 128, 1);
  k_lin4<<<N_USERS / 4, D, 0, stream>>>(ufeat, ue_w1, ue_b1, nullptr, tmp, nullptr, 512, 1);
  k_lin4<<<N_USERS / 4, D, 0, stream>>>(tmp, ue_w2, ue_b2, nullptr, mm_user, nullptr, 128, 1);
  // ---- collapsed cross-modal attention: mm_item = 2*((enc@vw+vb)@ow+ob) ----
  k_lin4<<<N_ITEMS / 4, D, 0, stream>>>(enc, cm_vw, cm_vb, nullptr, tmp, nullptr, 128, 0);
  k_lin4<<<N_ITEMS / 4, D, 0, stream>>>(tmp, cm_ow, cm_ob, nullptr, mm_item, nullptr, 128, 2);
  // ---- gated fusion -> emb0 ----
  k_gatefuse<<<N_ITEMS, D, 0, stream>>>(item_w, mm_item, mg_w, mg_b, emb0 + (size_t)N_USERS * D);
  k_gatefuse<<<N_USERS, D, 0, stream>>>(user_w, mm_user, ug_w, ug_b, emb0);
  k_copy<<<(N_ENT * D + 255) / 256, 256, 0, stream>>>(ent_w, emb0 + (size_t)(N_USERS + N_ITEMS) * D, N_ENT * D);
  k_relmean<<<1, D, 0, stream>>>(rel_w, relmean);

  // ---- GNN layers ----
  const long long spthreads = (long long)NEDGE * D;
  const int spgrid = (int)((spthreads + 255) / 256);
  const float* eml[3] = {emb0, emb1, emb2};
  for (int l = 0; l < 2; ++l) {
    const float* e = eml[l];
    float* enext   = (float*)eml[l + 1];
    hipMemsetAsync(side, 0, (size_t)NTOT * D * sizeof(float), stream);
    k_spmm<<<spgrid, 256, 0, stream>>>(adj_d, adj_r, adj_c, e, side);
    k_lin4<<<NTOT / 4, D, 0, stream>>>(e,    gnn_qw + (size_t)l * D * D, gnn_qb + (size_t)l * D, nullptr, qn, qb, 128, 0);
    k_lin4<<<NTOT / 4, D, 0, stream>>>(side, gnn_kw + (size_t)l * D * D, gnn_kb + (size_t)l * D, relmean, kn, kb, 128, 0);
    k_lin4<<<NTOT / 4, D, 0, stream>>>(side, gnn_vw + (size_t)l * D * D, gnn_vb + (size_t)l * D, nullptr, vn, nullptr, 128, 0);
    k_topk32<<<NTOT / 16, 64, 0, stream>>>(qb, kb, enext);
    k_rescore<<<NTOT, 64, 0, stream>>>(qn, kn, vn, enext);
  }

  // ---- layer aggregation + normalize -> d_out ----
  k_final_norm<<<N_USERS + N_ITEMS, D, 0, stream>>>(emb0, emb1, emb2, la_w, la_b, out);
  // ---- passthrough outputs ----
  k_copy<<<(N_ITEMS * D + 255) / 256, 256, 0, stream>>>(item_w, out + (size_t)(N_USERS + N_ITEMS) * D, N_ITEMS * D);
  k_copy<<<(N_ITEMS * D + 255) / 256, 256, 0, stream>>>(mm_item, out + (size_t)(N_USERS + 2 * N_ITEMS) * D, N_ITEMS * D);
}

// Round 5
// 2732.535 us; speedup vs baseline: 1.2869x; 1.2869x over previous
//
#include <hip/hip_runtime.h>
#include <hip/hip_bf16.h>
#include <math.h>

#define N_USERS 2500
#define N_ITEMS 3000
#define N_ENT   2500
#define NTOT    8000
#define D       128
#define NEDGE   256000
#define NSLICE  4
#define SLICE_TILES 125          // (NTOT/NSLICE)/16

typedef unsigned short u16;
typedef __attribute__((ext_vector_type(8))) short short8;
typedef __attribute__((ext_vector_type(4))) float f32x4;

// ---------------------------------------------------------------------------
// Generic 4-rows-per-block linear (unchanged)
// ---------------------------------------------------------------------------
__global__ void k_lin4(const float* __restrict__ A, const float* __restrict__ W,
                       const float* __restrict__ b, const float* __restrict__ ks,
                       float* __restrict__ out, u16* __restrict__ ob, int K, int mode) {
  const int r0 = blockIdx.x * 4;
  const int j  = threadIdx.x;
  const float* __restrict__ a0 = A + (size_t)r0 * K;
  const float* __restrict__ a1 = a0 + K;
  const float* __restrict__ a2 = a1 + K;
  const float* __restrict__ a3 = a2 + K;
  float c0 = 0.f, c1 = 0.f, c2 = 0.f, c3 = 0.f;
  if (ks) {
    for (int k = 0; k < K; ++k) {
      const float w = W[(size_t)k * D + j];
      const float s = ks[k];
      c0 = fmaf(a0[k] * s, w, c0);
      c1 = fmaf(a1[k] * s, w, c1);
      c2 = fmaf(a2[k] * s, w, c2);
      c3 = fmaf(a3[k] * s, w, c3);
    }
  } else {
    for (int k = 0; k < K; ++k) {
      const float w = W[(size_t)k * D + j];
      c0 = fmaf(a0[k], w, c0);
      c1 = fmaf(a1[k], w, c1);
      c2 = fmaf(a2[k], w, c2);
      c3 = fmaf(a3[k], w, c3);
    }
  }
  const float bj = b[j];
  c0 += bj; c1 += bj; c2 += bj; c3 += bj;
  if (mode == 1) {
    c0 = fmaxf(c0, 0.f); c1 = fmaxf(c1, 0.f); c2 = fmaxf(c2, 0.f); c3 = fmaxf(c3, 0.f);
  } else if (mode == 2) {
    c0 *= 2.f; c1 *= 2.f; c2 *= 2.f; c3 *= 2.f;
  }
  float* __restrict__ o = out + (size_t)r0 * D + j;
  o[0] = c0; o[D] = c1; o[2 * D] = c2; o[3 * D] = c3;
  if (ob) {
    __hip_bfloat16 h0 = __float2bfloat16(c0), h1 = __float2bfloat16(c1);
    __hip_bfloat16 h2 = __float2bfloat16(c2), h3 = __float2bfloat16(c3);
    u16* __restrict__ p = ob + (size_t)r0 * D + j;
    p[0]     = *reinterpret_cast<u16*>(&h0);
    p[D]     = *reinterpret_cast<u16*>(&h1);
    p[2 * D] = *reinterpret_cast<u16*>(&h2);
    p[3 * D] = *reinterpret_cast<u16*>(&h3);
  }
}

// ---------------------------------------------------------------------------
// Gated fusion (unchanged)
// ---------------------------------------------------------------------------
__global__ void k_gatefuse(const float* __restrict__ base, const float* __restrict__ mm,
                           const float* __restrict__ gw, const float* __restrict__ gb,
                           float* __restrict__ embout) {
  const int r = blockIdx.x;
  const int j = threadIdx.x;
  const float* __restrict__ b0 = base + (size_t)r * D;
  const float* __restrict__ m0 = mm + (size_t)r * D;
  float acc = 0.f;
  for (int k = 0; k < D; ++k) acc = fmaf(b0[k], gw[(size_t)k * D + j], acc);
  for (int k = 0; k < D; ++k) acc = fmaf(m0[k], gw[(size_t)(D + k) * D + j], acc);
  acc += gb[j];
  const float s1 = 1.f / (1.f + expf(-acc));
  const float g  = 1.f / (1.f + expf(-(s1 * 2.f)));
  const float bv = b0[j], mv = m0[j];
  embout[(size_t)r * D + j] = g * bv + (1.f - g) * mv + 0.1f * bv;
}

__global__ void k_relmean(const float* __restrict__ rel, float* __restrict__ out) {
  const int j = threadIdx.x;
  float s = 0.f;
  for (int i = 0; i < 32; ++i) s += rel[i * D + j];
  out[j] = s * (1.f / 32.f);
}

__global__ void k_copy(const float* __restrict__ src, float* __restrict__ dst, int n) {
  const int t = blockIdx.x * blockDim.x + threadIdx.x;
  if (t < n) dst[t] = src[t];
}

// ---------------------------------------------------------------------------
// side[row] += data * e[col]  via f32 atomics (unchanged)
// ---------------------------------------------------------------------------
__global__ void k_spmm(const float* __restrict__ dat, const int* __restrict__ rw,
                       const int* __restrict__ cl, const float* __restrict__ e,
                       float* __restrict__ side) {
  const long long t = (long long)blockIdx.x * blockDim.x + threadIdx.x;
  if (t >= (long long)NEDGE * D) return;
  const int ei = (int)(t >> 7);
  const int d  = (int)(t & 127);
  const float v = dat[ei] * e[(size_t)cl[ei] * D + d];
  atomicAdd(side + (size_t)rw[ei] * D + d, v);
}

// ---------------------------------------------------------------------------
// bf16-MFMA score scan, column-sliced: grid (500 row-groups, NSLICE slices).
// Each wave keeps per-slice top-32 per row (ballot insert, verified r4).
// Candidates -> cand[row*128 + slice*32 + {0..31}] (the dead `side` buffer).
// ---------------------------------------------------------------------------
__device__ __forceinline__ void insert2(float s, int cbase, int lane, int g16,
                                        float& sA, int& iA, float& sB, int& iB,
                                        float& thr) {
  unsigned long long ball = __ballot(s > thr);
  unsigned m16 = (unsigned)((ball >> g16) & 0xffffULL);
  if (!__any(m16 != 0)) return;
  while (__any(m16 != 0)) {
    const bool active = (m16 != 0);
    const int src = active ? (__ffs(m16) - 1) : 0;
    m16 &= (m16 - 1u);
    const float sv = __shfl(s, g16 + src);
    const int   scl = cbase + src;
    const bool aless = (sA < sB) || (sA == sB && iA > iB);
    float lv = aless ? sA : sB;
    int   li = aless ? iA : iB;
    int   ml = lane;
#pragma unroll
    for (int d2 = 1; d2 < 16; d2 <<= 1) {
      const float ov = __shfl_xor(lv, d2);
      const int   oi = __shfl_xor(li, d2);
      const int   ol = __shfl_xor(ml, d2);
      if (ov < lv || (ov == lv && (oi > li || (oi == li && ol < ml)))) {
        lv = ov; li = oi; ml = ol;
      }
    }
    if (active && sv > lv && lane == ml) {
      if (aless) { sA = sv; iA = scl; } else { sB = sv; iB = scl; }
    }
  }
  float t = fminf(sA, sB);
#pragma unroll
  for (int d2 = 1; d2 < 16; d2 <<= 1) t = fminf(t, __shfl_xor(t, d2));
  thr = t;
}

__global__ __launch_bounds__(64) void k_topk32(const u16* __restrict__ qb,
                                               const u16* __restrict__ kb,
                                               int* __restrict__ cand) {
  const int lane = threadIdx.x;
  const int rbase = blockIdx.x * 16;
  const int sl   = blockIdx.y;
  const int g16 = lane & 48;
  const int colL = lane & 15;
  const int kofs = (lane >> 4) * 8;

  short8 aF[4];
  {
    const u16* ap = qb + (size_t)(rbase + colL) * D + kofs;
#pragma unroll
    for (int t = 0; t < 4; ++t) aF[t] = *reinterpret_cast<const short8*>(ap + t * 32);
  }

  float sA[4], sB[4]; int iA[4], iB[4]; float thr[4];
#pragma unroll
  for (int r = 0; r < 4; ++r) {
    sA[r] = sB[r] = -3.0e38f;
    iA[r] = 0x40000000 + colL;
    iB[r] = 0x40000000 + 16 + colL;
    thr[r] = -3.0e38f;
  }

  const int tile0 = sl * SLICE_TILES;
  const u16* bb = kb + (size_t)(tile0 * 16 + colL) * D + kofs;

  short8 bF[4];
#pragma unroll
  for (int t = 0; t < 4; ++t) bF[t] = *reinterpret_cast<const short8*>(bb + t * 32);

  for (int c = 0; c < SLICE_TILES; ++c) {
    // prefetch next tile (clamped) before the insert shuffle chains
    const int cn = (c + 1 < SLICE_TILES) ? c + 1 : c;
    const u16* nb = bb + (size_t)cn * 16 * D;
    short8 bN[4];
#pragma unroll
    for (int t = 0; t < 4; ++t) bN[t] = *reinterpret_cast<const short8*>(nb + t * 32);

    f32x4 acc = {0.f, 0.f, 0.f, 0.f};
#pragma unroll
    for (int t = 0; t < 4; ++t)
      acc = __builtin_amdgcn_mfma_f32_16x16x32_bf16(aF[t], bF[t], acc, 0, 0, 0);

    const int cbase = (tile0 + c) * 16;
#pragma unroll
    for (int r = 0; r < 4; ++r)
      insert2(acc[r], cbase, lane, g16, sA[r], iA[r], sB[r], iB[r], thr[r]);

#pragma unroll
    for (int t = 0; t < 4; ++t) bF[t] = bN[t];
  }

#pragma unroll
  for (int r = 0; r < 4; ++r) {
    const int row = rbase + (lane >> 4) * 4 + r;
    int* cr = cand + (size_t)row * 128 + sl * 32;
    cr[colL]      = iA[r];
    cr[16 + colL] = iB[r];
  }
}

// ---------------------------------------------------------------------------
// Exact f32 rescore of 128 candidates (2/lane), true top-16 by (value, lower
// index), softmax, gather vn. One wave per row.
// ---------------------------------------------------------------------------
__global__ __launch_bounds__(64) void k_rescore128(const float* __restrict__ qn,
                                                   const float* __restrict__ kn,
                                                   const float* __restrict__ vn,
                                                   const int* __restrict__ cand,
                                                   float* __restrict__ enext) {
  const int row = blockIdx.x;
  const int lane = threadIdx.x;
  const int* cr = cand + (size_t)row * 128;
  const int c0 = cr[lane];
  const int c1 = cr[64 + lane];

  const float4* __restrict__ q4  = (const float4*)(qn + (size_t)row * D);
  const float4* __restrict__ k40 = (const float4*)(kn + (size_t)c0 * D);
  const float4* __restrict__ k41 = (const float4*)(kn + (size_t)c1 * D);
  float s0 = 0.f, s1 = 0.f;
#pragma unroll 8
  for (int j = 0; j < 32; ++j) {
    const float4 qv = q4[j];
    const float4 a = k40[j], b = k41[j];
    s0 = fmaf(qv.x, a.x, s0); s0 = fmaf(qv.y, a.y, s0);
    s0 = fmaf(qv.z, a.z, s0); s0 = fmaf(qv.w, a.w, s0);
    s1 = fmaf(qv.x, b.x, s1); s1 = fmaf(qv.y, b.y, s1);
    s1 = fmaf(qv.z, b.z, s1); s1 = fmaf(qv.w, b.w, s1);
  }
  const float inv = 0.088388347648318447f;   // 1/sqrt(128)
  s0 *= inv; s1 *= inv;

  // rank among 128 by (value desc, index asc); indices are unique
  int r0 = 0, r1 = 0;
  for (int j = 0; j < 64; ++j) {
    const float t0 = __shfl(s0, j), t1 = __shfl(s1, j);
    const int   u0 = __shfl(c0, j), u1 = __shfl(c1, j);
    r0 += (t0 > s0 || (t0 == s0 && u0 < c0)) ? 1 : 0;
    r0 += (t1 > s0 || (t1 == s0 && u1 < c0)) ? 1 : 0;
    r1 += (t0 > s1 || (t0 == s1 && u0 < c1)) ? 1 : 0;
    r1 += (t1 > s1 || (t1 == s1 && u1 < c1)) ? 1 : 0;
  }
  const bool sel0 = r0 < 16, sel1 = r1 < 16;

  float v = fmaxf(sel0 ? s0 : -3.0e38f, sel1 ? s1 : -3.0e38f);
#pragma unroll
  for (int d2 = 1; d2 < 64; d2 <<= 1) v = fmaxf(v, __shfl_xor(v, d2));
  const float e0 = sel0 ? expf(s0 - v) : 0.f;
  const float e1 = sel1 ? expf(s1 - v) : 0.f;
  float Z = e0 + e1;
#pragma unroll
  for (int d2 = 1; d2 < 64; d2 <<= 1) Z += __shfl_xor(Z, d2);
  const float w0 = e0 / Z, w1 = e1 / Z;

  float a0 = 0.f, a1 = 0.f;
  unsigned long long b0 = __ballot(sel0);
  while (b0) {
    const int src = __ffsll(b0) - 1; b0 &= b0 - 1;
    const float wj = __shfl(w0, src);
    const int   cj = __shfl(c0, src);
    const float* __restrict__ vr = vn + (size_t)cj * D;
    a0 = fmaf(wj, vr[lane], a0);
    a1 = fmaf(wj, vr[64 + lane], a1);
  }
  unsigned long long b1 = __ballot(sel1);
  while (b1) {
    const int src = __ffsll(b1) - 1; b1 &= b1 - 1;
    const float wj = __shfl(w1, src);
    const int   cj = __shfl(c1, src);
    const float* __restrict__ vr = vn + (size_t)cj * D;
    a0 = fmaf(wj, vr[lane], a0);
    a1 = fmaf(wj, vr[64 + lane], a1);
  }
  enext[(size_t)row * D + lane]      = fmaxf(a0, 0.f);
  enext[(size_t)row * D + 64 + lane] = fmaxf(a1, 0.f);
}

// ---------------------------------------------------------------------------
// final = [e0|e1|e2] @ la_w + la_b, row-L2-normalized (unchanged)
// ---------------------------------------------------------------------------
__global__ void k_final_norm(const float* __restrict__ e0, const float* __restrict__ e1,
                             const float* __restrict__ e2, const float* __restrict__ law,
                             const float* __restrict__ lab, float* __restrict__ out) {
  __shared__ float red[128];
  const int r = blockIdx.x;
  const int j = threadIdx.x;
  const float* __restrict__ a0 = e0 + (size_t)r * D;
  const float* __restrict__ a1 = e1 + (size_t)r * D;
  const float* __restrict__ a2 = e2 + (size_t)r * D;
  float acc = lab[j];
  for (int k = 0; k < D; ++k) acc = fmaf(a0[k], law[(size_t)k * D + j], acc);
  for (int k = 0; k < D; ++k) acc = fmaf(a1[k], law[(size_t)(D + k) * D + j], acc);
  for (int k = 0; k < D; ++k) acc = fmaf(a2[k], law[(size_t)(2 * D + k) * D + j], acc);
  red[j] = acc * acc;
  __syncthreads();
  for (int st = 64; st > 0; st >>= 1) {
    if (j < st) red[j] += red[j + st];
    __syncthreads();
  }
  const float nrm = fmaxf(sqrtf(red[0]), 1e-12f);
  const float o = acc / nrm;
  if (r < N_USERS) out[(size_t)r * D + j] = o;
  else             out[(size_t)N_USERS * D + (size_t)(r - N_USERS) * D + j] = o;
}

// ---------------------------------------------------------------------------
extern "C" void kernel_launch(void* const* d_in, const int* in_sizes, int n_in,
                              void* d_out, int out_size, void* d_ws, size_t ws_size,
                              hipStream_t stream) {
  const float* user_w = (const float*)d_in[0];
  const float* item_w = (const float*)d_in[1];
  const float* ent_w  = (const float*)d_in[2];
  const float* rel_w  = (const float*)d_in[3];
  const float* mfeat  = (const float*)d_in[4];
  const float* ufeat  = (const float*)d_in[5];
  const float* me_w1  = (const float*)d_in[6];
  const float* me_b1  = (const float*)d_in[7];
  const float* me_w2  = (const float*)d_in[8];
  const float* me_b2  = (const float*)d_in[9];
  const float* ue_w1  = (const float*)d_in[10];
  const float* ue_b1  = (const float*)d_in[11];
  const float* ue_w2  = (const float*)d_in[12];
  const float* ue_b2  = (const float*)d_in[13];
  const float* cm_vw  = (const float*)d_in[18];
  const float* cm_vb  = (const float*)d_in[19];
  const float* cm_ow  = (const float*)d_in[20];
  const float* cm_ob  = (const float*)d_in[21];
  const float* mg_w   = (const float*)d_in[22];
  const float* mg_b   = (const float*)d_in[23];
  const float* ug_w   = (const float*)d_in[24];
  const float* ug_b   = (const float*)d_in[25];
  const float* gnn_qw = (const float*)d_in[26];
  const float* gnn_qb = (const float*)d_in[27];
  const float* gnn_kw = (const float*)d_in[28];
  const float* gnn_kb = (const float*)d_in[29];
  const float* gnn_vw = (const float*)d_in[30];
  const float* gnn_vb = (const float*)d_in[31];
  const float* la_w   = (const float*)d_in[32];
  const float* la_b   = (const float*)d_in[33];
  const float* adj_d  = (const float*)d_in[34];
  const int*   adj_r  = (const int*)d_in[35];
  const int*   adj_c  = (const int*)d_in[36];
  float* out = (float*)d_out;
  float* ws  = (float*)d_ws;

  // ---- workspace layout (floats) ----
  size_t off = 0;
  float* mm_item = ws + off; off += (size_t)N_ITEMS * D;
  float* mm_user = ws + off; off += (size_t)N_USERS * D;
  float* enc     = ws + off; off += (size_t)N_ITEMS * D;
  float* tmp     = ws + off; off += (size_t)N_ITEMS * D;
  float* emb0    = ws + off; off += (size_t)NTOT * D;
  float* emb1    = ws + off; off += (size_t)NTOT * D;
  float* emb2    = ws + off; off += (size_t)NTOT * D;
  float* side    = ws + off; off += (size_t)NTOT * D;
  float* qn      = ws + off; off += (size_t)NTOT * D;
  float* kn      = ws + off; off += (size_t)NTOT * D;
  float* vn      = ws + off; off += (size_t)NTOT * D;
  float* relmean = ws + off; off += D;
  // bf16 mirrors overlay mm_user/enc/tmp (dead after the fusion stage)
  u16* qb = (u16*)mm_user;
  u16* kb = qb + (size_t)NTOT * D;
  // candidate indices overlay `side` (dead after kn/vn are computed)
  int* cand = (int*)side;

  // ---- modality encoders ----
  k_lin4<<<N_ITEMS / 4, D, 0, stream>>>(mfeat, me_w1, me_b1, nullptr, tmp, nullptr, 768, 1);
  k_lin4<<<N_ITEMS / 4, D, 0, stream>>>(tmp, me_w2, me_b2, nullptr, enc, nullptr, 128, 1);
  k_lin4<<<N_USERS / 4, D, 0, stream>>>(ufeat, ue_w1, ue_b1, nullptr, tmp, nullptr, 512, 1);
  k_lin4<<<N_USERS / 4, D, 0, stream>>>(tmp, ue_w2, ue_b2, nullptr, mm_user, nullptr, 128, 1);
  // ---- collapsed cross-modal attention: mm_item = 2*((enc@vw+vb)@ow+ob) ----
  k_lin4<<<N_ITEMS / 4, D, 0, stream>>>(enc, cm_vw, cm_vb, nullptr, tmp, nullptr, 128, 0);
  k_lin4<<<N_ITEMS / 4, D, 0, stream>>>(tmp, cm_ow, cm_ob, nullptr, mm_item, nullptr, 128, 2);
  // ---- gated fusion -> emb0 ----
  k_gatefuse<<<N_ITEMS, D, 0, stream>>>(item_w, mm_item, mg_w, mg_b, emb0 + (size_t)N_USERS * D);
  k_gatefuse<<<N_USERS, D, 0, stream>>>(user_w, mm_user, ug_w, ug_b, emb0);
  k_copy<<<(N_ENT * D + 255) / 256, 256, 0, stream>>>(ent_w, emb0 + (size_t)(N_USERS + N_ITEMS) * D, N_ENT * D);
  k_relmean<<<1, D, 0, stream>>>(rel_w, relmean);

  // ---- GNN layers ----
  const long long spthreads = (long long)NEDGE * D;
  const int spgrid = (int)((spthreads + 255) / 256);
  const float* eml[3] = {emb0, emb1, emb2};
  for (int l = 0; l < 2; ++l) {
    const float* e = eml[l];
    float* enext   = (float*)eml[l + 1];
    hipMemsetAsync(side, 0, (size_t)NTOT * D * sizeof(float), stream);
    k_spmm<<<spgrid, 256, 0, stream>>>(adj_d, adj_r, adj_c, e, side);
    k_lin4<<<NTOT / 4, D, 0, stream>>>(e,    gnn_qw + (size_t)l * D * D, gnn_qb + (size_t)l * D, nullptr, qn, qb, 128, 0);
    k_lin4<<<NTOT / 4, D, 0, stream>>>(side, gnn_kw + (size_t)l * D * D, gnn_kb + (size_t)l * D, relmean, kn, kb, 128, 0);
    k_lin4<<<NTOT / 4, D, 0, stream>>>(side, gnn_vw + (size_t)l * D * D, gnn_vb + (size_t)l * D, nullptr, vn, nullptr, 128, 0);
    // side is now dead -> reuse as candidate store
    dim3 tkgrid(NTOT / 16, NSLICE);
    k_topk32<<<tkgrid, 64, 0, stream>>>(qb, kb, cand);
    k_rescore128<<<NTOT, 64, 0, stream>>>(qn, kn, vn, cand, enext);
  }

  // ---- layer aggregation + normalize -> d_out ----
  k_final_norm<<<N_USERS + N_ITEMS, D, 0, stream>>>(emb0, emb1, emb2, la_w, la_b, out);
  // ---- passthrough outputs ----
  k_copy<<<(N_ITEMS * D + 255) / 256, 256, 0, stream>>>(item_w, out + (size_t)(N_USERS + N_ITEMS) * D, N_ITEMS * D);
  k_copy<<<(N_ITEMS * D + 255) / 256, 256, 0, stream>>>(mm_item, out + (size_t)(N_USERS + 2 * N_ITEMS) * D, N_ITEMS * D);
}

// Round 6
// 1983.601 us; speedup vs baseline: 1.7727x; 1.3776x over previous
//
#include <hip/hip_runtime.h>
#include <hip/hip_bf16.h>
#include <math.h>

#define N_USERS 2500
#define N_ITEMS 3000
#define N_ENT   2500
#define NTOT    8000
#define D       128
#define NEDGE   256000
#define NSLICE  8

typedef unsigned short u16;
typedef __attribute__((ext_vector_type(8))) short short8;
typedef __attribute__((ext_vector_type(4))) float f32x4;

// ---------------------------------------------------------------------------
// Generic 4-rows-per-block linear (unchanged)
// ---------------------------------------------------------------------------
__global__ void k_lin4(const float* __restrict__ A, const float* __restrict__ W,
                       const float* __restrict__ b, const float* __restrict__ ks,
                       float* __restrict__ out, u16* __restrict__ ob, int K, int mode) {
  const int r0 = blockIdx.x * 4;
  const int j  = threadIdx.x;
  const float* __restrict__ a0 = A + (size_t)r0 * K;
  const float* __restrict__ a1 = a0 + K;
  const float* __restrict__ a2 = a1 + K;
  const float* __restrict__ a3 = a2 + K;
  float c0 = 0.f, c1 = 0.f, c2 = 0.f, c3 = 0.f;
  if (ks) {
    for (int k = 0; k < K; ++k) {
      const float w = W[(size_t)k * D + j];
      const float s = ks[k];
      c0 = fmaf(a0[k] * s, w, c0);
      c1 = fmaf(a1[k] * s, w, c1);
      c2 = fmaf(a2[k] * s, w, c2);
      c3 = fmaf(a3[k] * s, w, c3);
    }
  } else {
    for (int k = 0; k < K; ++k) {
      const float w = W[(size_t)k * D + j];
      c0 = fmaf(a0[k], w, c0);
      c1 = fmaf(a1[k], w, c1);
      c2 = fmaf(a2[k], w, c2);
      c3 = fmaf(a3[k], w, c3);
    }
  }
  const float bj = b[j];
  c0 += bj; c1 += bj; c2 += bj; c3 += bj;
  if (mode == 1) {
    c0 = fmaxf(c0, 0.f); c1 = fmaxf(c1, 0.f); c2 = fmaxf(c2, 0.f); c3 = fmaxf(c3, 0.f);
  } else if (mode == 2) {
    c0 *= 2.f; c1 *= 2.f; c2 *= 2.f; c3 *= 2.f;
  }
  float* __restrict__ o = out + (size_t)r0 * D + j;
  o[0] = c0; o[D] = c1; o[2 * D] = c2; o[3 * D] = c3;
  if (ob) {
    __hip_bfloat16 h0 = __float2bfloat16(c0), h1 = __float2bfloat16(c1);
    __hip_bfloat16 h2 = __float2bfloat16(c2), h3 = __float2bfloat16(c3);
    u16* __restrict__ p = ob + (size_t)r0 * D + j;
    p[0]     = *reinterpret_cast<u16*>(&h0);
    p[D]     = *reinterpret_cast<u16*>(&h1);
    p[2 * D] = *reinterpret_cast<u16*>(&h2);
    p[3 * D] = *reinterpret_cast<u16*>(&h3);
  }
}

// ---------------------------------------------------------------------------
// Gated fusion (unchanged)
// ---------------------------------------------------------------------------
__global__ void k_gatefuse(const float* __restrict__ base, const float* __restrict__ mm,
                           const float* __restrict__ gw, const float* __restrict__ gb,
                           float* __restrict__ embout) {
  const int r = blockIdx.x;
  const int j = threadIdx.x;
  const float* __restrict__ b0 = base + (size_t)r * D;
  const float* __restrict__ m0 = mm + (size_t)r * D;
  float acc = 0.f;
  for (int k = 0; k < D; ++k) acc = fmaf(b0[k], gw[(size_t)k * D + j], acc);
  for (int k = 0; k < D; ++k) acc = fmaf(m0[k], gw[(size_t)(D + k) * D + j], acc);
  acc += gb[j];
  const float s1 = 1.f / (1.f + expf(-acc));
  const float g  = 1.f / (1.f + expf(-(s1 * 2.f)));
  const float bv = b0[j], mv = m0[j];
  embout[(size_t)r * D + j] = g * bv + (1.f - g) * mv + 0.1f * bv;
}

__global__ void k_relmean(const float* __restrict__ rel, float* __restrict__ out) {
  const int j = threadIdx.x;
  float s = 0.f;
  for (int i = 0; i < 32; ++i) s += rel[i * D + j];
  out[j] = s * (1.f / 32.f);
}

__global__ void k_copy(const float* __restrict__ src, float* __restrict__ dst, int n) {
  const int t = blockIdx.x * blockDim.x + threadIdx.x;
  if (t < n) dst[t] = src[t];
}

// ---------------------------------------------------------------------------
// side[row] += data * e[col]  via f32 atomics (unchanged)
// ---------------------------------------------------------------------------
__global__ void k_spmm(const float* __restrict__ dat, const int* __restrict__ rw,
                       const int* __restrict__ cl, const float* __restrict__ e,
                       float* __restrict__ side) {
  const long long t = (long long)blockIdx.x * blockDim.x + threadIdx.x;
  if (t >= (long long)NEDGE * D) return;
  const int ei = (int)(t >> 7);
  const int d  = (int)(t & 127);
  const float v = dat[ei] * e[(size_t)cl[ei] * D + d];
  atomicAdd(side + (size_t)rw[ei] * D + d, v);
}

// ---------------------------------------------------------------------------
// bf16-MFMA score scan, 8 column slices, per-row top-16 per slice.
// One slot per lane in each 16-lane row-group. Lean ballot insert:
//  - eviction tie-break on lane only (2 shfls/stage, unique winner)
//  - thr recomputed ONCE per tile (stale thr only wastes a butterfly;
//    the sv > lv check keeps correctness)
// Candidates -> cand[row*128 + slice*16 + col] (dead `side` buffer).
// ---------------------------------------------------------------------------
__device__ __forceinline__ void insert1(float s, int cbase, int lane, int g16,
                                        float& slotv, int& sloti, float& thr) {
  unsigned long long ball = __ballot(s > thr);
  unsigned m16 = (unsigned)((ball >> g16) & 0xffffULL);
  if (!__any(m16 != 0)) return;
  while (__any(m16 != 0)) {
    const bool active = (m16 != 0);
    const int src = active ? (__ffs(m16) - 1) : 0;
    m16 &= (m16 - 1u);
    const float sv = __shfl(s, g16 + src);
    const int   scl = cbase + src;
    // argmin over the 16 slots; unique winner via lane tie-break
    float lv = slotv; int ml = lane;
#pragma unroll
    for (int d2 = 1; d2 < 16; d2 <<= 1) {
      const float ov = __shfl_xor(lv, d2);
      const int   ol = __shfl_xor(ml, d2);
      if (ov < lv || (ov == lv && ol < ml)) { lv = ov; ml = ol; }
    }
    if (active && sv > lv && lane == ml) { slotv = sv; sloti = scl; }
  }
  float t = slotv;
#pragma unroll
  for (int d2 = 1; d2 < 16; d2 <<= 1) t = fminf(t, __shfl_xor(t, d2));
  thr = t;
}

__global__ __launch_bounds__(64) void k_topk16(const u16* __restrict__ qb,
                                               const u16* __restrict__ kb,
                                               int* __restrict__ cand) {
  const int lane = threadIdx.x;
  const int rbase = blockIdx.x * 16;
  const int sl   = blockIdx.y;
  const int g16 = lane & 48;
  const int colL = lane & 15;
  const int kofs = (lane >> 4) * 8;

  short8 aF[4];
  {
    const u16* ap = qb + (size_t)(rbase + colL) * D + kofs;
#pragma unroll
    for (int t = 0; t < 4; ++t) aF[t] = *reinterpret_cast<const short8*>(ap + t * 32);
  }

  float slotv[4]; int sloti[4]; float thr[4];
#pragma unroll
  for (int r = 0; r < 4; ++r) {
    slotv[r] = -3.0e38f;
    sloti[r] = 0x40000000 + colL;
    thr[r] = -3.0e38f;
  }

  // 500 tiles split 63,63,63,63,62,62,62,62
  const int tile0  = sl * 62 + (sl < 4 ? sl : 4);
  const int ntiles = 62 + (sl < 4 ? 1 : 0);
  const u16* bb = kb + (size_t)(tile0 * 16 + colL) * D + kofs;

  short8 bF[4];
#pragma unroll
  for (int t = 0; t < 4; ++t) bF[t] = *reinterpret_cast<const short8*>(bb + t * 32);

  for (int c = 0; c < ntiles; ++c) {
    const int cn = (c + 1 < ntiles) ? c + 1 : c;
    const u16* nb = bb + (size_t)cn * 16 * D;
    short8 bN[4];
#pragma unroll
    for (int t = 0; t < 4; ++t) bN[t] = *reinterpret_cast<const short8*>(nb + t * 32);

    f32x4 acc = {0.f, 0.f, 0.f, 0.f};
#pragma unroll
    for (int t = 0; t < 4; ++t)
      acc = __builtin_amdgcn_mfma_f32_16x16x32_bf16(aF[t], bF[t], acc, 0, 0, 0);

    const int cbase = (tile0 + c) * 16;
#pragma unroll
    for (int r = 0; r < 4; ++r)
      insert1(acc[r], cbase, lane, g16, slotv[r], sloti[r], thr[r]);

#pragma unroll
    for (int t = 0; t < 4; ++t) bF[t] = bN[t];
  }

#pragma unroll
  for (int r = 0; r < 4; ++r) {
    const int row = rbase + (lane >> 4) * 4 + r;
    cand[(size_t)row * 128 + sl * 16 + colL] = sloti[r];
  }
}

// ---------------------------------------------------------------------------
// Exact f32 rescore of 128 candidates (2/lane), true top-16 by (value, lower
// index), softmax, gather vn. One wave per row. (unchanged)
// ---------------------------------------------------------------------------
__global__ __launch_bounds__(64) void k_rescore128(const float* __restrict__ qn,
                                                   const float* __restrict__ kn,
                                                   const float* __restrict__ vn,
                                                   const int* __restrict__ cand,
                                                   float* __restrict__ enext) {
  const int row = blockIdx.x;
  const int lane = threadIdx.x;
  const int* cr = cand + (size_t)row * 128;
  const int c0 = cr[lane];
  const int c1 = cr[64 + lane];

  const float4* __restrict__ q4  = (const float4*)(qn + (size_t)row * D);
  const float4* __restrict__ k40 = (const float4*)(kn + (size_t)c0 * D);
  const float4* __restrict__ k41 = (const float4*)(kn + (size_t)c1 * D);
  float s0 = 0.f, s1 = 0.f;
#pragma unroll 8
  for (int j = 0; j < 32; ++j) {
    const float4 qv = q4[j];
    const float4 a = k40[j], b = k41[j];
    s0 = fmaf(qv.x, a.x, s0); s0 = fmaf(qv.y, a.y, s0);
    s0 = fmaf(qv.z, a.z, s0); s0 = fmaf(qv.w, a.w, s0);
    s1 = fmaf(qv.x, b.x, s1); s1 = fmaf(qv.y, b.y, s1);
    s1 = fmaf(qv.z, b.z, s1); s1 = fmaf(qv.w, b.w, s1);
  }
  const float inv = 0.088388347648318447f;   // 1/sqrt(128)
  s0 *= inv; s1 *= inv;

  // rank among 128 by (value desc, index asc); indices are unique
  int r0 = 0, r1 = 0;
  for (int j = 0; j < 64; ++j) {
    const float t0 = __shfl(s0, j), t1 = __shfl(s1, j);
    const int   u0 = __shfl(c0, j), u1 = __shfl(c1, j);
    r0 += (t0 > s0 || (t0 == s0 && u0 < c0)) ? 1 : 0;
    r0 += (t1 > s0 || (t1 == s0 && u1 < c0)) ? 1 : 0;
    r1 += (t0 > s1 || (t0 == s1 && u0 < c1)) ? 1 : 0;
    r1 += (t1 > s1 || (t1 == s1 && u1 < c1)) ? 1 : 0;
  }
  const bool sel0 = r0 < 16, sel1 = r1 < 16;

  float v = fmaxf(sel0 ? s0 : -3.0e38f, sel1 ? s1 : -3.0e38f);
#pragma unroll
  for (int d2 = 1; d2 < 64; d2 <<= 1) v = fmaxf(v, __shfl_xor(v, d2));
  const float e0 = sel0 ? expf(s0 - v) : 0.f;
  const float e1 = sel1 ? expf(s1 - v) : 0.f;
  float Z = e0 + e1;
#pragma unroll
  for (int d2 = 1; d2 < 64; d2 <<= 1) Z += __shfl_xor(Z, d2);
  const float w0 = e0 / Z, w1 = e1 / Z;

  float a0 = 0.f, a1 = 0.f;
  unsigned long long b0 = __ballot(sel0);
  while (b0) {
    const int src = __ffsll(b0) - 1; b0 &= b0 - 1;
    const float wj = __shfl(w0, src);
    const int   cj = __shfl(c0, src);
    const float* __restrict__ vr = vn + (size_t)cj * D;
    a0 = fmaf(wj, vr[lane], a0);
    a1 = fmaf(wj, vr[64 + lane], a1);
  }
  unsigned long long b1 = __ballot(sel1);
  while (b1) {
    const int src = __ffsll(b1) - 1; b1 &= b1 - 1;
    const float wj = __shfl(w1, src);
    const int   cj = __shfl(c1, src);
    const float* __restrict__ vr = vn + (size_t)cj * D;
    a0 = fmaf(wj, vr[lane], a0);
    a1 = fmaf(wj, vr[64 + lane], a1);
  }
  enext[(size_t)row * D + lane]      = fmaxf(a0, 0.f);
  enext[(size_t)row * D + 64 + lane] = fmaxf(a1, 0.f);
}

// ---------------------------------------------------------------------------
// final = [e0|e1|e2] @ la_w + la_b, row-L2-normalized (unchanged)
// ---------------------------------------------------------------------------
__global__ void k_final_norm(const float* __restrict__ e0, const float* __restrict__ e1,
                             const float* __restrict__ e2, const float* __restrict__ law,
                             const float* __restrict__ lab, float* __restrict__ out) {
  __shared__ float red[128];
  const int r = blockIdx.x;
  const int j = threadIdx.x;
  const float* __restrict__ a0 = e0 + (size_t)r * D;
  const float* __restrict__ a1 = e1 + (size_t)r * D;
  const float* __restrict__ a2 = e2 + (size_t)r * D;
  float acc = lab[j];
  for (int k = 0; k < D; ++k) acc = fmaf(a0[k], law[(size_t)k * D + j], acc);
  for (int k = 0; k < D; ++k) acc = fmaf(a1[k], law[(size_t)(D + k) * D + j], acc);
  for (int k = 0; k < D; ++k) acc = fmaf(a2[k], law[(size_t)(2 * D + k) * D + j], acc);
  red[j] = acc * acc;
  __syncthreads();
  for (int st = 64; st > 0; st >>= 1) {
    if (j < st) red[j] += red[j + st];
    __syncthreads();
  }
  const float nrm = fmaxf(sqrtf(red[0]), 1e-12f);
  const float o = acc / nrm;
  if (r < N_USERS) out[(size_t)r * D + j] = o;
  else             out[(size_t)N_USERS * D + (size_t)(r - N_USERS) * D + j] = o;
}

// ---------------------------------------------------------------------------
extern "C" void kernel_launch(void* const* d_in, const int* in_sizes, int n_in,
                              void* d_out, int out_size, void* d_ws, size_t ws_size,
                              hipStream_t stream) {
  const float* user_w = (const float*)d_in[0];
  const float* item_w = (const float*)d_in[1];
  const float* ent_w  = (const float*)d_in[2];
  const float* rel_w  = (const float*)d_in[3];
  const float* mfeat  = (const float*)d_in[4];
  const float* ufeat  = (const float*)d_in[5];
  const float* me_w1  = (const float*)d_in[6];
  const float* me_b1  = (const float*)d_in[7];
  const float* me_w2  = (const float*)d_in[8];
  const float* me_b2  = (const float*)d_in[9];
  const float* ue_w1  = (const float*)d_in[10];
  const float* ue_b1  = (const float*)d_in[11];
  const float* ue_w2  = (const float*)d_in[12];
  const float* ue_b2  = (const float*)d_in[13];
  const float* cm_vw  = (const float*)d_in[18];
  const float* cm_vb  = (const float*)d_in[19];
  const float* cm_ow  = (const float*)d_in[20];
  const float* cm_ob  = (const float*)d_in[21];
  const float* mg_w   = (const float*)d_in[22];
  const float* mg_b   = (const float*)d_in[23];
  const float* ug_w   = (const float*)d_in[24];
  const float* ug_b   = (const float*)d_in[25];
  const float* gnn_qw = (const float*)d_in[26];
  const float* gnn_qb = (const float*)d_in[27];
  const float* gnn_kw = (const float*)d_in[28];
  const float* gnn_kb = (const float*)d_in[29];
  const float* gnn_vw = (const float*)d_in[30];
  const float* gnn_vb = (const float*)d_in[31];
  const float* la_w   = (const float*)d_in[32];
  const float* la_b   = (const float*)d_in[33];
  const float* adj_d  = (const float*)d_in[34];
  const int*   adj_r  = (const int*)d_in[35];
  const int*   adj_c  = (const int*)d_in[36];
  float* out = (float*)d_out;
  float* ws  = (float*)d_ws;

  // ---- workspace layout (floats) ----
  size_t off = 0;
  float* mm_item = ws + off; off += (size_t)N_ITEMS * D;
  float* mm_user = ws + off; off += (size_t)N_USERS * D;
  float* enc     = ws + off; off += (size_t)N_ITEMS * D;
  float* tmp     = ws + off; off += (size_t)N_ITEMS * D;
  float* emb0    = ws + off; off += (size_t)NTOT * D;
  float* emb1    = ws + off; off += (size_t)NTOT * D;
  float* emb2    = ws + off; off += (size_t)NTOT * D;
  float* side    = ws + off; off += (size_t)NTOT * D;
  float* qn      = ws + off; off += (size_t)NTOT * D;
  float* kn      = ws + off; off += (size_t)NTOT * D;
  float* vn      = ws + off; off += (size_t)NTOT * D;
  float* relmean = ws + off; off += D;
  // bf16 mirrors overlay mm_user/enc/tmp (dead after the fusion stage)
  u16* qb = (u16*)mm_user;
  u16* kb = qb + (size_t)NTOT * D;
  // candidate indices overlay `side` (dead after kn/vn are computed)
  int* cand = (int*)side;

  // ---- modality encoders ----
  k_lin4<<<N_ITEMS / 4, D, 0, stream>>>(mfeat, me_w1, me_b1, nullptr, tmp, nullptr, 768, 1);
  k_lin4<<<N_ITEMS / 4, D, 0, stream>>>(tmp, me_w2, me_b2, nullptr, enc, nullptr, 128, 1);
  k_lin4<<<N_USERS / 4, D, 0, stream>>>(ufeat, ue_w1, ue_b1, nullptr, tmp, nullptr, 512, 1);
  k_lin4<<<N_USERS / 4, D, 0, stream>>>(tmp, ue_w2, ue_b2, nullptr, mm_user, nullptr, 128, 1);
  // ---- collapsed cross-modal attention: mm_item = 2*((enc@vw+vb)@ow+ob) ----
  k_lin4<<<N_ITEMS / 4, D, 0, stream>>>(enc, cm_vw, cm_vb, nullptr, tmp, nullptr, 128, 0);
  k_lin4<<<N_ITEMS / 4, D, 0, stream>>>(tmp, cm_ow, cm_ob, nullptr, mm_item, nullptr, 128, 2);
  // ---- gated fusion -> emb0 ----
  k_gatefuse<<<N_ITEMS, D, 0, stream>>>(item_w, mm_item, mg_w, mg_b, emb0 + (size_t)N_USERS * D);
  k_gatefuse<<<N_USERS, D, 0, stream>>>(user_w, mm_user, ug_w, ug_b, emb0);
  k_copy<<<(N_ENT * D + 255) / 256, 256, 0, stream>>>(ent_w, emb0 + (size_t)(N_USERS + N_ITEMS) * D, N_ENT * D);
  k_relmean<<<1, D, 0, stream>>>(rel_w, relmean);

  // ---- GNN layers ----
  const long long spthreads = (long long)NEDGE * D;
  const int spgrid = (int)((spthreads + 255) / 256);
  const float* eml[3] = {emb0, emb1, emb2};
  for (int l = 0; l < 2; ++l) {
    const float* e = eml[l];
    float* enext   = (float*)eml[l + 1];
    hipMemsetAsync(side, 0, (size_t)NTOT * D * sizeof(float), stream);
    k_spmm<<<spgrid, 256, 0, stream>>>(adj_d, adj_r, adj_c, e, side);
    k_lin4<<<NTOT / 4, D, 0, stream>>>(e,    gnn_qw + (size_t)l * D * D, gnn_qb + (size_t)l * D, nullptr, qn, qb, 128, 0);
    k_lin4<<<NTOT / 4, D, 0, stream>>>(side, gnn_kw + (size_t)l * D * D, gnn_kb + (size_t)l * D, relmean, kn, kb, 128, 0);
    k_lin4<<<NTOT / 4, D, 0, stream>>>(side, gnn_vw + (size_t)l * D * D, gnn_vb + (size_t)l * D, nullptr, vn, nullptr, 128, 0);
    // side is now dead -> reuse as candidate store
    dim3 tkgrid(NTOT / 16, NSLICE);
    k_topk16<<<tkgrid, 64, 0, stream>>>(qb, kb, cand);
    k_rescore128<<<NTOT, 64, 0, stream>>>(qn, kn, vn, cand, enext);
  }

  // ---- layer aggregation + normalize -> d_out ----
  k_final_norm<<<N_USERS + N_ITEMS, D, 0, stream>>>(emb0, emb1, emb2, la_w, la_b, out);
  // ---- passthrough outputs ----
  k_copy<<<(N_ITEMS * D + 255) / 256, 256, 0, stream>>>(item_w, out + (size_t)(N_USERS + N_ITEMS) * D, N_ITEMS * D);
  k_copy<<<(N_ITEMS * D + 255) / 256, 256, 0, stream>>>(mm_item, out + (size_t)(N_USERS + 2 * N_ITEMS) * D, N_ITEMS * D);
}

// Round 8
// 1865.790 us; speedup vs baseline: 1.8847x; 1.0631x over previous
//
#include <hip/hip_runtime.h>
#include <hip/hip_bf16.h>
#include <math.h>

#define N_USERS 2500
#define N_ITEMS 3000
#define N_ENT   2500
#define NTOT    8000
#define D       128
#define NEDGE   256000
#define NSLICE  8

typedef unsigned short u16;
typedef unsigned int u32;
typedef __attribute__((ext_vector_type(8))) short short8;
typedef __attribute__((ext_vector_type(4))) float f32x4;

// ---------------------------------------------------------------------------
// Generic 4-rows-per-block linear (unchanged)
// ---------------------------------------------------------------------------
__global__ void k_lin4(const float* __restrict__ A, const float* __restrict__ W,
                       const float* __restrict__ b, const float* __restrict__ ks,
                       float* __restrict__ out, u16* __restrict__ ob, int K, int mode) {
  const int r0 = blockIdx.x * 4;
  const int j  = threadIdx.x;
  const float* __restrict__ a0 = A + (size_t)r0 * K;
  const float* __restrict__ a1 = a0 + K;
  const float* __restrict__ a2 = a1 + K;
  const float* __restrict__ a3 = a2 + K;
  float c0 = 0.f, c1 = 0.f, c2 = 0.f, c3 = 0.f;
  if (ks) {
    for (int k = 0; k < K; ++k) {
      const float w = W[(size_t)k * D + j];
      const float s = ks[k];
      c0 = fmaf(a0[k] * s, w, c0);
      c1 = fmaf(a1[k] * s, w, c1);
      c2 = fmaf(a2[k] * s, w, c2);
      c3 = fmaf(a3[k] * s, w, c3);
    }
  } else {
    for (int k = 0; k < K; ++k) {
      const float w = W[(size_t)k * D + j];
      c0 = fmaf(a0[k], w, c0);
      c1 = fmaf(a1[k], w, c1);
      c2 = fmaf(a2[k], w, c2);
      c3 = fmaf(a3[k], w, c3);
    }
  }
  const float bj = b[j];
  c0 += bj; c1 += bj; c2 += bj; c3 += bj;
  if (mode == 1) {
    c0 = fmaxf(c0, 0.f); c1 = fmaxf(c1, 0.f); c2 = fmaxf(c2, 0.f); c3 = fmaxf(c3, 0.f);
  } else if (mode == 2) {
    c0 *= 2.f; c1 *= 2.f; c2 *= 2.f; c3 *= 2.f;
  }
  float* __restrict__ o = out + (size_t)r0 * D + j;
  o[0] = c0; o[D] = c1; o[2 * D] = c2; o[3 * D] = c3;
  if (ob) {
    __hip_bfloat16 h0 = __float2bfloat16(c0), h1 = __float2bfloat16(c1);
    __hip_bfloat16 h2 = __float2bfloat16(c2), h3 = __float2bfloat16(c3);
    u16* __restrict__ p = ob + (size_t)r0 * D + j;
    p[0]     = *reinterpret_cast<u16*>(&h0);
    p[D]     = *reinterpret_cast<u16*>(&h1);
    p[2 * D] = *reinterpret_cast<u16*>(&h2);
    p[3 * D] = *reinterpret_cast<u16*>(&h3);
  }
}

// ---------------------------------------------------------------------------
// Gated fusion (unchanged)
// ---------------------------------------------------------------------------
__global__ void k_gatefuse(const float* __restrict__ base, const float* __restrict__ mm,
                           const float* __restrict__ gw, const float* __restrict__ gb,
                           float* __restrict__ embout) {
  const int r = blockIdx.x;
  const int j = threadIdx.x;
  const float* __restrict__ b0 = base + (size_t)r * D;
  const float* __restrict__ m0 = mm + (size_t)r * D;
  float acc = 0.f;
  for (int k = 0; k < D; ++k) acc = fmaf(b0[k], gw[(size_t)k * D + j], acc);
  for (int k = 0; k < D; ++k) acc = fmaf(m0[k], gw[(size_t)(D + k) * D + j], acc);
  acc += gb[j];
  const float s1 = 1.f / (1.f + expf(-acc));
  const float g  = 1.f / (1.f + expf(-(s1 * 2.f)));
  const float bv = b0[j], mv = m0[j];
  embout[(size_t)r * D + j] = g * bv + (1.f - g) * mv + 0.1f * bv;
}

__global__ void k_relmean(const float* __restrict__ rel, float* __restrict__ out) {
  const int j = threadIdx.x;
  float s = 0.f;
  for (int i = 0; i < 32; ++i) s += rel[i * D + j];
  out[j] = s * (1.f / 32.f);
}

__global__ void k_copy(const float* __restrict__ src, float* __restrict__ dst, int n) {
  const int t = blockIdx.x * blockDim.x + threadIdx.x;
  if (t < n) dst[t] = src[t];
}

// ---------------------------------------------------------------------------
// side[row] += data * e[col]  via f32 atomics (unchanged)
// ---------------------------------------------------------------------------
__global__ void k_spmm(const float* __restrict__ dat, const int* __restrict__ rw,
                       const int* __restrict__ cl, const float* __restrict__ e,
                       float* __restrict__ side) {
  const long long t = (long long)blockIdx.x * blockDim.x + threadIdx.x;
  if (t >= (long long)NEDGE * D) return;
  const int ei = (int)(t >> 7);
  const int d  = (int)(t & 127);
  const float v = dat[ei] * e[(size_t)cl[ei] * D + d];
  atomicAdd(side + (size_t)rw[ei] * D + d, v);
}

// ---------------------------------------------------------------------------
// bf16-MFMA score scan, 8 column slices, shuffle-free selection.
// r8 REWRITE of r7: the packed-u32-key machinery (monotonic bit-pack with
// 13-bit truncation, u32 bubble, uint4 LDS reads) is replaced with exact
// (float score, int col) pairs and the REFERENCE comparator
//   better(a,b) = sa > sb || (sa == sb && ca < cb)      [score desc, col asc]
// so the selection semantics are exactly r6's proven per-slice top-16 plus
// the per-cell top-6 pre-filter (loss prob ~3e-9 per member).
// Each lane owns cell (rows 4g..4g+3, cols == colL mod 16); keeps top-6/row.
// LDS rank-merge: 96 survivors/row -> rank<16 -> cand slots (dead `side`).
// ---------------------------------------------------------------------------
__global__ __launch_bounds__(64) void k_topk6f(const u16* __restrict__ qb,
                                               const u16* __restrict__ kb,
                                               int* __restrict__ cand) {
  __shared__ float ss[16][100];   // pad 96->100: rows land on distinct banks
  __shared__ int   sc[16][100];
  const int lane = threadIdx.x;
  const int rbase = blockIdx.x * 16;
  const int sl   = blockIdx.y;
  const int colL = lane & 15;
  const int kofs = (lane >> 4) * 8;

  short8 aF[4];
  {
    const u16* ap = qb + (size_t)(rbase + colL) * D + kofs;
#pragma unroll
    for (int t = 0; t < 4; ++t) aF[t] = *reinterpret_cast<const short8*>(ap + t * 32);
  }

  float s[4][6]; int c[4][6];
#pragma unroll
  for (int r = 0; r < 4; ++r)
#pragma unroll
    for (int j = 0; j < 6; ++j) { s[r][j] = -3.0e38f; c[r][j] = 0x40000000 + colL * 6 + j; }

  // 500 tiles split 63,63,63,63,62,62,62,62
  const int tile0  = sl * 62 + (sl < 4 ? sl : 4);
  const int ntiles = 62 + (sl < 4 ? 1 : 0);
  const u16* bb = kb + (size_t)(tile0 * 16 + colL) * D + kofs;

  short8 bF[4];
#pragma unroll
  for (int t = 0; t < 4; ++t) bF[t] = *reinterpret_cast<const short8*>(bb + t * 32);

  for (int ct = 0; ct < ntiles; ++ct) {
    const int cn = (ct + 1 < ntiles) ? ct + 1 : ct;
    const u16* nb = bb + (size_t)cn * 16 * D;
    short8 bN[4];
#pragma unroll
    for (int t = 0; t < 4; ++t) bN[t] = *reinterpret_cast<const short8*>(nb + t * 32);

    f32x4 acc = {0.f, 0.f, 0.f, 0.f};
#pragma unroll
    for (int t = 0; t < 4; ++t)
      acc = __builtin_amdgcn_mfma_f32_16x16x32_bf16(aF[t], bF[t], acc, 0, 0, 0);

    const int colIdx = (tile0 + ct) * 16 + colL;
#pragma unroll
    for (int r = 0; r < 4; ++r) {
      float ks = acc[r]; int kc = colIdx;
      if (ks > s[r][5] || (ks == s[r][5] && kc < c[r][5])) {
#pragma unroll
        for (int i = 0; i < 6; ++i) {   // bubble (ks,kc) into sorted-desc list
          const bool bgt = (ks > s[r][i]) || (ks == s[r][i] && kc < c[r][i]);
          const float os = s[r][i]; const int oc = c[r][i];
          s[r][i] = bgt ? ks : os;  c[r][i] = bgt ? kc : oc;
          ks      = bgt ? os : ks;  kc      = bgt ? oc : kc;
        }
      }
    }

#pragma unroll
    for (int t = 0; t < 4; ++t) bF[t] = bN[t];
  }

  // ---- LDS rank-merge: per row, rank each survivor among its 96 ----
#pragma unroll
  for (int r = 0; r < 4; ++r)
#pragma unroll
    for (int j = 0; j < 6; ++j) {
      ss[(lane >> 4) * 4 + r][colL * 6 + j] = s[r][j];
      sc[(lane >> 4) * 4 + r][colL * 6 + j] = c[r][j];
    }
  __syncthreads();

#pragma unroll
  for (int r = 0; r < 4; ++r) {
    const int row4 = (lane >> 4) * 4 + r;
    int cnt[6] = {0, 0, 0, 0, 0, 0};
    for (int q2 = 0; q2 < 96; ++q2) {
      const float os = ss[row4][q2];
      const int   oc = sc[row4][q2];
#pragma unroll
      for (int j = 0; j < 6; ++j)
        cnt[j] += ((os > s[r][j]) || (os == s[r][j] && oc < c[r][j])) ? 1 : 0;
    }
    const int row = rbase + row4;
#pragma unroll
    for (int j = 0; j < 6; ++j)
      if (cnt[j] < 16)
        cand[(size_t)row * 128 + sl * 16 + cnt[j]] = c[r][j];
  }
}

// ---------------------------------------------------------------------------
// Exact f32 rescore of 128 candidates (2/lane), true top-16 by (value, lower
// index), softmax, gather vn. One wave per row. (unchanged)
// ---------------------------------------------------------------------------
__global__ __launch_bounds__(64) void k_rescore128(const float* __restrict__ qn,
                                                   const float* __restrict__ kn,
                                                   const float* __restrict__ vn,
                                                   const int* __restrict__ cand,
                                                   float* __restrict__ enext) {
  const int row = blockIdx.x;
  const int lane = threadIdx.x;
  const int* cr = cand + (size_t)row * 128;
  const int c0 = cr[lane];
  const int c1 = cr[64 + lane];

  const float4* __restrict__ q4  = (const float4*)(qn + (size_t)row * D);
  const float4* __restrict__ k40 = (const float4*)(kn + (size_t)c0 * D);
  const float4* __restrict__ k41 = (const float4*)(kn + (size_t)c1 * D);
  float s0 = 0.f, s1 = 0.f;
#pragma unroll 8
  for (int j = 0; j < 32; ++j) {
    const float4 qv = q4[j];
    const float4 a = k40[j], b = k41[j];
    s0 = fmaf(qv.x, a.x, s0); s0 = fmaf(qv.y, a.y, s0);
    s0 = fmaf(qv.z, a.z, s0); s0 = fmaf(qv.w, a.w, s0);
    s1 = fmaf(qv.x, b.x, s1); s1 = fmaf(qv.y, b.y, s1);
    s1 = fmaf(qv.z, b.z, s1); s1 = fmaf(qv.w, b.w, s1);
  }
  const float inv = 0.088388347648318447f;   // 1/sqrt(128)
  s0 *= inv; s1 *= inv;

  // rank among 128 by (value desc, index asc); indices are unique
  int r0 = 0, r1 = 0;
  for (int j = 0; j < 64; ++j) {
    const float t0 = __shfl(s0, j), t1 = __shfl(s1, j);
    const int   u0 = __shfl(c0, j), u1 = __shfl(c1, j);
    r0 += (t0 > s0 || (t0 == s0 && u0 < c0)) ? 1 : 0;
    r0 += (t1 > s0 || (t1 == s0 && u1 < c0)) ? 1 : 0;
    r1 += (t0 > s1 || (t0 == s1 && u0 < c1)) ? 1 : 0;
    r1 += (t1 > s1 || (t1 == s1 && u1 < c1)) ? 1 : 0;
  }
  const bool sel0 = r0 < 16, sel1 = r1 < 16;

  float v = fmaxf(sel0 ? s0 : -3.0e38f, sel1 ? s1 : -3.0e38f);
#pragma unroll
  for (int d2 = 1; d2 < 64; d2 <<= 1) v = fmaxf(v, __shfl_xor(v, d2));
  const float e0 = sel0 ? expf(s0 - v) : 0.f;
  const float e1 = sel1 ? expf(s1 - v) : 0.f;
  float Z = e0 + e1;
#pragma unroll
  for (int d2 = 1; d2 < 64; d2 <<= 1) Z += __shfl_xor(Z, d2);
  const float w0 = e0 / Z, w1 = e1 / Z;

  float a0 = 0.f, a1 = 0.f;
  unsigned long long b0 = __ballot(sel0);
  while (b0) {
    const int src = __ffsll(b0) - 1; b0 &= b0 - 1;
    const float wj = __shfl(w0, src);
    const int   cj = __shfl(c0, src);
    const float* __restrict__ vr = vn + (size_t)cj * D;
    a0 = fmaf(wj, vr[lane], a0);
    a1 = fmaf(wj, vr[64 + lane], a1);
  }
  unsigned long long b1 = __ballot(sel1);
  while (b1) {
    const int src = __ffsll(b1) - 1; b1 &= b1 - 1;
    const float wj = __shfl(w1, src);
    const int   cj = __shfl(c1, src);
    const float* __restrict__ vr = vn + (size_t)cj * D;
    a0 = fmaf(wj, vr[lane], a0);
    a1 = fmaf(wj, vr[64 + lane], a1);
  }
  enext[(size_t)row * D + lane]      = fmaxf(a0, 0.f);
  enext[(size_t)row * D + 64 + lane] = fmaxf(a1, 0.f);
}

// ---------------------------------------------------------------------------
// final = [e0|e1|e2] @ la_w + la_b, row-L2-normalized (unchanged)
// ---------------------------------------------------------------------------
__global__ void k_final_norm(const float* __restrict__ e0, const float* __restrict__ e1,
                             const float* __restrict__ e2, const float* __restrict__ law,
                             const float* __restrict__ lab, float* __restrict__ out) {
  __shared__ float red[128];
  const int r = blockIdx.x;
  const int j = threadIdx.x;
  const float* __restrict__ a0 = e0 + (size_t)r * D;
  const float* __restrict__ a1 = e1 + (size_t)r * D;
  const float* __restrict__ a2 = e2 + (size_t)r * D;
  float acc = lab[j];
  for (int k = 0; k < D; ++k) acc = fmaf(a0[k], law[(size_t)k * D + j], acc);
  for (int k = 0; k < D; ++k) acc = fmaf(a1[k], law[(size_t)(D + k) * D + j], acc);
  for (int k = 0; k < D; ++k) acc = fmaf(a2[k], law[(size_t)(2 * D + k) * D + j], acc);
  red[j] = acc * acc;
  __syncthreads();
  for (int st = 64; st > 0; st >>= 1) {
    if (j < st) red[j] += red[j + st];
    __syncthreads();
  }
  const float nrm = fmaxf(sqrtf(red[0]), 1e-12f);
  const float o = acc / nrm;
  if (r < N_USERS) out[(size_t)r * D + j] = o;
  else             out[(size_t)N_USERS * D + (size_t)(r - N_USERS) * D + j] = o;
}

// ---------------------------------------------------------------------------
extern "C" void kernel_launch(void* const* d_in, const int* in_sizes, int n_in,
                              void* d_out, int out_size, void* d_ws, size_t ws_size,
                              hipStream_t stream) {
  const float* user_w = (const float*)d_in[0];
  const float* item_w = (const float*)d_in[1];
  const float* ent_w  = (const float*)d_in[2];
  const float* rel_w  = (const float*)d_in[3];
  const float* mfeat  = (const float*)d_in[4];
  const float* ufeat  = (const float*)d_in[5];
  const float* me_w1  = (const float*)d_in[6];
  const float* me_b1  = (const float*)d_in[7];
  const float* me_w2  = (const float*)d_in[8];
  const float* me_b2  = (const float*)d_in[9];
  const float* ue_w1  = (const float*)d_in[10];
  const float* ue_b1  = (const float*)d_in[11];
  const float* ue_w2  = (const float*)d_in[12];
  const float* ue_b2  = (const float*)d_in[13];
  const float* cm_vw  = (const float*)d_in[18];
  const float* cm_vb  = (const float*)d_in[19];
  const float* cm_ow  = (const float*)d_in[20];
  const float* cm_ob  = (const float*)d_in[21];
  const float* mg_w   = (const float*)d_in[22];
  const float* mg_b   = (const float*)d_in[23];
  const float* ug_w   = (const float*)d_in[24];
  const float* ug_b   = (const float*)d_in[25];
  const float* gnn_qw = (const float*)d_in[26];
  const float* gnn_qb = (const float*)d_in[27];
  const float* gnn_kw = (const float*)d_in[28];
  const float* gnn_kb = (const float*)d_in[29];
  const float* gnn_vw = (const float*)d_in[30];
  const float* gnn_vb = (const float*)d_in[31];
  const float* la_w   = (const float*)d_in[32];
  const float* la_b   = (const float*)d_in[33];
  const float* adj_d  = (const float*)d_in[34];
  const int*   adj_r  = (const int*)d_in[35];
  const int*   adj_c  = (const int*)d_in[36];
  float* out = (float*)d_out;
  float* ws  = (float*)d_ws;

  // ---- workspace layout (floats) ----
  size_t off = 0;
  float* mm_item = ws + off; off += (size_t)N_ITEMS * D;
  float* mm_user = ws + off; off += (size_t)N_USERS * D;
  float* enc     = ws + off; off += (size_t)N_ITEMS * D;
  float* tmp     = ws + off; off += (size_t)N_ITEMS * D;
  float* emb0    = ws + off; off += (size_t)NTOT * D;
  float* emb1    = ws + off; off += (size_t)NTOT * D;
  float* emb2    = ws + off; off += (size_t)NTOT * D;
  float* side    = ws + off; off += (size_t)NTOT * D;
  float* qn      = ws + off; off += (size_t)NTOT * D;
  float* kn      = ws + off; off += (size_t)NTOT * D;
  float* vn      = ws + off; off += (size_t)NTOT * D;
  float* relmean = ws + off; off += D;
  // bf16 mirrors overlay mm_user/enc/tmp (dead after the fusion stage)
  u16* qb = (u16*)mm_user;
  u16* kb = qb + (size_t)NTOT * D;
  // candidate indices overlay `side` (dead after kn/vn are computed)
  int* cand = (int*)side;

  // ---- modality encoders ----
  k_lin4<<<N_ITEMS / 4, D, 0, stream>>>(mfeat, me_w1, me_b1, nullptr, tmp, nullptr, 768, 1);
  k_lin4<<<N_ITEMS / 4, D, 0, stream>>>(tmp, me_w2, me_b2, nullptr, enc, nullptr, 128, 1);
  k_lin4<<<N_USERS / 4, D, 0, stream>>>(ufeat, ue_w1, ue_b1, nullptr, tmp, nullptr, 512, 1);
  k_lin4<<<N_USERS / 4, D, 0, stream>>>(tmp, ue_w2, ue_b2, nullptr, mm_user, nullptr, 128, 1);
  // ---- collapsed cross-modal attention: mm_item = 2*((enc@vw+vb)@ow+ob) ----
  k_lin4<<<N_ITEMS / 4, D, 0, stream>>>(enc, cm_vw, cm_vb, nullptr, tmp, nullptr, 128, 0);
  k_lin4<<<N_ITEMS / 4, D, 0, stream>>>(tmp, cm_ow, cm_ob, nullptr, mm_item, nullptr, 128, 2);
  // ---- gated fusion -> emb0 ----
  k_gatefuse<<<N_ITEMS, D, 0, stream>>>(item_w, mm_item, mg_w, mg_b, emb0 + (size_t)N_USERS * D);
  k_gatefuse<<<N_USERS, D, 0, stream>>>(user_w, mm_user, ug_w, ug_b, emb0);
  k_copy<<<(N_ENT * D + 255) / 256, 256, 0, stream>>>(ent_w, emb0 + (size_t)(N_USERS + N_ITEMS) * D, N_ENT * D);
  k_relmean<<<1, D, 0, stream>>>(rel_w, relmean);

  // ---- GNN layers ----
  const long long spthreads = (long long)NEDGE * D;
  const int spgrid = (int)((spthreads + 255) / 256);
  const float* eml[3] = {emb0, emb1, emb2};
  for (int l = 0; l < 2; ++l) {
    const float* e = eml[l];
    float* enext   = (float*)eml[l + 1];
    hipMemsetAsync(side, 0, (size_t)NTOT * D * sizeof(float), stream);
    k_spmm<<<spgrid, 256, 0, stream>>>(adj_d, adj_r, adj_c, e, side);
    k_lin4<<<NTOT / 4, D, 0, stream>>>(e,    gnn_qw + (size_t)l * D * D, gnn_qb + (size_t)l * D, nullptr, qn, qb, 128, 0);
    k_lin4<<<NTOT / 4, D, 0, stream>>>(side, gnn_kw + (size_t)l * D * D, gnn_kb + (size_t)l * D, relmean, kn, kb, 128, 0);
    k_lin4<<<NTOT / 4, D, 0, stream>>>(side, gnn_vw + (size_t)l * D * D, gnn_vb + (size_t)l * D, nullptr, vn, nullptr, 128, 0);
    // side is now dead -> reuse as candidate store
    dim3 tkgrid(NTOT / 16, NSLICE);
    k_topk6f<<<tkgrid, 64, 0, stream>>>(qb, kb, cand);
    k_rescore128<<<NTOT, 64, 0, stream>>>(qn, kn, vn, cand, enext);
  }

  // ---- layer aggregation + normalize -> d_out ----
  k_final_norm<<<N_USERS + N_ITEMS, D, 0, stream>>>(emb0, emb1, emb2, la_w, la_b, out);
  // ---- passthrough outputs ----
  k_copy<<<(N_ITEMS * D + 255) / 256, 256, 0, stream>>>(item_w, out + (size_t)(N_USERS + N_ITEMS) * D, N_ITEMS * D);
  k_copy<<<(N_ITEMS * D + 255) / 256, 256, 0, stream>>>(mm_item, out + (size_t)(N_USERS + 2 * N_ITEMS) * D, N_ITEMS * D);
}

// Round 10
// 1615.751 us; speedup vs baseline: 2.1763x; 1.1548x over previous
//
#include <hip/hip_runtime.h>
#include <hip/hip_bf16.h>
#include <math.h>

#define N_USERS 2500
#define N_ITEMS 3000
#define N_ENT   2500
#define NTOT    8000
#define D       128
#define NEDGE   256000
#define NSLICE  8

typedef unsigned short u16;
typedef unsigned int u32;
typedef unsigned long long u64;
typedef __attribute__((ext_vector_type(8))) short short8;
typedef __attribute__((ext_vector_type(4))) float f32x4;

// ---------------------------------------------------------------------------
// Generic 4-rows-per-block linear (unchanged)
// ---------------------------------------------------------------------------
__global__ void k_lin4(const float* __restrict__ A, const float* __restrict__ W,
                       const float* __restrict__ b, const float* __restrict__ ks,
                       float* __restrict__ out, u16* __restrict__ ob, int K, int mode) {
  const int r0 = blockIdx.x * 4;
  const int j  = threadIdx.x;
  const float* __restrict__ a0 = A + (size_t)r0 * K;
  const float* __restrict__ a1 = a0 + K;
  const float* __restrict__ a2 = a1 + K;
  const float* __restrict__ a3 = a2 + K;
  float c0 = 0.f, c1 = 0.f, c2 = 0.f, c3 = 0.f;
  if (ks) {
    for (int k = 0; k < K; ++k) {
      const float w = W[(size_t)k * D + j];
      const float s = ks[k];
      c0 = fmaf(a0[k] * s, w, c0);
      c1 = fmaf(a1[k] * s, w, c1);
      c2 = fmaf(a2[k] * s, w, c2);
      c3 = fmaf(a3[k] * s, w, c3);
    }
  } else {
    for (int k = 0; k < K; ++k) {
      const float w = W[(size_t)k * D + j];
      c0 = fmaf(a0[k], w, c0);
      c1 = fmaf(a1[k], w, c1);
      c2 = fmaf(a2[k], w, c2);
      c3 = fmaf(a3[k], w, c3);
    }
  }
  const float bj = b[j];
  c0 += bj; c1 += bj; c2 += bj; c3 += bj;
  if (mode == 1) {
    c0 = fmaxf(c0, 0.f); c1 = fmaxf(c1, 0.f); c2 = fmaxf(c2, 0.f); c3 = fmaxf(c3, 0.f);
  } else if (mode == 2) {
    c0 *= 2.f; c1 *= 2.f; c2 *= 2.f; c3 *= 2.f;
  }
  float* __restrict__ o = out + (size_t)r0 * D + j;
  o[0] = c0; o[D] = c1; o[2 * D] = c2; o[3 * D] = c3;
  if (ob) {
    __hip_bfloat16 h0 = __float2bfloat16(c0), h1 = __float2bfloat16(c1);
    __hip_bfloat16 h2 = __float2bfloat16(c2), h3 = __float2bfloat16(c3);
    u16* __restrict__ p = ob + (size_t)r0 * D + j;
    p[0]     = *reinterpret_cast<u16*>(&h0);
    p[D]     = *reinterpret_cast<u16*>(&h1);
    p[2 * D] = *reinterpret_cast<u16*>(&h2);
    p[3 * D] = *reinterpret_cast<u16*>(&h3);
  }
}

// ---------------------------------------------------------------------------
// Gated fusion (unchanged)
// ---------------------------------------------------------------------------
__global__ void k_gatefuse(const float* __restrict__ base, const float* __restrict__ mm,
                           const float* __restrict__ gw, const float* __restrict__ gb,
                           float* __restrict__ embout) {
  const int r = blockIdx.x;
  const int j = threadIdx.x;
  const float* __restrict__ b0 = base + (size_t)r * D;
  const float* __restrict__ m0 = mm + (size_t)r * D;
  float acc = 0.f;
  for (int k = 0; k < D; ++k) acc = fmaf(b0[k], gw[(size_t)k * D + j], acc);
  for (int k = 0; k < D; ++k) acc = fmaf(m0[k], gw[(size_t)(D + k) * D + j], acc);
  acc += gb[j];
  const float s1 = 1.f / (1.f + expf(-acc));
  const float g  = 1.f / (1.f + expf(-(s1 * 2.f)));
  const float bv = b0[j], mv = m0[j];
  embout[(size_t)r * D + j] = g * bv + (1.f - g) * mv + 0.1f * bv;
}

__global__ void k_relmean(const float* __restrict__ rel, float* __restrict__ out) {
  const int j = threadIdx.x;
  float s = 0.f;
  for (int i = 0; i < 32; ++i) s += rel[i * D + j];
  out[j] = s * (1.f / 32.f);
}

__global__ void k_copy(const float* __restrict__ src, float* __restrict__ dst, int n) {
  const int t = blockIdx.x * blockDim.x + threadIdx.x;
  if (t < n) dst[t] = src[t];
}

// ---------------------------------------------------------------------------
// side[row] += data * e[col]  via f32 atomics (unchanged)
// ---------------------------------------------------------------------------
__global__ void k_spmm(const float* __restrict__ dat, const int* __restrict__ rw,
                       const int* __restrict__ cl, const float* __restrict__ e,
                       float* __restrict__ side) {
  const long long t = (long long)blockIdx.x * blockDim.x + threadIdx.x;
  if (t >= (long long)NEDGE * D) return;
  const int ei = (int)(t >> 7);
  const int d  = (int)(t & 127);
  const float v = dat[ei] * e[(size_t)cl[ei] * D + d];
  atomicAdd(side + (size_t)rw[ei] * D + d, v);
}

// ---------------------------------------------------------------------------
// bf16-MFMA score scan, 8 column slices, shuffle-free selection.
// r10 = r8's PROVEN kernel with ONLY the merge phase changed:
//   scan/bubble: verbatim r8 (float score, int col, reference comparator).
//   merge: survivors packed ONCE to exact u64 keys at LDS-store time,
//     kk = (mono(score) << 32) | (0xFFFFFFFF - col),
//     mono(b) = b ^ ((b>>31)|0x80000000)   [exact, order-preserving]
//   u64 '>' is order-isomorphic to (score desc, col asc). Keys are ONLY
//   compared, never decoded: the cand write uses c[r][j] directly.
// This halves the merge compare cost and bisects r9's failure: if this
// passes, r9's bug was in its u64 scan bubble; if it fails, packed-key
// LDS compare is the broken half and we revert to full r8.
// ---------------------------------------------------------------------------
__global__ __launch_bounds__(64) void k_topk6h(const u16* __restrict__ qb,
                                               const u16* __restrict__ kb,
                                               int* __restrict__ cand) {
  __shared__ u64 km[16][101];
  const int lane = threadIdx.x;
  const int rbase = blockIdx.x * 16;
  const int sl   = blockIdx.y;
  const int colL = lane & 15;
  const int kofs = (lane >> 4) * 8;

  short8 aF[4];
  {
    const u16* ap = qb + (size_t)(rbase + colL) * D + kofs;
#pragma unroll
    for (int t = 0; t < 4; ++t) aF[t] = *reinterpret_cast<const short8*>(ap + t * 32);
  }

  float s[4][6]; int c[4][6];
#pragma unroll
  for (int r = 0; r < 4; ++r)
#pragma unroll
    for (int j = 0; j < 6; ++j) { s[r][j] = -3.0e38f; c[r][j] = 0x40000000 + colL * 6 + j; }

  // 500 tiles split 63,63,63,63,62,62,62,62
  const int tile0  = sl * 62 + (sl < 4 ? sl : 4);
  const int ntiles = 62 + (sl < 4 ? 1 : 0);
  const u16* bb = kb + (size_t)(tile0 * 16 + colL) * D + kofs;

  short8 bF[4];
#pragma unroll
  for (int t = 0; t < 4; ++t) bF[t] = *reinterpret_cast<const short8*>(bb + t * 32);

  for (int ct = 0; ct < ntiles; ++ct) {
    const int cn = (ct + 1 < ntiles) ? ct + 1 : ct;
    const u16* nb = bb + (size_t)cn * 16 * D;
    short8 bN[4];
#pragma unroll
    for (int t = 0; t < 4; ++t) bN[t] = *reinterpret_cast<const short8*>(nb + t * 32);

    f32x4 acc = {0.f, 0.f, 0.f, 0.f};
#pragma unroll
    for (int t = 0; t < 4; ++t)
      acc = __builtin_amdgcn_mfma_f32_16x16x32_bf16(aF[t], bF[t], acc, 0, 0, 0);

    const int colIdx = (tile0 + ct) * 16 + colL;
#pragma unroll
    for (int r = 0; r < 4; ++r) {
      float ks = acc[r]; int kc = colIdx;
      if (ks > s[r][5] || (ks == s[r][5] && kc < c[r][5])) {
#pragma unroll
        for (int i = 0; i < 6; ++i) {   // bubble (ks,kc) into sorted-desc list
          const bool bgt = (ks > s[r][i]) || (ks == s[r][i] && kc < c[r][i]);
          const float os = s[r][i]; const int oc = c[r][i];
          s[r][i] = bgt ? ks : os;  c[r][i] = bgt ? kc : oc;
          ks      = bgt ? os : ks;  kc      = bgt ? oc : kc;
        }
      }
    }

#pragma unroll
    for (int t = 0; t < 4; ++t) bF[t] = bN[t];
  }

  // ---- pack survivors to exact u64 keys; LDS rank-merge ----
  u64 kk[4][6];
#pragma unroll
  for (int r = 0; r < 4; ++r)
#pragma unroll
    for (int j = 0; j < 6; ++j) {
      const u32 b = __builtin_bit_cast(u32, s[r][j]);
      const u32 mono = b ^ ((u32)(((int)b) >> 31) | 0x80000000u);
      kk[r][j] = ((u64)mono << 32) | (u64)(0xFFFFFFFFu - (u32)c[r][j]);
      km[(lane >> 4) * 4 + r][colL * 6 + j] = kk[r][j];
    }
  __syncthreads();

#pragma unroll
  for (int r = 0; r < 4; ++r) {
    const int row4 = (lane >> 4) * 4 + r;
    int cnt[6] = {0, 0, 0, 0, 0, 0};
    for (int q2 = 0; q2 < 96; ++q2) {
      const u64 o = km[row4][q2];
#pragma unroll
      for (int j = 0; j < 6; ++j) cnt[j] += (o > kk[r][j]) ? 1 : 0;
    }
    const int row = rbase + row4;
#pragma unroll
    for (int j = 0; j < 6; ++j)
      if (cnt[j] < 16)
        cand[(size_t)row * 128 + sl * 16 + cnt[j]] = c[r][j];
  }
}

// ---------------------------------------------------------------------------
// Exact f32 rescore of 128 candidates (2/lane), true top-16 by (value, lower
// index), softmax, gather vn. One wave per row. (unchanged from r8)
// ---------------------------------------------------------------------------
__global__ __launch_bounds__(64) void k_rescore128(const float* __restrict__ qn,
                                                   const float* __restrict__ kn,
                                                   const float* __restrict__ vn,
                                                   const int* __restrict__ cand,
                                                   float* __restrict__ enext) {
  const int row = blockIdx.x;
  const int lane = threadIdx.x;
  const int* cr = cand + (size_t)row * 128;
  const int c0 = cr[lane];
  const int c1 = cr[64 + lane];

  const float4* __restrict__ q4  = (const float4*)(qn + (size_t)row * D);
  const float4* __restrict__ k40 = (const float4*)(kn + (size_t)c0 * D);
  const float4* __restrict__ k41 = (const float4*)(kn + (size_t)c1 * D);
  float s0 = 0.f, s1 = 0.f;
#pragma unroll 8
  for (int j = 0; j < 32; ++j) {
    const float4 qv = q4[j];
    const float4 a = k40[j], b = k41[j];
    s0 = fmaf(qv.x, a.x, s0); s0 = fmaf(qv.y, a.y, s0);
    s0 = fmaf(qv.z, a.z, s0); s0 = fmaf(qv.w, a.w, s0);
    s1 = fmaf(qv.x, b.x, s1); s1 = fmaf(qv.y, b.y, s1);
    s1 = fmaf(qv.z, b.z, s1); s1 = fmaf(qv.w, b.w, s1);
  }
  const float inv = 0.088388347648318447f;   // 1/sqrt(128)
  s0 *= inv; s1 *= inv;

  // rank among 128 by (value desc, index asc); indices are unique
  int r0 = 0, r1 = 0;
  for (int j = 0; j < 64; ++j) {
    const float t0 = __shfl(s0, j), t1 = __shfl(s1, j);
    const int   u0 = __shfl(c0, j), u1 = __shfl(c1, j);
    r0 += (t0 > s0 || (t0 == s0 && u0 < c0)) ? 1 : 0;
    r0 += (t1 > s0 || (t1 == s0 && u1 < c0)) ? 1 : 0;
    r1 += (t0 > s1 || (t0 == s1 && u0 < c1)) ? 1 : 0;
    r1 += (t1 > s1 || (t1 == s1 && u1 < c1)) ? 1 : 0;
  }
  const bool sel0 = r0 < 16, sel1 = r1 < 16;

  float v = fmaxf(sel0 ? s0 : -3.0e38f, sel1 ? s1 : -3.0e38f);
#pragma unroll
  for (int d2 = 1; d2 < 64; d2 <<= 1) v = fmaxf(v, __shfl_xor(v, d2));
  const float e0 = sel0 ? expf(s0 - v) : 0.f;
  const float e1 = sel1 ? expf(s1 - v) : 0.f;
  float Z = e0 + e1;
#pragma unroll
  for (int d2 = 1; d2 < 64; d2 <<= 1) Z += __shfl_xor(Z, d2);
  const float w0 = e0 / Z, w1 = e1 / Z;

  float a0 = 0.f, a1 = 0.f;
  unsigned long long b0 = __ballot(sel0);
  while (b0) {
    const int src = __ffsll(b0) - 1; b0 &= b0 - 1;
    const float wj = __shfl(w0, src);
    const int   cj = __shfl(c0, src);
    const float* __restrict__ vr = vn + (size_t)cj * D;
    a0 = fmaf(wj, vr[lane], a0);
    a1 = fmaf(wj, vr[64 + lane], a1);
  }
  unsigned long long b1 = __ballot(sel1);
  while (b1) {
    const int src = __ffsll(b1) - 1; b1 &= b1 - 1;
    const float wj = __shfl(w1, src);
    const int   cj = __shfl(c1, src);
    const float* __restrict__ vr = vn + (size_t)cj * D;
    a0 = fmaf(wj, vr[lane], a0);
    a1 = fmaf(wj, vr[64 + lane], a1);
  }
  enext[(size_t)row * D + lane]      = fmaxf(a0, 0.f);
  enext[(size_t)row * D + 64 + lane] = fmaxf(a1, 0.f);
}

// ---------------------------------------------------------------------------
// final = [e0|e1|e2] @ la_w + la_b, row-L2-normalized (unchanged)
// ---------------------------------------------------------------------------
__global__ void k_final_norm(const float* __restrict__ e0, const float* __restrict__ e1,
                             const float* __restrict__ e2, const float* __restrict__ law,
                             const float* __restrict__ lab, float* __restrict__ out) {
  __shared__ float red[128];
  const int r = blockIdx.x;
  const int j = threadIdx.x;
  const float* __restrict__ a0 = e0 + (size_t)r * D;
  const float* __restrict__ a1 = e1 + (size_t)r * D;
  const float* __restrict__ a2 = e2 + (size_t)r * D;
  float acc = lab[j];
  for (int k = 0; k < D; ++k) acc = fmaf(a0[k], law[(size_t)k * D + j], acc);
  for (int k = 0; k < D; ++k) acc = fmaf(a1[k], law[(size_t)(D + k) * D + j], acc);
  for (int k = 0; k < D; ++k) acc = fmaf(a2[k], law[(size_t)(2 * D + k) * D + j], acc);
  red[j] = acc * acc;
  __syncthreads();
  for (int st = 64; st > 0; st >>= 1) {
    if (j < st) red[j] += red[j + st];
    __syncthreads();
  }
  const float nrm = fmaxf(sqrtf(red[0]), 1e-12f);
  const float o = acc / nrm;
  if (r < N_USERS) out[(size_t)r * D + j] = o;
  else             out[(size_t)N_USERS * D + (size_t)(r - N_USERS) * D + j] = o;
}

// ---------------------------------------------------------------------------
extern "C" void kernel_launch(void* const* d_in, const int* in_sizes, int n_in,
                              void* d_out, int out_size, void* d_ws, size_t ws_size,
                              hipStream_t stream) {
  const float* user_w = (const float*)d_in[0];
  const float* item_w = (const float*)d_in[1];
  const float* ent_w  = (const float*)d_in[2];
  const float* rel_w  = (const float*)d_in[3];
  const float* mfeat  = (const float*)d_in[4];
  const float* ufeat  = (const float*)d_in[5];
  const float* me_w1  = (const float*)d_in[6];
  const float* me_b1  = (const float*)d_in[7];
  const float* me_w2  = (const float*)d_in[8];
  const float* me_b2  = (const float*)d_in[9];
  const float* ue_w1  = (const float*)d_in[10];
  const float* ue_b1  = (const float*)d_in[11];
  const float* ue_w2  = (const float*)d_in[12];
  const float* ue_b2  = (const float*)d_in[13];
  const float* cm_vw  = (const float*)d_in[18];
  const float* cm_vb  = (const float*)d_in[19];
  const float* cm_ow  = (const float*)d_in[20];
  const float* cm_ob  = (const float*)d_in[21];
  const float* mg_w   = (const float*)d_in[22];
  const float* mg_b   = (const float*)d_in[23];
  const float* ug_w   = (const float*)d_in[24];
  const float* ug_b   = (const float*)d_in[25];
  const float* gnn_qw = (const float*)d_in[26];
  const float* gnn_qb = (const float*)d_in[27];
  const float* gnn_kw = (const float*)d_in[28];
  const float* gnn_kb = (const float*)d_in[29];
  const float* gnn_vw = (const float*)d_in[30];
  const float* gnn_vb = (const float*)d_in[31];
  const float* la_w   = (const float*)d_in[32];
  const float* la_b   = (const float*)d_in[33];
  const float* adj_d  = (const float*)d_in[34];
  const int*   adj_r  = (const int*)d_in[35];
  const int*   adj_c  = (const int*)d_in[36];
  float* out = (float*)d_out;
  float* ws  = (float*)d_ws;

  // ---- workspace layout (floats) ----
  size_t off = 0;
  float* mm_item = ws + off; off += (size_t)N_ITEMS * D;
  float* mm_user = ws + off; off += (size_t)N_USERS * D;
  float* enc     = ws + off; off += (size_t)N_ITEMS * D;
  float* tmp     = ws + off; off += (size_t)N_ITEMS * D;
  float* emb0    = ws + off; off += (size_t)NTOT * D;
  float* emb1    = ws + off; off += (size_t)NTOT * D;
  float* emb2    = ws + off; off += (size_t)NTOT * D;
  float* side    = ws + off; off += (size_t)NTOT * D;
  float* qn      = ws + off; off += (size_t)NTOT * D;
  float* kn      = ws + off; off += (size_t)NTOT * D;
  float* vn      = ws + off; off += (size_t)NTOT * D;
  float* relmean = ws + off; off += D;
  // bf16 mirrors overlay mm_user/enc/tmp (dead after the fusion stage)
  u16* qb = (u16*)mm_user;
  u16* kb = qb + (size_t)NTOT * D;
  // candidate indices overlay `side` (dead after kn/vn are computed)
  int* cand = (int*)side;

  // ---- modality encoders ----
  k_lin4<<<N_ITEMS / 4, D, 0, stream>>>(mfeat, me_w1, me_b1, nullptr, tmp, nullptr, 768, 1);
  k_lin4<<<N_ITEMS / 4, D, 0, stream>>>(tmp, me_w2, me_b2, nullptr, enc, nullptr, 128, 1);
  k_lin4<<<N_USERS / 4, D, 0, stream>>>(ufeat, ue_w1, ue_b1, nullptr, tmp, nullptr, 512, 1);
  k_lin4<<<N_USERS / 4, D, 0, stream>>>(tmp, ue_w2, ue_b2, nullptr, mm_user, nullptr, 128, 1);
  // ---- collapsed cross-modal attention: mm_item = 2*((enc@vw+vb)@ow+ob) ----
  k_lin4<<<N_ITEMS / 4, D, 0, stream>>>(enc, cm_vw, cm_vb, nullptr, tmp, nullptr, 128, 0);
  k_lin4<<<N_ITEMS / 4, D, 0, stream>>>(tmp, cm_ow, cm_ob, nullptr, mm_item, nullptr, 128, 2);
  // ---- gated fusion -> emb0 ----
  k_gatefuse<<<N_ITEMS, D, 0, stream>>>(item_w, mm_item, mg_w, mg_b, emb0 + (size_t)N_USERS * D);
  k_gatefuse<<<N_USERS, D, 0, stream>>>(user_w, mm_user, ug_w, ug_b, emb0);
  k_copy<<<(N_ENT * D + 255) / 256, 256, 0, stream>>>(ent_w, emb0 + (size_t)(N_USERS + N_ITEMS) * D, N_ENT * D);
  k_relmean<<<1, D, 0, stream>>>(rel_w, relmean);

  // ---- GNN layers ----
  const long long spthreads = (long long)NEDGE * D;
  const int spgrid = (int)((spthreads + 255) / 256);
  const float* eml[3] = {emb0, emb1, emb2};
  for (int l = 0; l < 2; ++l) {
    const float* e = eml[l];
    float* enext   = (float*)eml[l + 1];
    hipMemsetAsync(side, 0, (size_t)NTOT * D * sizeof(float), stream);
    k_spmm<<<spgrid, 256, 0, stream>>>(adj_d, adj_r, adj_c, e, side);
    k_lin4<<<NTOT / 4, D, 0, stream>>>(e,    gnn_qw + (size_t)l * D * D, gnn_qb + (size_t)l * D, nullptr, qn, qb, 128, 0);
    k_lin4<<<NTOT / 4, D, 0, stream>>>(side, gnn_kw + (size_t)l * D * D, gnn_kb + (size_t)l * D, relmean, kn, kb, 128, 0);
    k_lin4<<<NTOT / 4, D, 0, stream>>>(side, gnn_vw + (size_t)l * D * D, gnn_vb + (size_t)l * D, nullptr, vn, nullptr, 128, 0);
    // side is now dead -> reuse as candidate store
    dim3 tkgrid(NTOT / 16, NSLICE);
    k_topk6h<<<tkgrid, 64, 0, stream>>>(qb, kb, cand);
    k_rescore128<<<NTOT, 64, 0, stream>>>(qn, kn, vn, cand, enext);
  }

  // ---- layer aggregation + normalize -> d_out ----
  k_final_norm<<<N_USERS + N_ITEMS, D, 0, stream>>>(emb0, emb1, emb2, la_w, la_b, out);
  // ---- passthrough outputs ----
  k_copy<<<(N_ITEMS * D + 255) / 256, 256, 0, stream>>>(item_w, out + (size_t)(N_USERS + N_ITEMS) * D, N_ITEMS * D);
  k_copy<<<(N_ITEMS * D + 255) / 256, 256, 0, stream>>>(mm_item, out + (size_t)(N_USERS + 2 * N_ITEMS) * D, N_ITEMS * D);
}

// Round 11
// 1413.225 us; speedup vs baseline: 2.4882x; 1.1433x over previous
//
#include <hip/hip_runtime.h>
#include <hip/hip_bf16.h>
#include <math.h>

#define N_USERS 2500
#define N_ITEMS 3000
#define N_ENT   2500
#define NTOT    8000
#define D       128
#define NEDGE   256000
#define NSLICE  8

typedef unsigned short u16;
typedef unsigned int u32;
typedef unsigned long long u64;
typedef __attribute__((ext_vector_type(8))) short short8;
typedef __attribute__((ext_vector_type(4))) float f32x4;

static __device__ __forceinline__ u16 bf16bits(float x) {
  __hip_bfloat16 h = __float2bfloat16(x);
  return *reinterpret_cast<u16*>(&h);
}

// ---------------------------------------------------------------------------
// W pre-split: W[K][128] (f32, optional row scale ks[k]) -> three bf16 planes
// stored TRANSPOSED: wsg[p*128*K + j*K + k], p in {0,1,2}.
// a = a1+a2+a3 exact 3-way bf16 split (rel err ~2^-27).
// ---------------------------------------------------------------------------
__global__ void k_wsplit(const float* __restrict__ W, const float* __restrict__ ks,
                         u16* __restrict__ wsg, int K) {
  const int e = blockIdx.x * 256 + threadIdx.x;
  if (e >= K * 128) return;
  const int k = e >> 7, j = e & 127;
  float x = W[(size_t)k * 128 + j];
  if (ks) x *= ks[k];
  const __hip_bfloat16 h1 = __float2bfloat16(x);
  const float r1 = x - __bfloat162float(h1);
  const __hip_bfloat16 h2 = __float2bfloat16(r1);
  const float r2 = r1 - __bfloat162float(h2);
  const __hip_bfloat16 h3 = __float2bfloat16(r2);
  const size_t base = (size_t)j * K + k;
  wsg[base]                   = *(const u16*)&h1;
  wsg[(size_t)128 * K + base] = *(const u16*)&h2;
  wsg[(size_t)256 * K + base] = *(const u16*)&h3;
}

// ---------------------------------------------------------------------------
// MFMA GEMM, f32-accurate via 3xbf16 splits (6 MFMA per 16x16x32 tile).
// out[M][128] = act(A[M][K] @ Wsplit + b). Block = 256 thr = 4 waves; each
// wave owns 16 rows x 128 cols. B frags read straight from the L2-resident
// transposed split planes with the SAME lane<->(row,k) mapping as A (this
// pairing is end-to-end verified by the r4-r10 topk path).
// mode: 0 none, 1 relu, 2 x2. ob: optional bf16 mirror.
// ---------------------------------------------------------------------------
__global__ __launch_bounds__(256) void k_gemm3(const float* __restrict__ A,
                                               const u16* __restrict__ wsg,
                                               const float* __restrict__ b,
                                               float* __restrict__ out,
                                               u16* __restrict__ ob,
                                               int M, int K, int mode) {
  const int tid  = threadIdx.x;
  const int lane = tid & 63;
  const int wave = tid >> 6;
  const int rbase = blockIdx.x * 64 + wave * 16;
  const int colL = lane & 15;
  const int kofs = (lane >> 4) * 8;

  f32x4 acc[8];
#pragma unroll
  for (int ct = 0; ct < 8; ++ct) acc[ct] = (f32x4){0.f, 0.f, 0.f, 0.f};

  const int arow = (rbase + colL < M) ? (rbase + colL) : (M - 1);
  const float* __restrict__ arp = A + (size_t)arow * K;

  for (int k0 = 0; k0 < K; k0 += 32) {
    // ---- A fragment: 8 f32 -> 3 bf16x8 splits ----
    const float4 f0 = *(const float4*)(arp + k0 + kofs);
    const float4 f1 = *(const float4*)(arp + k0 + kofs + 4);
    float av[8] = {f0.x, f0.y, f0.z, f0.w, f1.x, f1.y, f1.z, f1.w};
    short8 a1, a2, a3;
#pragma unroll
    for (int e = 0; e < 8; ++e) {
      const float x = av[e];
      const __hip_bfloat16 h1 = __float2bfloat16(x);
      const float r1 = x - __bfloat162float(h1);
      const __hip_bfloat16 h2 = __float2bfloat16(r1);
      const float r2 = r1 - __bfloat162float(h2);
      const __hip_bfloat16 h3 = __float2bfloat16(r2);
      a1[e] = *(const short*)&h1;
      a2[e] = *(const short*)&h2;
      a3[e] = *(const short*)&h3;
    }
    // ---- B frags + 6-term MFMA per col tile ----
#pragma unroll
    for (int ct = 0; ct < 8; ++ct) {
      const int j = ct * 16 + colL;
      const u16* wp = wsg + (size_t)j * K + k0 + kofs;
      const short8 b1 = *(const short8*)wp;
      const short8 b2 = *(const short8*)(wp + (size_t)128 * K);
      const short8 b3 = *(const short8*)(wp + (size_t)256 * K);
      acc[ct] = __builtin_amdgcn_mfma_f32_16x16x32_bf16(a1, b1, acc[ct], 0, 0, 0);
      acc[ct] = __builtin_amdgcn_mfma_f32_16x16x32_bf16(a1, b2, acc[ct], 0, 0, 0);
      acc[ct] = __builtin_amdgcn_mfma_f32_16x16x32_bf16(a2, b1, acc[ct], 0, 0, 0);
      acc[ct] = __builtin_amdgcn_mfma_f32_16x16x32_bf16(a2, b2, acc[ct], 0, 0, 0);
      acc[ct] = __builtin_amdgcn_mfma_f32_16x16x32_bf16(a1, b3, acc[ct], 0, 0, 0);
      acc[ct] = __builtin_amdgcn_mfma_f32_16x16x32_bf16(a3, b1, acc[ct], 0, 0, 0);
    }
  }

  // ---- epilogue: bias + mode + stores (C layout: col=lane&15, row=(lane>>4)*4+r) ----
#pragma unroll
  for (int ct = 0; ct < 8; ++ct) {
    const int j = ct * 16 + colL;
    const float bj = b[j];
#pragma unroll
    for (int r = 0; r < 4; ++r) {
      const int row = rbase + (lane >> 4) * 4 + r;
      if (row < M) {
        float c = acc[ct][r] + bj;
        if (mode == 1) c = fmaxf(c, 0.f);
        else if (mode == 2) c *= 2.f;
        out[(size_t)row * 128 + j] = c;
        if (ob) ob[(size_t)row * 128 + j] = bf16bits(c);
      }
    }
  }
}

// ---------------------------------------------------------------------------
// Gated fusion (unchanged)
// ---------------------------------------------------------------------------
__global__ void k_gatefuse(const float* __restrict__ base, const float* __restrict__ mm,
                           const float* __restrict__ gw, const float* __restrict__ gb,
                           float* __restrict__ embout) {
  const int r = blockIdx.x;
  const int j = threadIdx.x;
  const float* __restrict__ b0 = base + (size_t)r * D;
  const float* __restrict__ m0 = mm + (size_t)r * D;
  float acc = 0.f;
  for (int k = 0; k < D; ++k) acc = fmaf(b0[k], gw[(size_t)k * D + j], acc);
  for (int k = 0; k < D; ++k) acc = fmaf(m0[k], gw[(size_t)(D + k) * D + j], acc);
  acc += gb[j];
  const float s1 = 1.f / (1.f + expf(-acc));
  const float g  = 1.f / (1.f + expf(-(s1 * 2.f)));
  const float bv = b0[j], mv = m0[j];
  embout[(size_t)r * D + j] = g * bv + (1.f - g) * mv + 0.1f * bv;
}

__global__ void k_relmean(const float* __restrict__ rel, float* __restrict__ out) {
  const int j = threadIdx.x;
  float s = 0.f;
  for (int i = 0; i < 32; ++i) s += rel[i * D + j];
  out[j] = s * (1.f / 32.f);
}

__global__ void k_copy(const float* __restrict__ src, float* __restrict__ dst, int n) {
  const int t = blockIdx.x * blockDim.x + threadIdx.x;
  if (t < n) dst[t] = src[t];
}

// ---------------------------------------------------------------------------
// side[row] += data * e[col]  via f32 atomics (unchanged)
// ---------------------------------------------------------------------------
__global__ void k_spmm(const float* __restrict__ dat, const int* __restrict__ rw,
                       const int* __restrict__ cl, const float* __restrict__ e,
                       float* __restrict__ side) {
  const long long t = (long long)blockIdx.x * blockDim.x + threadIdx.x;
  if (t >= (long long)NEDGE * D) return;
  const int ei = (int)(t >> 7);
  const int d  = (int)(t & 127);
  const float v = dat[ei] * e[(size_t)cl[ei] * D + d];
  atomicAdd(side + (size_t)rw[ei] * D + d, v);
}

// ---------------------------------------------------------------------------
// bf16-MFMA score scan + shuffle-free top selection (r10 version, PROVEN):
// f32 scan bubble, u64 packed-key LDS rank-merge, cand from c[] directly.
// ---------------------------------------------------------------------------
__global__ __launch_bounds__(64) void k_topk6h(const u16* __restrict__ qb,
                                               const u16* __restrict__ kb,
                                               int* __restrict__ cand) {
  __shared__ u64 km[16][101];
  const int lane = threadIdx.x;
  const int rbase = blockIdx.x * 16;
  const int sl   = blockIdx.y;
  const int colL = lane & 15;
  const int kofs = (lane >> 4) * 8;

  short8 aF[4];
  {
    const u16* ap = qb + (size_t)(rbase + colL) * D + kofs;
#pragma unroll
    for (int t = 0; t < 4; ++t) aF[t] = *reinterpret_cast<const short8*>(ap + t * 32);
  }

  float s[4][6]; int c[4][6];
#pragma unroll
  for (int r = 0; r < 4; ++r)
#pragma unroll
    for (int j = 0; j < 6; ++j) { s[r][j] = -3.0e38f; c[r][j] = 0x40000000 + colL * 6 + j; }

  // 500 tiles split 63,63,63,63,62,62,62,62
  const int tile0  = sl * 62 + (sl < 4 ? sl : 4);
  const int ntiles = 62 + (sl < 4 ? 1 : 0);
  const u16* bb = kb + (size_t)(tile0 * 16 + colL) * D + kofs;

  short8 bF[4];
#pragma unroll
  for (int t = 0; t < 4; ++t) bF[t] = *reinterpret_cast<const short8*>(bb + t * 32);

  for (int ct = 0; ct < ntiles; ++ct) {
    const int cn = (ct + 1 < ntiles) ? ct + 1 : ct;
    const u16* nb = bb + (size_t)cn * 16 * D;
    short8 bN[4];
#pragma unroll
    for (int t = 0; t < 4; ++t) bN[t] = *reinterpret_cast<const short8*>(nb + t * 32);

    f32x4 acc = {0.f, 0.f, 0.f, 0.f};
#pragma unroll
    for (int t = 0; t < 4; ++t)
      acc = __builtin_amdgcn_mfma_f32_16x16x32_bf16(aF[t], bF[t], acc, 0, 0, 0);

    const int colIdx = (tile0 + ct) * 16 + colL;
#pragma unroll
    for (int r = 0; r < 4; ++r) {
      float ks = acc[r]; int kc = colIdx;
      if (ks > s[r][5] || (ks == s[r][5] && kc < c[r][5])) {
#pragma unroll
        for (int i = 0; i < 6; ++i) {   // bubble (ks,kc) into sorted-desc list
          const bool bgt = (ks > s[r][i]) || (ks == s[r][i] && kc < c[r][i]);
          const float os = s[r][i]; const int oc = c[r][i];
          s[r][i] = bgt ? ks : os;  c[r][i] = bgt ? kc : oc;
          ks      = bgt ? os : ks;  kc      = bgt ? oc : kc;
        }
      }
    }

#pragma unroll
    for (int t = 0; t < 4; ++t) bF[t] = bN[t];
  }

  // ---- pack survivors to exact u64 keys; LDS rank-merge ----
  u64 kk[4][6];
#pragma unroll
  for (int r = 0; r < 4; ++r)
#pragma unroll
    for (int j = 0; j < 6; ++j) {
      const u32 b = __builtin_bit_cast(u32, s[r][j]);
      const u32 mono = b ^ ((u32)(((int)b) >> 31) | 0x80000000u);
      kk[r][j] = ((u64)mono << 32) | (u64)(0xFFFFFFFFu - (u32)c[r][j]);
      km[(lane >> 4) * 4 + r][colL * 6 + j] = kk[r][j];
    }
  __syncthreads();

#pragma unroll
  for (int r = 0; r < 4; ++r) {
    const int row4 = (lane >> 4) * 4 + r;
    int cnt[6] = {0, 0, 0, 0, 0, 0};
    for (int q2 = 0; q2 < 96; ++q2) {
      const u64 o = km[row4][q2];
#pragma unroll
      for (int j = 0; j < 6; ++j) cnt[j] += (o > kk[r][j]) ? 1 : 0;
    }
    const int row = rbase + row4;
#pragma unroll
    for (int j = 0; j < 6; ++j)
      if (cnt[j] < 16)
        cand[(size_t)row * 128 + sl * 16 + cnt[j]] = c[r][j];
  }
}

// ---------------------------------------------------------------------------
// Exact f32 rescore of 128 candidates (2/lane), true top-16 by (value, lower
// index), softmax, gather vn. One wave per row. (unchanged)
// ---------------------------------------------------------------------------
__global__ __launch_bounds__(64) void k_rescore128(const float* __restrict__ qn,
                                                   const float* __restrict__ kn,
                                                   const float* __restrict__ vn,
                                                   const int* __restrict__ cand,
                                                   float* __restrict__ enext) {
  const int row = blockIdx.x;
  const int lane = threadIdx.x;
  const int* cr = cand + (size_t)row * 128;
  const int c0 = cr[lane];
  const int c1 = cr[64 + lane];

  const float4* __restrict__ q4  = (const float4*)(qn + (size_t)row * D);
  const float4* __restrict__ k40 = (const float4*)(kn + (size_t)c0 * D);
  const float4* __restrict__ k41 = (const float4*)(kn + (size_t)c1 * D);
  float s0 = 0.f, s1 = 0.f;
#pragma unroll 8
  for (int j = 0; j < 32; ++j) {
    const float4 qv = q4[j];
    const float4 a = k40[j], b = k41[j];
    s0 = fmaf(qv.x, a.x, s0); s0 = fmaf(qv.y, a.y, s0);
    s0 = fmaf(qv.z, a.z, s0); s0 = fmaf(qv.w, a.w, s0);
    s1 = fmaf(qv.x, b.x, s1); s1 = fmaf(qv.y, b.y, s1);
    s1 = fmaf(qv.z, b.z, s1); s1 = fmaf(qv.w, b.w, s1);
  }
  const float inv = 0.088388347648318447f;   // 1/sqrt(128)
  s0 *= inv; s1 *= inv;

  // rank among 128 by (value desc, index asc); indices are unique
  int r0 = 0, r1 = 0;
  for (int j = 0; j < 64; ++j) {
    const float t0 = __shfl(s0, j), t1 = __shfl(s1, j);
    const int   u0 = __shfl(c0, j), u1 = __shfl(c1, j);
    r0 += (t0 > s0 || (t0 == s0 && u0 < c0)) ? 1 : 0;
    r0 += (t1 > s0 || (t1 == s0 && u1 < c0)) ? 1 : 0;
    r1 += (t0 > s1 || (t0 == s1 && u0 < c1)) ? 1 : 0;
    r1 += (t1 > s1 || (t1 == s1 && u1 < c1)) ? 1 : 0;
  }
  const bool sel0 = r0 < 16, sel1 = r1 < 16;

  float v = fmaxf(sel0 ? s0 : -3.0e38f, sel1 ? s1 : -3.0e38f);
#pragma unroll
  for (int d2 = 1; d2 < 64; d2 <<= 1) v = fmaxf(v, __shfl_xor(v, d2));
  const float e0 = sel0 ? expf(s0 - v) : 0.f;
  const float e1 = sel1 ? expf(s1 - v) : 0.f;
  float Z = e0 + e1;
#pragma unroll
  for (int d2 = 1; d2 < 64; d2 <<= 1) Z += __shfl_xor(Z, d2);
  const float w0 = e0 / Z, w1 = e1 / Z;

  float a0 = 0.f, a1 = 0.f;
  unsigned long long b0 = __ballot(sel0);
  while (b0) {
    const int src = __ffsll(b0) - 1; b0 &= b0 - 1;
    const float wj = __shfl(w0, src);
    const int   cj = __shfl(c0, src);
    const float* __restrict__ vr = vn + (size_t)cj * D;
    a0 = fmaf(wj, vr[lane], a0);
    a1 = fmaf(wj, vr[64 + lane], a1);
  }
  unsigned long long b1 = __ballot(sel1);
  while (b1) {
    const int src = __ffsll(b1) - 1; b1 &= b1 - 1;
    const float wj = __shfl(w1, src);
    const int   cj = __shfl(c1, src);
    const float* __restrict__ vr = vn + (size_t)cj * D;
    a0 = fmaf(wj, vr[lane], a0);
    a1 = fmaf(wj, vr[64 + lane], a1);
  }
  enext[(size_t)row * D + lane]      = fmaxf(a0, 0.f);
  enext[(size_t)row * D + 64 + lane] = fmaxf(a1, 0.f);
}

// ---------------------------------------------------------------------------
// final = [e0|e1|e2] @ la_w + la_b, row-L2-normalized (unchanged)
// ---------------------------------------------------------------------------
__global__ void k_final_norm(const float* __restrict__ e0, const float* __restrict__ e1,
                             const float* __restrict__ e2, const float* __restrict__ law,
                             const float* __restrict__ lab, float* __restrict__ out) {
  __shared__ float red[128];
  const int r = blockIdx.x;
  const int j = threadIdx.x;
  const float* __restrict__ a0 = e0 + (size_t)r * D;
  const float* __restrict__ a1 = e1 + (size_t)r * D;
  const float* __restrict__ a2 = e2 + (size_t)r * D;
  float acc = lab[j];
  for (int k = 0; k < D; ++k) acc = fmaf(a0[k], law[(size_t)k * D + j], acc);
  for (int k = 0; k < D; ++k) acc = fmaf(a1[k], law[(size_t)(D + k) * D + j], acc);
  for (int k = 0; k < D; ++k) acc = fmaf(a2[k], law[(size_t)(2 * D + k) * D + j], acc);
  red[j] = acc * acc;
  __syncthreads();
  for (int st = 64; st > 0; st >>= 1) {
    if (j < st) red[j] += red[j + st];
    __syncthreads();
  }
  const float nrm = fmaxf(sqrtf(red[0]), 1e-12f);
  const float o = acc / nrm;
  if (r < N_USERS) out[(size_t)r * D + j] = o;
  else             out[(size_t)N_USERS * D + (size_t)(r - N_USERS) * D + j] = o;
}

// ---------------------------------------------------------------------------
extern "C" void kernel_launch(void* const* d_in, const int* in_sizes, int n_in,
                              void* d_out, int out_size, void* d_ws, size_t ws_size,
                              hipStream_t stream) {
  const float* user_w = (const float*)d_in[0];
  const float* item_w = (const float*)d_in[1];
  const float* ent_w  = (const float*)d_in[2];
  const float* rel_w  = (const float*)d_in[3];
  const float* mfeat  = (const float*)d_in[4];
  const float* ufeat  = (const float*)d_in[5];
  const float* me_w1  = (const float*)d_in[6];
  const float* me_b1  = (const float*)d_in[7];
  const float* me_w2  = (const float*)d_in[8];
  const float* me_b2  = (const float*)d_in[9];
  const float* ue_w1  = (const float*)d_in[10];
  const float* ue_b1  = (const float*)d_in[11];
  const float* ue_w2  = (const float*)d_in[12];
  const float* ue_b2  = (const float*)d_in[13];
  const float* cm_vw  = (const float*)d_in[18];
  const float* cm_vb  = (const float*)d_in[19];
  const float* cm_ow  = (const float*)d_in[20];
  const float* cm_ob  = (const float*)d_in[21];
  const float* mg_w   = (const float*)d_in[22];
  const float* mg_b   = (const float*)d_in[23];
  const float* ug_w   = (const float*)d_in[24];
  const float* ug_b   = (const float*)d_in[25];
  const float* gnn_qw = (const float*)d_in[26];
  const float* gnn_qb = (const float*)d_in[27];
  const float* gnn_kw = (const float*)d_in[28];
  const float* gnn_kb = (const float*)d_in[29];
  const float* gnn_vw = (const float*)d_in[30];
  const float* gnn_vb = (const float*)d_in[31];
  const float* la_w   = (const float*)d_in[32];
  const float* la_b   = (const float*)d_in[33];
  const float* adj_d  = (const float*)d_in[34];
  const int*   adj_r  = (const int*)d_in[35];
  const int*   adj_c  = (const int*)d_in[36];
  float* out = (float*)d_out;
  float* ws  = (float*)d_ws;

  // ---- workspace layout (floats) ----
  size_t off = 0;
  float* mm_item = ws + off; off += (size_t)N_ITEMS * D;
  float* mm_user = ws + off; off += (size_t)N_USERS * D;
  float* enc     = ws + off; off += (size_t)N_ITEMS * D;
  float* tmp     = ws + off; off += (size_t)N_ITEMS * D;
  float* emb0    = ws + off; off += (size_t)NTOT * D;
  float* emb1    = ws + off; off += (size_t)NTOT * D;
  float* emb2    = ws + off; off += (size_t)NTOT * D;
  float* side    = ws + off; off += (size_t)NTOT * D;
  float* qn      = ws + off; off += (size_t)NTOT * D;
  float* kn      = ws + off; off += (size_t)NTOT * D;
  float* vn      = ws + off; off += (size_t)NTOT * D;
  float* relmean = ws + off; off += D;
  // W split triplet scratch (max K=768): 768*128*3 u16 = 147456 f32 slots
  u16* wsg = (u16*)(ws + off); off += 147456;
  // bf16 mirrors overlay mm_user/enc/tmp (dead after the fusion stage)
  u16* qb = (u16*)mm_user;
  u16* kb = qb + (size_t)NTOT * D;
  // candidate indices overlay `side` (dead after kn/vn are computed)
  int* cand = (int*)side;

  // ---- modality encoders (MFMA 3xbf16 GEMMs) ----
  k_wsplit<<<(768 * 128 + 255) / 256, 256, 0, stream>>>(me_w1, nullptr, wsg, 768);
  k_gemm3<<<(3000 + 63) / 64, 256, 0, stream>>>(mfeat, wsg, me_b1, tmp, nullptr, 3000, 768, 1);
  k_wsplit<<<(128 * 128 + 255) / 256, 256, 0, stream>>>(me_w2, nullptr, wsg, 128);
  k_gemm3<<<(3000 + 63) / 64, 256, 0, stream>>>(tmp, wsg, me_b2, enc, nullptr, 3000, 128, 1);
  k_wsplit<<<(512 * 128 + 255) / 256, 256, 0, stream>>>(ue_w1, nullptr, wsg, 512);
  k_gemm3<<<(2500 + 63) / 64, 256, 0, stream>>>(ufeat, wsg, ue_b1, tmp, nullptr, 2500, 512, 1);
  k_wsplit<<<(128 * 128 + 255) / 256, 256, 0, stream>>>(ue_w2, nullptr, wsg, 128);
  k_gemm3<<<(2500 + 63) / 64, 256, 0, stream>>>(tmp, wsg, ue_b2, mm_user, nullptr, 2500, 128, 1);
  // ---- collapsed cross-modal attention: mm_item = 2*((enc@vw+vb)@ow+ob) ----
  k_wsplit<<<(128 * 128 + 255) / 256, 256, 0, stream>>>(cm_vw, nullptr, wsg, 128);
  k_gemm3<<<(3000 + 63) / 64, 256, 0, stream>>>(enc, wsg, cm_vb, tmp, nullptr, 3000, 128, 0);
  k_wsplit<<<(128 * 128 + 255) / 256, 256, 0, stream>>>(cm_ow, nullptr, wsg, 128);
  k_gemm3<<<(3000 + 63) / 64, 256, 0, stream>>>(tmp, wsg, cm_ob, mm_item, nullptr, 3000, 128, 2);
  // ---- gated fusion -> emb0 ----
  k_gatefuse<<<N_ITEMS, D, 0, stream>>>(item_w, mm_item, mg_w, mg_b, emb0 + (size_t)N_USERS * D);
  k_gatefuse<<<N_USERS, D, 0, stream>>>(user_w, mm_user, ug_w, ug_b, emb0);
  k_copy<<<(N_ENT * D + 255) / 256, 256, 0, stream>>>(ent_w, emb0 + (size_t)(N_USERS + N_ITEMS) * D, N_ENT * D);
  k_relmean<<<1, D, 0, stream>>>(rel_w, relmean);

  // ---- GNN layers ----
  const long long spthreads = (long long)NEDGE * D;
  const int spgrid = (int)((spthreads + 255) / 256);
  const float* eml[3] = {emb0, emb1, emb2};
  for (int l = 0; l < 2; ++l) {
    const float* e = eml[l];
    float* enext   = (float*)eml[l + 1];
    hipMemsetAsync(side, 0, (size_t)NTOT * D * sizeof(float), stream);
    k_spmm<<<spgrid, 256, 0, stream>>>(adj_d, adj_r, adj_c, e, side);
    k_wsplit<<<(128 * 128 + 255) / 256, 256, 0, stream>>>(gnn_qw + (size_t)l * D * D, nullptr, wsg, 128);
    k_gemm3<<<(NTOT + 63) / 64, 256, 0, stream>>>(e, wsg, gnn_qb + (size_t)l * D, qn, qb, NTOT, 128, 0);
    k_wsplit<<<(128 * 128 + 255) / 256, 256, 0, stream>>>(gnn_kw + (size_t)l * D * D, relmean, wsg, 128);
    k_gemm3<<<(NTOT + 63) / 64, 256, 0, stream>>>(side, wsg, gnn_kb + (size_t)l * D, kn, kb, NTOT, 128, 0);
    k_wsplit<<<(128 * 128 + 255) / 256, 256, 0, stream>>>(gnn_vw + (size_t)l * D * D, nullptr, wsg, 128);
    k_gemm3<<<(NTOT + 63) / 64, 256, 0, stream>>>(side, wsg, gnn_vb + (size_t)l * D, vn, nullptr, NTOT, 128, 0);
    // side is now dead -> reuse as candidate store
    dim3 tkgrid(NTOT / 16, NSLICE);
    k_topk6h<<<tkgrid, 64, 0, stream>>>(qb, kb, cand);
    k_rescore128<<<NTOT, 64, 0, stream>>>(qn, kn, vn, cand, enext);
  }

  // ---- layer aggregation + normalize -> d_out ----
  k_final_norm<<<N_USERS + N_ITEMS, D, 0, stream>>>(emb0, emb1, emb2, la_w, la_b, out);
  // ---- passthrough outputs ----
  k_copy<<<(N_ITEMS * D + 255) / 256, 256, 0, stream>>>(item_w, out + (size_t)(N_USERS + N_ITEMS) * D, N_ITEMS * D);
  k_copy<<<(N_ITEMS * D + 255) / 256, 256, 0, stream>>>(mm_item, out + (size_t)(N_USERS + 2 * N_ITEMS) * D, N_ITEMS * D);
}

// Round 12
// 1297.181 us; speedup vs baseline: 2.7108x; 1.0895x over previous
//
#include <hip/hip_runtime.h>
#include <hip/hip_bf16.h>
#include <math.h>

#define N_USERS 2500
#define N_ITEMS 3000
#define N_ENT   2500
#define NTOT    8000
#define D       128
#define NEDGE   256000
#define NSLICE  8

typedef unsigned short u16;
typedef unsigned int u32;
typedef unsigned long long u64;
typedef __attribute__((ext_vector_type(8))) short short8;
typedef __attribute__((ext_vector_type(4))) float f32x4;

static __device__ __forceinline__ u16 bf16bits(float x) {
  __hip_bfloat16 h = __float2bfloat16(x);
  return *reinterpret_cast<u16*>(&h);
}

// ---------------------------------------------------------------------------
// W pre-split: W[K][128] (f32, optional row scale ks[k]) -> three bf16 planes
// stored TRANSPOSED: wsg[p*128*K + j*K + k], p in {0,1,2}.
// ---------------------------------------------------------------------------
__global__ void k_wsplit(const float* __restrict__ W, const float* __restrict__ ks,
                         u16* __restrict__ wsg, int K) {
  const int e = blockIdx.x * 256 + threadIdx.x;
  if (e >= K * 128) return;
  const int k = e >> 7, j = e & 127;
  float x = W[(size_t)k * 128 + j];
  if (ks) x *= ks[k];
  const __hip_bfloat16 h1 = __float2bfloat16(x);
  const float r1 = x - __bfloat162float(h1);
  const __hip_bfloat16 h2 = __float2bfloat16(r1);
  const float r2 = r1 - __bfloat162float(h2);
  const __hip_bfloat16 h3 = __float2bfloat16(r2);
  const size_t base = (size_t)j * K + k;
  wsg[base]                   = *(const u16*)&h1;
  wsg[(size_t)128 * K + base] = *(const u16*)&h2;
  wsg[(size_t)256 * K + base] = *(const u16*)&h3;
}

// ---------------------------------------------------------------------------
// MFMA GEMM, f32-accurate via 3xbf16 splits (6 MFMA per 16x16x32 tile).
// (unchanged from r11 — verified)
// ---------------------------------------------------------------------------
__global__ __launch_bounds__(256) void k_gemm3(const float* __restrict__ A,
                                               const u16* __restrict__ wsg,
                                               const float* __restrict__ b,
                                               float* __restrict__ out,
                                               u16* __restrict__ ob,
                                               int M, int K, int mode) {
  const int tid  = threadIdx.x;
  const int lane = tid & 63;
  const int wave = tid >> 6;
  const int rbase = blockIdx.x * 64 + wave * 16;
  const int colL = lane & 15;
  const int kofs = (lane >> 4) * 8;

  f32x4 acc[8];
#pragma unroll
  for (int ct = 0; ct < 8; ++ct) acc[ct] = (f32x4){0.f, 0.f, 0.f, 0.f};

  const int arow = (rbase + colL < M) ? (rbase + colL) : (M - 1);
  const float* __restrict__ arp = A + (size_t)arow * K;

  for (int k0 = 0; k0 < K; k0 += 32) {
    const float4 f0 = *(const float4*)(arp + k0 + kofs);
    const float4 f1 = *(const float4*)(arp + k0 + kofs + 4);
    float av[8] = {f0.x, f0.y, f0.z, f0.w, f1.x, f1.y, f1.z, f1.w};
    short8 a1, a2, a3;
#pragma unroll
    for (int e = 0; e < 8; ++e) {
      const float x = av[e];
      const __hip_bfloat16 h1 = __float2bfloat16(x);
      const float r1 = x - __bfloat162float(h1);
      const __hip_bfloat16 h2 = __float2bfloat16(r1);
      const float r2 = r1 - __bfloat162float(h2);
      const __hip_bfloat16 h3 = __float2bfloat16(r2);
      a1[e] = *(const short*)&h1;
      a2[e] = *(const short*)&h2;
      a3[e] = *(const short*)&h3;
    }
#pragma unroll
    for (int ct = 0; ct < 8; ++ct) {
      const int j = ct * 16 + colL;
      const u16* wp = wsg + (size_t)j * K + k0 + kofs;
      const short8 b1 = *(const short8*)wp;
      const short8 b2 = *(const short8*)(wp + (size_t)128 * K);
      const short8 b3 = *(const short8*)(wp + (size_t)256 * K);
      acc[ct] = __builtin_amdgcn_mfma_f32_16x16x32_bf16(a1, b1, acc[ct], 0, 0, 0);
      acc[ct] = __builtin_amdgcn_mfma_f32_16x16x32_bf16(a1, b2, acc[ct], 0, 0, 0);
      acc[ct] = __builtin_amdgcn_mfma_f32_16x16x32_bf16(a2, b1, acc[ct], 0, 0, 0);
      acc[ct] = __builtin_amdgcn_mfma_f32_16x16x32_bf16(a2, b2, acc[ct], 0, 0, 0);
      acc[ct] = __builtin_amdgcn_mfma_f32_16x16x32_bf16(a1, b3, acc[ct], 0, 0, 0);
      acc[ct] = __builtin_amdgcn_mfma_f32_16x16x32_bf16(a3, b1, acc[ct], 0, 0, 0);
    }
  }

#pragma unroll
  for (int ct = 0; ct < 8; ++ct) {
    const int j = ct * 16 + colL;
    const float bj = b[j];
#pragma unroll
    for (int r = 0; r < 4; ++r) {
      const int row = rbase + (lane >> 4) * 4 + r;
      if (row < M) {
        float c = acc[ct][r] + bj;
        if (mode == 1) c = fmaxf(c, 0.f);
        else if (mode == 2) c *= 2.f;
        out[(size_t)row * 128 + j] = c;
        if (ob) ob[(size_t)row * 128 + j] = bf16bits(c);
      }
    }
  }
}

// ---------------------------------------------------------------------------
// Gated fusion (unchanged)
// ---------------------------------------------------------------------------
__global__ void k_gatefuse(const float* __restrict__ base, const float* __restrict__ mm,
                           const float* __restrict__ gw, const float* __restrict__ gb,
                           float* __restrict__ embout) {
  const int r = blockIdx.x;
  const int j = threadIdx.x;
  const float* __restrict__ b0 = base + (size_t)r * D;
  const float* __restrict__ m0 = mm + (size_t)r * D;
  float acc = 0.f;
  for (int k = 0; k < D; ++k) acc = fmaf(b0[k], gw[(size_t)k * D + j], acc);
  for (int k = 0; k < D; ++k) acc = fmaf(m0[k], gw[(size_t)(D + k) * D + j], acc);
  acc += gb[j];
  const float s1 = 1.f / (1.f + expf(-acc));
  const float g  = 1.f / (1.f + expf(-(s1 * 2.f)));
  const float bv = b0[j], mv = m0[j];
  embout[(size_t)r * D + j] = g * bv + (1.f - g) * mv + 0.1f * bv;
}

__global__ void k_relmean(const float* __restrict__ rel, float* __restrict__ out) {
  const int j = threadIdx.x;
  float s = 0.f;
  for (int i = 0; i < 32; ++i) s += rel[i * D + j];
  out[j] = s * (1.f / 32.f);
}

__global__ void k_copy(const float* __restrict__ src, float* __restrict__ dst, int n) {
  const int t = blockIdx.x * blockDim.x + threadIdx.x;
  if (t < n) dst[t] = src[t];
}

// ---------------------------------------------------------------------------
// side[row] += data * e[col]  via f32 atomics (unchanged)
// ---------------------------------------------------------------------------
__global__ void k_spmm(const float* __restrict__ dat, const int* __restrict__ rw,
                       const int* __restrict__ cl, const float* __restrict__ e,
                       float* __restrict__ side) {
  const long long t = (long long)blockIdx.x * blockDim.x + threadIdx.x;
  if (t >= (long long)NEDGE * D) return;
  const int ei = (int)(t >> 7);
  const int d  = (int)(t & 127);
  const float v = dat[ei] * e[(size_t)cl[ei] * D + d];
  atomicAdd(side + (size_t)rw[ei] * D + d, v);
}

// ---------------------------------------------------------------------------
// bf16-MFMA score scan + shuffle-free top selection.
// r12 restructure of the proven r10 kernel for OCCUPANCY:
//  - 4 waves/block (256 thr), grid (500, 2); wave w handles slice
//    sl = blockIdx.y*4 + w. Same 4000 (row-group, slice) waves total.
//  - two-phase merge reusing an 8-row per-wave LDS buffer: lanes 0-31
//    (rows 0-7) write+rank, barrier, lanes 32-63 (rows 8-15). LDS/block
//    = 4 waves x 8 x 97 x 8B = 24.8 KB -> 6 blocks/CU = 24 waves/CU
//    (vs 12 one-wave blocks at 13 KB each before).
//  - scan bubble comparator is SCORE-ONLY (bitwise-f32-tie at the exact
//    6th-slot boundary is a ~1e-7 event; merge keys keep the exact col
//    tie-break and rescore is exact, so semantics are preserved).
// Merge itself is r10's proven u64 packed-key linear rank.
// ---------------------------------------------------------------------------
__global__ __launch_bounds__(256) void k_topk6v(const u16* __restrict__ qb,
                                                const u16* __restrict__ kb,
                                                int* __restrict__ cand) {
  __shared__ u64 km[4][8][97];
  const int tid  = threadIdx.x;
  const int lane = tid & 63;
  const int wave = tid >> 6;
  const int rbase = blockIdx.x * 16;
  const int sl   = blockIdx.y * 4 + wave;
  const int colL = lane & 15;
  const int g    = lane >> 4;
  const int kofs = g * 8;

  short8 aF[4];
  {
    const u16* ap = qb + (size_t)(rbase + colL) * D + kofs;
#pragma unroll
    for (int t = 0; t < 4; ++t) aF[t] = *reinterpret_cast<const short8*>(ap + t * 32);
  }

  float s[4][6]; int c[4][6];
#pragma unroll
  for (int r = 0; r < 4; ++r)
#pragma unroll
    for (int j = 0; j < 6; ++j) { s[r][j] = -3.0e38f; c[r][j] = 0x40000000 + colL * 6 + j; }

  // 500 tiles split 63,63,63,63,62,62,62,62
  const int tile0  = sl * 62 + (sl < 4 ? sl : 4);
  const int ntiles = 62 + (sl < 4 ? 1 : 0);
  const u16* bb = kb + (size_t)(tile0 * 16 + colL) * D + kofs;

  short8 bF[4];
#pragma unroll
  for (int t = 0; t < 4; ++t) bF[t] = *reinterpret_cast<const short8*>(bb + t * 32);

  for (int ct = 0; ct < ntiles; ++ct) {
    const int cn = (ct + 1 < ntiles) ? ct + 1 : ct;
    const u16* nb = bb + (size_t)cn * 16 * D;
    short8 bN[4];
#pragma unroll
    for (int t = 0; t < 4; ++t) bN[t] = *reinterpret_cast<const short8*>(nb + t * 32);

    f32x4 acc = {0.f, 0.f, 0.f, 0.f};
#pragma unroll
    for (int t = 0; t < 4; ++t)
      acc = __builtin_amdgcn_mfma_f32_16x16x32_bf16(aF[t], bF[t], acc, 0, 0, 0);

    const int colIdx = (tile0 + ct) * 16 + colL;
#pragma unroll
    for (int r = 0; r < 4; ++r) {
      float ks = acc[r]; int kc = colIdx;
      if (ks > s[r][5]) {                 // score-only gate + bubble
#pragma unroll
        for (int i = 0; i < 6; ++i) {
          const bool bgt = ks > s[r][i];
          const float os = s[r][i]; const int oc = c[r][i];
          s[r][i] = bgt ? ks : os;  c[r][i] = bgt ? kc : oc;
          ks      = bgt ? os : ks;  kc      = bgt ? oc : kc;
        }
      }
    }

#pragma unroll
    for (int t = 0; t < 4; ++t) bF[t] = bN[t];
  }

  // ---- pack survivors to exact u64 keys (score desc, col asc order) ----
  u64 kk[4][6];
#pragma unroll
  for (int r = 0; r < 4; ++r)
#pragma unroll
    for (int j = 0; j < 6; ++j) {
      const u32 b = __builtin_bit_cast(u32, s[r][j]);
      const u32 mono = b ^ ((u32)(((int)b) >> 31) | 0x80000000u);
      kk[r][j] = ((u64)mono << 32) | (u64)(0xFFFFFFFFu - (u32)c[r][j]);
    }

  // ---- phase A: rows 0-7 (lanes 0-31) ----
  if (g < 2) {
#pragma unroll
    for (int r = 0; r < 4; ++r)
#pragma unroll
      for (int j = 0; j < 6; ++j)
        km[wave][4 * g + r][colL * 6 + j] = kk[r][j];
  }
  __syncthreads();
  if (g < 2) {
#pragma unroll
    for (int r = 0; r < 4; ++r) {
      int cnt[6] = {0, 0, 0, 0, 0, 0};
      for (int q2 = 0; q2 < 96; ++q2) {
        const u64 o = km[wave][4 * g + r][q2];
#pragma unroll
        for (int j = 0; j < 6; ++j) cnt[j] += (o > kk[r][j]) ? 1 : 0;
      }
      const int row = rbase + 4 * g + r;
#pragma unroll
      for (int j = 0; j < 6; ++j)
        if (cnt[j] < 16)
          cand[(size_t)row * 128 + sl * 16 + cnt[j]] = c[r][j];
    }
  }
  __syncthreads();
  // ---- phase B: rows 8-15 (lanes 32-63), reuse the same buffer ----
  if (g >= 2) {
#pragma unroll
    for (int r = 0; r < 4; ++r)
#pragma unroll
      for (int j = 0; j < 6; ++j)
        km[wave][4 * (g - 2) + r][colL * 6 + j] = kk[r][j];
  }
  __syncthreads();
  if (g >= 2) {
#pragma unroll
    for (int r = 0; r < 4; ++r) {
      int cnt[6] = {0, 0, 0, 0, 0, 0};
      for (int q2 = 0; q2 < 96; ++q2) {
        const u64 o = km[wave][4 * (g - 2) + r][q2];
#pragma unroll
        for (int j = 0; j < 6; ++j) cnt[j] += (o > kk[r][j]) ? 1 : 0;
      }
      const int row = rbase + 4 * g + r;
#pragma unroll
      for (int j = 0; j < 6; ++j)
        if (cnt[j] < 16)
          cand[(size_t)row * 128 + sl * 16 + cnt[j]] = c[r][j];
    }
  }
}

// ---------------------------------------------------------------------------
// Exact f32 rescore of 128 candidates (2/lane), true top-16 by (value, lower
// index), softmax, gather vn. One wave per row. (unchanged)
// ---------------------------------------------------------------------------
__global__ __launch_bounds__(64) void k_rescore128(const float* __restrict__ qn,
                                                   const float* __restrict__ kn,
                                                   const float* __restrict__ vn,
                                                   const int* __restrict__ cand,
                                                   float* __restrict__ enext) {
  const int row = blockIdx.x;
  const int lane = threadIdx.x;
  const int* cr = cand + (size_t)row * 128;
  const int c0 = cr[lane];
  const int c1 = cr[64 + lane];

  const float4* __restrict__ q4  = (const float4*)(qn + (size_t)row * D);
  const float4* __restrict__ k40 = (const float4*)(kn + (size_t)c0 * D);
  const float4* __restrict__ k41 = (const float4*)(kn + (size_t)c1 * D);
  float s0 = 0.f, s1 = 0.f;
#pragma unroll 8
  for (int j = 0; j < 32; ++j) {
    const float4 qv = q4[j];
    const float4 a = k40[j], b = k41[j];
    s0 = fmaf(qv.x, a.x, s0); s0 = fmaf(qv.y, a.y, s0);
    s0 = fmaf(qv.z, a.z, s0); s0 = fmaf(qv.w, a.w, s0);
    s1 = fmaf(qv.x, b.x, s1); s1 = fmaf(qv.y, b.y, s1);
    s1 = fmaf(qv.z, b.z, s1); s1 = fmaf(qv.w, b.w, s1);
  }
  const float inv = 0.088388347648318447f;   // 1/sqrt(128)
  s0 *= inv; s1 *= inv;

  // rank among 128 by (value desc, index asc); indices are unique
  int r0 = 0, r1 = 0;
  for (int j = 0; j < 64; ++j) {
    const float t0 = __shfl(s0, j), t1 = __shfl(s1, j);
    const int   u0 = __shfl(c0, j), u1 = __shfl(c1, j);
    r0 += (t0 > s0 || (t0 == s0 && u0 < c0)) ? 1 : 0;
    r0 += (t1 > s0 || (t1 == s0 && u1 < c0)) ? 1 : 0;
    r1 += (t0 > s1 || (t0 == s1 && u0 < c1)) ? 1 : 0;
    r1 += (t1 > s1 || (t1 == s1 && u1 < c1)) ? 1 : 0;
  }
  const bool sel0 = r0 < 16, sel1 = r1 < 16;

  float v = fmaxf(sel0 ? s0 : -3.0e38f, sel1 ? s1 : -3.0e38f);
#pragma unroll
  for (int d2 = 1; d2 < 64; d2 <<= 1) v = fmaxf(v, __shfl_xor(v, d2));
  const float e0 = sel0 ? expf(s0 - v) : 0.f;
  const float e1 = sel1 ? expf(s1 - v) : 0.f;
  float Z = e0 + e1;
#pragma unroll
  for (int d2 = 1; d2 < 64; d2 <<= 1) Z += __shfl_xor(Z, d2);
  const float w0 = e0 / Z, w1 = e1 / Z;

  float a0 = 0.f, a1 = 0.f;
  unsigned long long b0 = __ballot(sel0);
  while (b0) {
    const int src = __ffsll(b0) - 1; b0 &= b0 - 1;
    const float wj = __shfl(w0, src);
    const int   cj = __shfl(c0, src);
    const float* __restrict__ vr = vn + (size_t)cj * D;
    a0 = fmaf(wj, vr[lane], a0);
    a1 = fmaf(wj, vr[64 + lane], a1);
  }
  unsigned long long b1 = __ballot(sel1);
  while (b1) {
    const int src = __ffsll(b1) - 1; b1 &= b1 - 1;
    const float wj = __shfl(w1, src);
    const int   cj = __shfl(c1, src);
    const float* __restrict__ vr = vn + (size_t)cj * D;
    a0 = fmaf(wj, vr[lane], a0);
    a1 = fmaf(wj, vr[64 + lane], a1);
  }
  enext[(size_t)row * D + lane]      = fmaxf(a0, 0.f);
  enext[(size_t)row * D + 64 + lane] = fmaxf(a1, 0.f);
}

// ---------------------------------------------------------------------------
// final = [e0|e1|e2] @ la_w + la_b, row-L2-normalized (unchanged)
// ---------------------------------------------------------------------------
__global__ void k_final_norm(const float* __restrict__ e0, const float* __restrict__ e1,
                             const float* __restrict__ e2, const float* __restrict__ law,
                             const float* __restrict__ lab, float* __restrict__ out) {
  __shared__ float red[128];
  const int r = blockIdx.x;
  const int j = threadIdx.x;
  const float* __restrict__ a0 = e0 + (size_t)r * D;
  const float* __restrict__ a1 = e1 + (size_t)r * D;
  const float* __restrict__ a2 = e2 + (size_t)r * D;
  float acc = lab[j];
  for (int k = 0; k < D; ++k) acc = fmaf(a0[k], law[(size_t)k * D + j], acc);
  for (int k = 0; k < D; ++k) acc = fmaf(a1[k], law[(size_t)(D + k) * D + j], acc);
  for (int k = 0; k < D; ++k) acc = fmaf(a2[k], law[(size_t)(2 * D + k) * D + j], acc);
  red[j] = acc * acc;
  __syncthreads();
  for (int st = 64; st > 0; st >>= 1) {
    if (j < st) red[j] += red[j + st];
    __syncthreads();
  }
  const float nrm = fmaxf(sqrtf(red[0]), 1e-12f);
  const float o = acc / nrm;
  if (r < N_USERS) out[(size_t)r * D + j] = o;
  else             out[(size_t)N_USERS * D + (size_t)(r - N_USERS) * D + j] = o;
}

// ---------------------------------------------------------------------------
extern "C" void kernel_launch(void* const* d_in, const int* in_sizes, int n_in,
                              void* d_out, int out_size, void* d_ws, size_t ws_size,
                              hipStream_t stream) {
  const float* user_w = (const float*)d_in[0];
  const float* item_w = (const float*)d_in[1];
  const float* ent_w  = (const float*)d_in[2];
  const float* rel_w  = (const float*)d_in[3];
  const float* mfeat  = (const float*)d_in[4];
  const float* ufeat  = (const float*)d_in[5];
  const float* me_w1  = (const float*)d_in[6];
  const float* me_b1  = (const float*)d_in[7];
  const float* me_w2  = (const float*)d_in[8];
  const float* me_b2  = (const float*)d_in[9];
  const float* ue_w1  = (const float*)d_in[10];
  const float* ue_b1  = (const float*)d_in[11];
  const float* ue_w2  = (const float*)d_in[12];
  const float* ue_b2  = (const float*)d_in[13];
  const float* cm_vw  = (const float*)d_in[18];
  const float* cm_vb  = (const float*)d_in[19];
  const float* cm_ow  = (const float*)d_in[20];
  const float* cm_ob  = (const float*)d_in[21];
  const float* mg_w   = (const float*)d_in[22];
  const float* mg_b   = (const float*)d_in[23];
  const float* ug_w   = (const float*)d_in[24];
  const float* ug_b   = (const float*)d_in[25];
  const float* gnn_qw = (const float*)d_in[26];
  const float* gnn_qb = (const float*)d_in[27];
  const float* gnn_kw = (const float*)d_in[28];
  const float* gnn_kb = (const float*)d_in[29];
  const float* gnn_vw = (const float*)d_in[30];
  const float* gnn_vb = (const float*)d_in[31];
  const float* la_w   = (const float*)d_in[32];
  const float* la_b   = (const float*)d_in[33];
  const float* adj_d  = (const float*)d_in[34];
  const int*   adj_r  = (const int*)d_in[35];
  const int*   adj_c  = (const int*)d_in[36];
  float* out = (float*)d_out;
  float* ws  = (float*)d_ws;

  // ---- workspace layout (floats) ----
  size_t off = 0;
  float* mm_item = ws + off; off += (size_t)N_ITEMS * D;
  float* mm_user = ws + off; off += (size_t)N_USERS * D;
  float* enc     = ws + off; off += (size_t)N_ITEMS * D;
  float* tmp     = ws + off; off += (size_t)N_ITEMS * D;
  float* emb0    = ws + off; off += (size_t)NTOT * D;
  float* emb1    = ws + off; off += (size_t)NTOT * D;
  float* emb2    = ws + off; off += (size_t)NTOT * D;
  float* side    = ws + off; off += (size_t)NTOT * D;
  float* qn      = ws + off; off += (size_t)NTOT * D;
  float* kn      = ws + off; off += (size_t)NTOT * D;
  float* vn      = ws + off; off += (size_t)NTOT * D;
  float* relmean = ws + off; off += D;
  // W split triplet scratch (max K=768): 768*128*3 u16 = 147456 f32 slots
  u16* wsg = (u16*)(ws + off); off += 147456;
  // bf16 mirrors overlay mm_user/enc/tmp (dead after the fusion stage)
  u16* qb = (u16*)mm_user;
  u16* kb = qb + (size_t)NTOT * D;
  // candidate indices overlay `side` (dead after kn/vn are computed)
  int* cand = (int*)side;

  // ---- modality encoders (MFMA 3xbf16 GEMMs) ----
  k_wsplit<<<(768 * 128 + 255) / 256, 256, 0, stream>>>(me_w1, nullptr, wsg, 768);
  k_gemm3<<<(3000 + 63) / 64, 256, 0, stream>>>(mfeat, wsg, me_b1, tmp, nullptr, 3000, 768, 1);
  k_wsplit<<<(128 * 128 + 255) / 256, 256, 0, stream>>>(me_w2, nullptr, wsg, 128);
  k_gemm3<<<(3000 + 63) / 64, 256, 0, stream>>>(tmp, wsg, me_b2, enc, nullptr, 3000, 128, 1);
  k_wsplit<<<(512 * 128 + 255) / 256, 256, 0, stream>>>(ue_w1, nullptr, wsg, 512);
  k_gemm3<<<(2500 + 63) / 64, 256, 0, stream>>>(ufeat, wsg, ue_b1, tmp, nullptr, 2500, 512, 1);
  k_wsplit<<<(128 * 128 + 255) / 256, 256, 0, stream>>>(ue_w2, nullptr, wsg, 128);
  k_gemm3<<<(2500 + 63) / 64, 256, 0, stream>>>(tmp, wsg, ue_b2, mm_user, nullptr, 2500, 128, 1);
  // ---- collapsed cross-modal attention: mm_item = 2*((enc@vw+vb)@ow+ob) ----
  k_wsplit<<<(128 * 128 + 255) / 256, 256, 0, stream>>>(cm_vw, nullptr, wsg, 128);
  k_gemm3<<<(3000 + 63) / 64, 256, 0, stream>>>(enc, wsg, cm_vb, tmp, nullptr, 3000, 128, 0);
  k_wsplit<<<(128 * 128 + 255) / 256, 256, 0, stream>>>(cm_ow, nullptr, wsg, 128);
  k_gemm3<<<(3000 + 63) / 64, 256, 0, stream>>>(tmp, wsg, cm_ob, mm_item, nullptr, 3000, 128, 2);
  // ---- gated fusion -> emb0 ----
  k_gatefuse<<<N_ITEMS, D, 0, stream>>>(item_w, mm_item, mg_w, mg_b, emb0 + (size_t)N_USERS * D);
  k_gatefuse<<<N_USERS, D, 0, stream>>>(user_w, mm_user, ug_w, ug_b, emb0);
  k_copy<<<(N_ENT * D + 255) / 256, 256, 0, stream>>>(ent_w, emb0 + (size_t)(N_USERS + N_ITEMS) * D, N_ENT * D);
  k_relmean<<<1, D, 0, stream>>>(rel_w, relmean);

  // ---- GNN layers ----
  const long long spthreads = (long long)NEDGE * D;
  const int spgrid = (int)((spthreads + 255) / 256);
  const float* eml[3] = {emb0, emb1, emb2};
  for (int l = 0; l < 2; ++l) {
    const float* e = eml[l];
    float* enext   = (float*)eml[l + 1];
    hipMemsetAsync(side, 0, (size_t)NTOT * D * sizeof(float), stream);
    k_spmm<<<spgrid, 256, 0, stream>>>(adj_d, adj_r, adj_c, e, side);
    k_wsplit<<<(128 * 128 + 255) / 256, 256, 0, stream>>>(gnn_qw + (size_t)l * D * D, nullptr, wsg, 128);
    k_gemm3<<<(NTOT + 63) / 64, 256, 0, stream>>>(e, wsg, gnn_qb + (size_t)l * D, qn, qb, NTOT, 128, 0);
    k_wsplit<<<(128 * 128 + 255) / 256, 256, 0, stream>>>(gnn_kw + (size_t)l * D * D, relmean, wsg, 128);
    k_gemm3<<<(NTOT + 63) / 64, 256, 0, stream>>>(side, wsg, gnn_kb + (size_t)l * D, kn, kb, NTOT, 128, 0);
    k_wsplit<<<(128 * 128 + 255) / 256, 256, 0, stream>>>(gnn_vw + (size_t)l * D * D, nullptr, wsg, 128);
    k_gemm3<<<(NTOT + 63) / 64, 256, 0, stream>>>(side, wsg, gnn_vb + (size_t)l * D, vn, nullptr, NTOT, 128, 0);
    // side is now dead -> reuse as candidate store
    dim3 tkgrid(NTOT / 16, 2);
    k_topk6v<<<tkgrid, 256, 0, stream>>>(qb, kb, cand);
    k_rescore128<<<NTOT, 64, 0, stream>>>(qn, kn, vn, cand, enext);
  }

  // ---- layer aggregation + normalize -> d_out ----
  k_final_norm<<<N_USERS + N_ITEMS, D, 0, stream>>>(emb0, emb1, emb2, la_w, la_b, out);
  // ---- passthrough outputs ----
  k_copy<<<(N_ITEMS * D + 255) / 256, 256, 0, stream>>>(item_w, out + (size_t)(N_USERS + N_ITEMS) * D, N_ITEMS * D);
  k_copy<<<(N_ITEMS * D + 255) / 256, 256, 0, stream>>>(mm_item, out + (size_t)(N_USERS + 2 * N_ITEMS) * D, N_ITEMS * D);
}

// Round 13
// 1202.532 us; speedup vs baseline: 2.9241x; 1.0787x over previous
//
#include <hip/hip_runtime.h>
#include <hip/hip_bf16.h>
#include <math.h>

#define N_USERS 2500
#define N_ITEMS 3000
#define N_ENT   2500
#define NTOT    8000
#define D       128
#define NEDGE   256000
#define NSLICE  8

typedef unsigned short u16;
typedef unsigned int u32;
typedef unsigned long long u64;
typedef __attribute__((ext_vector_type(8))) short short8;
typedef __attribute__((ext_vector_type(4))) float f32x4;

static __device__ __forceinline__ u16 bf16bits(float x) {
  __hip_bfloat16 h = __float2bfloat16(x);
  return *reinterpret_cast<u16*>(&h);
}

// ---------------------------------------------------------------------------
// W pre-split: W[K][128] (f32, optional row scale ks[k]) -> three bf16 planes
// stored TRANSPOSED: wsg[p*128*K + j*K + k], p in {0,1,2}.
// ---------------------------------------------------------------------------
__global__ void k_wsplit(const float* __restrict__ W, const float* __restrict__ ks,
                         u16* __restrict__ wsg, int K) {
  const int e = blockIdx.x * 256 + threadIdx.x;
  if (e >= K * 128) return;
  const int k = e >> 7, j = e & 127;
  float x = W[(size_t)k * 128 + j];
  if (ks) x *= ks[k];
  const __hip_bfloat16 h1 = __float2bfloat16(x);
  const float r1 = x - __bfloat162float(h1);
  const __hip_bfloat16 h2 = __float2bfloat16(r1);
  const float r2 = r1 - __bfloat162float(h2);
  const __hip_bfloat16 h3 = __float2bfloat16(r2);
  const size_t base = (size_t)j * K + k;
  wsg[base]                   = *(const u16*)&h1;
  wsg[(size_t)128 * K + base] = *(const u16*)&h2;
  wsg[(size_t)256 * K + base] = *(const u16*)&h3;
}

// ---------------------------------------------------------------------------
// MFMA GEMM, f32-accurate via 3xbf16 splits (unchanged from r11 — verified)
// ---------------------------------------------------------------------------
__global__ __launch_bounds__(256) void k_gemm3(const float* __restrict__ A,
                                               const u16* __restrict__ wsg,
                                               const float* __restrict__ b,
                                               float* __restrict__ out,
                                               u16* __restrict__ ob,
                                               int M, int K, int mode) {
  const int tid  = threadIdx.x;
  const int lane = tid & 63;
  const int wave = tid >> 6;
  const int rbase = blockIdx.x * 64 + wave * 16;
  const int colL = lane & 15;
  const int kofs = (lane >> 4) * 8;

  f32x4 acc[8];
#pragma unroll
  for (int ct = 0; ct < 8; ++ct) acc[ct] = (f32x4){0.f, 0.f, 0.f, 0.f};

  const int arow = (rbase + colL < M) ? (rbase + colL) : (M - 1);
  const float* __restrict__ arp = A + (size_t)arow * K;

  for (int k0 = 0; k0 < K; k0 += 32) {
    const float4 f0 = *(const float4*)(arp + k0 + kofs);
    const float4 f1 = *(const float4*)(arp + k0 + kofs + 4);
    float av[8] = {f0.x, f0.y, f0.z, f0.w, f1.x, f1.y, f1.z, f1.w};
    short8 a1, a2, a3;
#pragma unroll
    for (int e = 0; e < 8; ++e) {
      const float x = av[e];
      const __hip_bfloat16 h1 = __float2bfloat16(x);
      const float r1 = x - __bfloat162float(h1);
      const __hip_bfloat16 h2 = __float2bfloat16(r1);
      const float r2 = r1 - __bfloat162float(h2);
      const __hip_bfloat16 h3 = __float2bfloat16(r2);
      a1[e] = *(const short*)&h1;
      a2[e] = *(const short*)&h2;
      a3[e] = *(const short*)&h3;
    }
#pragma unroll
    for (int ct = 0; ct < 8; ++ct) {
      const int j = ct * 16 + colL;
      const u16* wp = wsg + (size_t)j * K + k0 + kofs;
      const short8 b1 = *(const short8*)wp;
      const short8 b2 = *(const short8*)(wp + (size_t)128 * K);
      const short8 b3 = *(const short8*)(wp + (size_t)256 * K);
      acc[ct] = __builtin_amdgcn_mfma_f32_16x16x32_bf16(a1, b1, acc[ct], 0, 0, 0);
      acc[ct] = __builtin_amdgcn_mfma_f32_16x16x32_bf16(a1, b2, acc[ct], 0, 0, 0);
      acc[ct] = __builtin_amdgcn_mfma_f32_16x16x32_bf16(a2, b1, acc[ct], 0, 0, 0);
      acc[ct] = __builtin_amdgcn_mfma_f32_16x16x32_bf16(a2, b2, acc[ct], 0, 0, 0);
      acc[ct] = __builtin_amdgcn_mfma_f32_16x16x32_bf16(a1, b3, acc[ct], 0, 0, 0);
      acc[ct] = __builtin_amdgcn_mfma_f32_16x16x32_bf16(a3, b1, acc[ct], 0, 0, 0);
    }
  }

#pragma unroll
  for (int ct = 0; ct < 8; ++ct) {
    const int j = ct * 16 + colL;
    const float bj = b[j];
#pragma unroll
    for (int r = 0; r < 4; ++r) {
      const int row = rbase + (lane >> 4) * 4 + r;
      if (row < M) {
        float c = acc[ct][r] + bj;
        if (mode == 1) c = fmaxf(c, 0.f);
        else if (mode == 2) c *= 2.f;
        out[(size_t)row * 128 + j] = c;
        if (ob) ob[(size_t)row * 128 + j] = bf16bits(c);
      }
    }
  }
}

// ---------------------------------------------------------------------------
// Gated fusion (unchanged)
// ---------------------------------------------------------------------------
__global__ void k_gatefuse(const float* __restrict__ base, const float* __restrict__ mm,
                           const float* __restrict__ gw, const float* __restrict__ gb,
                           float* __restrict__ embout) {
  const int r = blockIdx.x;
  const int j = threadIdx.x;
  const float* __restrict__ b0 = base + (size_t)r * D;
  const float* __restrict__ m0 = mm + (size_t)r * D;
  float acc = 0.f;
  for (int k = 0; k < D; ++k) acc = fmaf(b0[k], gw[(size_t)k * D + j], acc);
  for (int k = 0; k < D; ++k) acc = fmaf(m0[k], gw[(size_t)(D + k) * D + j], acc);
  acc += gb[j];
  const float s1 = 1.f / (1.f + expf(-acc));
  const float g  = 1.f / (1.f + expf(-(s1 * 2.f)));
  const float bv = b0[j], mv = m0[j];
  embout[(size_t)r * D + j] = g * bv + (1.f - g) * mv + 0.1f * bv;
}

__global__ void k_relmean(const float* __restrict__ rel, float* __restrict__ out) {
  const int j = threadIdx.x;
  float s = 0.f;
  for (int i = 0; i < 32; ++i) s += rel[i * D + j];
  out[j] = s * (1.f / 32.f);
}

__global__ void k_copy(const float* __restrict__ src, float* __restrict__ dst, int n) {
  const int t = blockIdx.x * blockDim.x + threadIdx.x;
  if (t < n) dst[t] = src[t];
}

// ---------------------------------------------------------------------------
// CSR build (once per launch; adj is static across both GNN layers)
// ---------------------------------------------------------------------------
__global__ void k_hist(const int* __restrict__ rw, int* __restrict__ cnt) {
  const int e = blockIdx.x * 256 + threadIdx.x;
  if (e < NEDGE) atomicAdd(&cnt[rw[e]], 1);
}

// single block, 1024 threads; 8 bins/thread. Reads cnt (=cursor buf), writes
// exclusive-prefix rowptr[0..8000] and resets cursor[i]=rowptr[i].
__global__ __launch_bounds__(1024) void k_scan(int* __restrict__ cnt,
                                               int* __restrict__ rowptr,
                                               int* __restrict__ cursor) {
  __shared__ int part[1024];
  const int t = threadIdx.x;
  const int base = t * 8;
  int loc[8];
  int s = 0;
#pragma unroll
  for (int j = 0; j < 8; ++j) {
    const int v = (base + j < NTOT) ? cnt[base + j] : 0;
    loc[j] = s; s += v;
  }
  part[t] = s;
  __syncthreads();
  for (int off = 1; off < 1024; off <<= 1) {
    const int v = (t >= off) ? part[t - off] : 0;
    __syncthreads();
    part[t] += v;
    __syncthreads();
  }
  const int pre = (t == 0) ? 0 : part[t - 1];
#pragma unroll
  for (int j = 0; j < 8; ++j) {
    if (base + j < NTOT) {
      const int p = pre + loc[j];
      rowptr[base + j] = p;
      cursor[base + j] = p;
    }
  }
  if (t == 1023) rowptr[NTOT] = part[1023];
}

__global__ void k_scatter(const int* __restrict__ rw, int* __restrict__ cursor,
                          int* __restrict__ perm) {
  const int e = blockIdx.x * 256 + threadIdx.x;
  if (e >= NEDGE) return;
  const int pos = atomicAdd(&cursor[rw[e]], 1);
  perm[pos] = e;
}

// ---------------------------------------------------------------------------
// Atomic-free SpMM gather: one 128-thread block per row.
// side[r][d] = sum over edges of row r of dat[e]*emb[col[e]][d].
// perm/dat/col loads are wave-uniform (scalarized); emb row reads coalesced.
// ---------------------------------------------------------------------------
__global__ __launch_bounds__(128) void k_spmm_csr(const float* __restrict__ dat,
                                                  const int* __restrict__ cl,
                                                  const int* __restrict__ perm,
                                                  const int* __restrict__ rowptr,
                                                  const float* __restrict__ emb,
                                                  float* __restrict__ side) {
  const int r = blockIdx.x;
  const int d = threadIdx.x;
  const int beg = rowptr[r], end = rowptr[r + 1];
  float acc = 0.f;
  for (int i = beg; i < end; ++i) {
    const int ei = perm[i];
    acc = fmaf(dat[ei], emb[(size_t)cl[ei] * D + d], acc);
  }
  side[(size_t)r * D + d] = acc;
}

// ---------------------------------------------------------------------------
// bf16-MFMA score scan + shuffle-free top selection (r12 version, PROVEN)
// ---------------------------------------------------------------------------
__global__ __launch_bounds__(256) void k_topk6v(const u16* __restrict__ qb,
                                                const u16* __restrict__ kb,
                                                int* __restrict__ cand) {
  __shared__ u64 km[4][8][97];
  const int tid  = threadIdx.x;
  const int lane = tid & 63;
  const int wave = tid >> 6;
  const int rbase = blockIdx.x * 16;
  const int sl   = blockIdx.y * 4 + wave;
  const int colL = lane & 15;
  const int g    = lane >> 4;
  const int kofs = g * 8;

  short8 aF[4];
  {
    const u16* ap = qb + (size_t)(rbase + colL) * D + kofs;
#pragma unroll
    for (int t = 0; t < 4; ++t) aF[t] = *reinterpret_cast<const short8*>(ap + t * 32);
  }

  float s[4][6]; int c[4][6];
#pragma unroll
  for (int r = 0; r < 4; ++r)
#pragma unroll
    for (int j = 0; j < 6; ++j) { s[r][j] = -3.0e38f; c[r][j] = 0x40000000 + colL * 6 + j; }

  const int tile0  = sl * 62 + (sl < 4 ? sl : 4);
  const int ntiles = 62 + (sl < 4 ? 1 : 0);
  const u16* bb = kb + (size_t)(tile0 * 16 + colL) * D + kofs;

  short8 bF[4];
#pragma unroll
  for (int t = 0; t < 4; ++t) bF[t] = *reinterpret_cast<const short8*>(bb + t * 32);

  for (int ct = 0; ct < ntiles; ++ct) {
    const int cn = (ct + 1 < ntiles) ? ct + 1 : ct;
    const u16* nb = bb + (size_t)cn * 16 * D;
    short8 bN[4];
#pragma unroll
    for (int t = 0; t < 4; ++t) bN[t] = *reinterpret_cast<const short8*>(nb + t * 32);

    f32x4 acc = {0.f, 0.f, 0.f, 0.f};
#pragma unroll
    for (int t = 0; t < 4; ++t)
      acc = __builtin_amdgcn_mfma_f32_16x16x32_bf16(aF[t], bF[t], acc, 0, 0, 0);

    const int colIdx = (tile0 + ct) * 16 + colL;
#pragma unroll
    for (int r = 0; r < 4; ++r) {
      float ks = acc[r]; int kc = colIdx;
      if (ks > s[r][5]) {
#pragma unroll
        for (int i = 0; i < 6; ++i) {
          const bool bgt = ks > s[r][i];
          const float os = s[r][i]; const int oc = c[r][i];
          s[r][i] = bgt ? ks : os;  c[r][i] = bgt ? kc : oc;
          ks      = bgt ? os : ks;  kc      = bgt ? oc : kc;
        }
      }
    }

#pragma unroll
    for (int t = 0; t < 4; ++t) bF[t] = bN[t];
  }

  u64 kk[4][6];
#pragma unroll
  for (int r = 0; r < 4; ++r)
#pragma unroll
    for (int j = 0; j < 6; ++j) {
      const u32 b = __builtin_bit_cast(u32, s[r][j]);
      const u32 mono = b ^ ((u32)(((int)b) >> 31) | 0x80000000u);
      kk[r][j] = ((u64)mono << 32) | (u64)(0xFFFFFFFFu - (u32)c[r][j]);
    }

  if (g < 2) {
#pragma unroll
    for (int r = 0; r < 4; ++r)
#pragma unroll
      for (int j = 0; j < 6; ++j)
        km[wave][4 * g + r][colL * 6 + j] = kk[r][j];
  }
  __syncthreads();
  if (g < 2) {
#pragma unroll
    for (int r = 0; r < 4; ++r) {
      int cnt[6] = {0, 0, 0, 0, 0, 0};
      for (int q2 = 0; q2 < 96; ++q2) {
        const u64 o = km[wave][4 * g + r][q2];
#pragma unroll
        for (int j = 0; j < 6; ++j) cnt[j] += (o > kk[r][j]) ? 1 : 0;
      }
      const int row = rbase + 4 * g + r;
#pragma unroll
      for (int j = 0; j < 6; ++j)
        if (cnt[j] < 16)
          cand[(size_t)row * 128 + sl * 16 + cnt[j]] = c[r][j];
    }
  }
  __syncthreads();
  if (g >= 2) {
#pragma unroll
    for (int r = 0; r < 4; ++r)
#pragma unroll
      for (int j = 0; j < 6; ++j)
        km[wave][4 * (g - 2) + r][colL * 6 + j] = kk[r][j];
  }
  __syncthreads();
  if (g >= 2) {
#pragma unroll
    for (int r = 0; r < 4; ++r) {
      int cnt[6] = {0, 0, 0, 0, 0, 0};
      for (int q2 = 0; q2 < 96; ++q2) {
        const u64 o = km[wave][4 * (g - 2) + r][q2];
#pragma unroll
        for (int j = 0; j < 6; ++j) cnt[j] += (o > kk[r][j]) ? 1 : 0;
      }
      const int row = rbase + 4 * g + r;
#pragma unroll
      for (int j = 0; j < 6; ++j)
        if (cnt[j] < 16)
          cand[(size_t)row * 128 + sl * 16 + cnt[j]] = c[r][j];
    }
  }
}

// ---------------------------------------------------------------------------
// Exact f32 rescore of 128 candidates (unchanged)
// ---------------------------------------------------------------------------
__global__ __launch_bounds__(64) void k_rescore128(const float* __restrict__ qn,
                                                   const float* __restrict__ kn,
                                                   const float* __restrict__ vn,
                                                   const int* __restrict__ cand,
                                                   float* __restrict__ enext) {
  const int row = blockIdx.x;
  const int lane = threadIdx.x;
  const int* cr = cand + (size_t)row * 128;
  const int c0 = cr[lane];
  const int c1 = cr[64 + lane];

  const float4* __restrict__ q4  = (const float4*)(qn + (size_t)row * D);
  const float4* __restrict__ k40 = (const float4*)(kn + (size_t)c0 * D);
  const float4* __restrict__ k41 = (const float4*)(kn + (size_t)c1 * D);
  float s0 = 0.f, s1 = 0.f;
#pragma unroll 8
  for (int j = 0; j < 32; ++j) {
    const float4 qv = q4[j];
    const float4 a = k40[j], b = k41[j];
    s0 = fmaf(qv.x, a.x, s0); s0 = fmaf(qv.y, a.y, s0);
    s0 = fmaf(qv.z, a.z, s0); s0 = fmaf(qv.w, a.w, s0);
    s1 = fmaf(qv.x, b.x, s1); s1 = fmaf(qv.y, b.y, s1);
    s1 = fmaf(qv.z, b.z, s1); s1 = fmaf(qv.w, b.w, s1);
  }
  const float inv = 0.088388347648318447f;   // 1/sqrt(128)
  s0 *= inv; s1 *= inv;

  int r0 = 0, r1 = 0;
  for (int j = 0; j < 64; ++j) {
    const float t0 = __shfl(s0, j), t1 = __shfl(s1, j);
    const int   u0 = __shfl(c0, j), u1 = __shfl(c1, j);
    r0 += (t0 > s0 || (t0 == s0 && u0 < c0)) ? 1 : 0;
    r0 += (t1 > s0 || (t1 == s0 && u1 < c0)) ? 1 : 0;
    r1 += (t0 > s1 || (t0 == s1 && u0 < c1)) ? 1 : 0;
    r1 += (t1 > s1 || (t1 == s1 && u1 < c1)) ? 1 : 0;
  }
  const bool sel0 = r0 < 16, sel1 = r1 < 16;

  float v = fmaxf(sel0 ? s0 : -3.0e38f, sel1 ? s1 : -3.0e38f);
#pragma unroll
  for (int d2 = 1; d2 < 64; d2 <<= 1) v = fmaxf(v, __shfl_xor(v, d2));
  const float e0 = sel0 ? expf(s0 - v) : 0.f;
  const float e1 = sel1 ? expf(s1 - v) : 0.f;
  float Z = e0 + e1;
#pragma unroll
  for (int d2 = 1; d2 < 64; d2 <<= 1) Z += __shfl_xor(Z, d2);
  const float w0 = e0 / Z, w1 = e1 / Z;

  float a0 = 0.f, a1 = 0.f;
  unsigned long long b0 = __ballot(sel0);
  while (b0) {
    const int src = __ffsll(b0) - 1; b0 &= b0 - 1;
    const float wj = __shfl(w0, src);
    const int   cj = __shfl(c0, src);
    const float* __restrict__ vr = vn + (size_t)cj * D;
    a0 = fmaf(wj, vr[lane], a0);
    a1 = fmaf(wj, vr[64 + lane], a1);
  }
  unsigned long long b1 = __ballot(sel1);
  while (b1) {
    const int src = __ffsll(b1) - 1; b1 &= b1 - 1;
    const float wj = __shfl(w1, src);
    const int   cj = __shfl(c1, src);
    const float* __restrict__ vr = vn + (size_t)cj * D;
    a0 = fmaf(wj, vr[lane], a0);
    a1 = fmaf(wj, vr[64 + lane], a1);
  }
  enext[(size_t)row * D + lane]      = fmaxf(a0, 0.f);
  enext[(size_t)row * D + 64 + lane] = fmaxf(a1, 0.f);
}

// ---------------------------------------------------------------------------
// final = [e0|e1|e2] @ la_w + la_b, row-L2-normalized (unchanged)
// ---------------------------------------------------------------------------
__global__ void k_final_norm(const float* __restrict__ e0, const float* __restrict__ e1,
                             const float* __restrict__ e2, const float* __restrict__ law,
                             const float* __restrict__ lab, float* __restrict__ out) {
  __shared__ float red[128];
  const int r = blockIdx.x;
  const int j = threadIdx.x;
  const float* __restrict__ a0 = e0 + (size_t)r * D;
  const float* __restrict__ a1 = e1 + (size_t)r * D;
  const float* __restrict__ a2 = e2 + (size_t)r * D;
  float acc = lab[j];
  for (int k = 0; k < D; ++k) acc = fmaf(a0[k], law[(size_t)k * D + j], acc);
  for (int k = 0; k < D; ++k) acc = fmaf(a1[k], law[(size_t)(D + k) * D + j], acc);
  for (int k = 0; k < D; ++k) acc = fmaf(a2[k], law[(size_t)(2 * D + k) * D + j], acc);
  red[j] = acc * acc;
  __syncthreads();
  for (int st = 64; st > 0; st >>= 1) {
    if (j < st) red[j] += red[j + st];
    __syncthreads();
  }
  const float nrm = fmaxf(sqrtf(red[0]), 1e-12f);
  const float o = acc / nrm;
  if (r < N_USERS) out[(size_t)r * D + j] = o;
  else             out[(size_t)N_USERS * D + (size_t)(r - N_USERS) * D + j] = o;
}

// ---------------------------------------------------------------------------
extern "C" void kernel_launch(void* const* d_in, const int* in_sizes, int n_in,
                              void* d_out, int out_size, void* d_ws, size_t ws_size,
                              hipStream_t stream) {
  const float* user_w = (const float*)d_in[0];
  const float* item_w = (const float*)d_in[1];
  const float* ent_w  = (const float*)d_in[2];
  const float* rel_w  = (const float*)d_in[3];
  const float* mfeat  = (const float*)d_in[4];
  const float* ufeat  = (const float*)d_in[5];
  const float* me_w1  = (const float*)d_in[6];
  const float* me_b1  = (const float*)d_in[7];
  const float* me_w2  = (const float*)d_in[8];
  const float* me_b2  = (const float*)d_in[9];
  const float* ue_w1  = (const float*)d_in[10];
  const float* ue_b1  = (const float*)d_in[11];
  const float* ue_w2  = (const float*)d_in[12];
  const float* ue_b2  = (const float*)d_in[13];
  const float* cm_vw  = (const float*)d_in[18];
  const float* cm_vb  = (const float*)d_in[19];
  const float* cm_ow  = (const float*)d_in[20];
  const float* cm_ob  = (const float*)d_in[21];
  const float* mg_w   = (const float*)d_in[22];
  const float* mg_b   = (const float*)d_in[23];
  const float* ug_w   = (const float*)d_in[24];
  const float* ug_b   = (const float*)d_in[25];
  const float* gnn_qw = (const float*)d_in[26];
  const float* gnn_qb = (const float*)d_in[27];
  const float* gnn_kw = (const float*)d_in[28];
  const float* gnn_kb = (const float*)d_in[29];
  const float* gnn_vw = (const float*)d_in[30];
  const float* gnn_vb = (const float*)d_in[31];
  const float* la_w   = (const float*)d_in[32];
  const float* la_b   = (const float*)d_in[33];
  const float* adj_d  = (const float*)d_in[34];
  const int*   adj_r  = (const int*)d_in[35];
  const int*   adj_c  = (const int*)d_in[36];
  float* out = (float*)d_out;
  float* ws  = (float*)d_ws;

  // ---- workspace layout (floats) ----
  size_t off = 0;
  float* mm_item = ws + off; off += (size_t)N_ITEMS * D;
  float* mm_user = ws + off; off += (size_t)N_USERS * D;
  float* enc     = ws + off; off += (size_t)N_ITEMS * D;
  float* tmp     = ws + off; off += (size_t)N_ITEMS * D;
  float* emb0    = ws + off; off += (size_t)NTOT * D;
  float* emb1    = ws + off; off += (size_t)NTOT * D;
  float* emb2    = ws + off; off += (size_t)NTOT * D;
  float* side    = ws + off; off += (size_t)NTOT * D;
  float* qn      = ws + off; off += (size_t)NTOT * D;
  float* kn      = ws + off; off += (size_t)NTOT * D;
  float* vn      = ws + off; off += (size_t)NTOT * D;
  float* relmean = ws + off; off += D;
  // W split triplet scratch (max K=768)
  u16* wsg = (u16*)(ws + off); off += 147456;
  // bf16 mirrors overlay mm_user/enc/tmp (dead after the fusion stage)
  u16* qb = (u16*)mm_user;
  u16* kb = qb + (size_t)NTOT * D;
  // candidate indices overlay `side` (dead after kn/vn are computed)
  int* cand = (int*)side;
  // CSR overlays emb2 (emb2 is first written by layer-1's rescore, which runs
  // AFTER the last CSR use). rowptr[8001] | cursor[8000] | perm[256000].
  int* rowptr = (int*)emb2;
  int* cursor = rowptr + 8064;
  int* permB  = cursor + 8064;

  // ---- modality encoders (MFMA 3xbf16 GEMMs) ----
  k_wsplit<<<(768 * 128 + 255) / 256, 256, 0, stream>>>(me_w1, nullptr, wsg, 768);
  k_gemm3<<<(3000 + 63) / 64, 256, 0, stream>>>(mfeat, wsg, me_b1, tmp, nullptr, 3000, 768, 1);
  k_wsplit<<<(128 * 128 + 255) / 256, 256, 0, stream>>>(me_w2, nullptr, wsg, 128);
  k_gemm3<<<(3000 + 63) / 64, 256, 0, stream>>>(tmp, wsg, me_b2, enc, nullptr, 3000, 128, 1);
  k_wsplit<<<(512 * 128 + 255) / 256, 256, 0, stream>>>(ue_w1, nullptr, wsg, 512);
  k_gemm3<<<(2500 + 63) / 64, 256, 0, stream>>>(ufeat, wsg, ue_b1, tmp, nullptr, 2500, 512, 1);
  k_wsplit<<<(128 * 128 + 255) / 256, 256, 0, stream>>>(ue_w2, nullptr, wsg, 128);
  k_gemm3<<<(2500 + 63) / 64, 256, 0, stream>>>(tmp, wsg, ue_b2, mm_user, nullptr, 2500, 128, 1);
  // ---- collapsed cross-modal attention: mm_item = 2*((enc@vw+vb)@ow+ob) ----
  k_wsplit<<<(128 * 128 + 255) / 256, 256, 0, stream>>>(cm_vw, nullptr, wsg, 128);
  k_gemm3<<<(3000 + 63) / 64, 256, 0, stream>>>(enc, wsg, cm_vb, tmp, nullptr, 3000, 128, 0);
  k_wsplit<<<(128 * 128 + 255) / 256, 256, 0, stream>>>(cm_ow, nullptr, wsg, 128);
  k_gemm3<<<(3000 + 63) / 64, 256, 0, stream>>>(tmp, wsg, cm_ob, mm_item, nullptr, 3000, 128, 2);
  // ---- gated fusion -> emb0 ----
  k_gatefuse<<<N_ITEMS, D, 0, stream>>>(item_w, mm_item, mg_w, mg_b, emb0 + (size_t)N_USERS * D);
  k_gatefuse<<<N_USERS, D, 0, stream>>>(user_w, mm_user, ug_w, ug_b, emb0);
  k_copy<<<(N_ENT * D + 255) / 256, 256, 0, stream>>>(ent_w, emb0 + (size_t)(N_USERS + N_ITEMS) * D, N_ENT * D);
  k_relmean<<<1, D, 0, stream>>>(rel_w, relmean);

  // ---- CSR build (once; adj static across layers) ----
  hipMemsetAsync(cursor, 0, NTOT * sizeof(int), stream);
  k_hist<<<(NEDGE + 255) / 256, 256, 0, stream>>>(adj_r, cursor);
  k_scan<<<1, 1024, 0, stream>>>(cursor, rowptr, cursor);
  k_scatter<<<(NEDGE + 255) / 256, 256, 0, stream>>>(adj_r, cursor, permB);

  // ---- GNN layers ----
  const float* eml[3] = {emb0, emb1, emb2};
  for (int l = 0; l < 2; ++l) {
    const float* e = eml[l];
    float* enext   = (float*)eml[l + 1];
    k_spmm_csr<<<NTOT, 128, 0, stream>>>(adj_d, adj_c, permB, rowptr, e, side);
    k_wsplit<<<(128 * 128 + 255) / 256, 256, 0, stream>>>(gnn_qw + (size_t)l * D * D, nullptr, wsg, 128);
    k_gemm3<<<(NTOT + 63) / 64, 256, 0, stream>>>(e, wsg, gnn_qb + (size_t)l * D, qn, qb, NTOT, 128, 0);
    k_wsplit<<<(128 * 128 + 255) / 256, 256, 0, stream>>>(gnn_kw + (size_t)l * D * D, relmean, wsg, 128);
    k_gemm3<<<(NTOT + 63) / 64, 256, 0, stream>>>(side, wsg, gnn_kb + (size_t)l * D, kn, kb, NTOT, 128, 0);
    k_wsplit<<<(128 * 128 + 255) / 256, 256, 0, stream>>>(gnn_vw + (size_t)l * D * D, nullptr, wsg, 128);
    k_gemm3<<<(NTOT + 63) / 64, 256, 0, stream>>>(side, wsg, gnn_vb + (size_t)l * D, vn, nullptr, NTOT, 128, 0);
    // side is now dead -> reuse as candidate store
    dim3 tkgrid(NTOT / 16, 2);
    k_topk6v<<<tkgrid, 256, 0, stream>>>(qb, kb, cand);
    k_rescore128<<<NTOT, 64, 0, stream>>>(qn, kn, vn, cand, enext);
  }

  // ---- layer aggregation + normalize -> d_out ----
  k_final_norm<<<N_USERS + N_ITEMS, D, 0, stream>>>(emb0, emb1, emb2, la_w, la_b, out);
  // ---- passthrough outputs ----
  k_copy<<<(N_ITEMS * D + 255) / 256, 256, 0, stream>>>(item_w, out + (size_t)(N_USERS + N_ITEMS) * D, N_ITEMS * D);
  k_copy<<<(N_ITEMS * D + 255) / 256, 256, 0, stream>>>(mm_item, out + (size_t)(N_USERS + 2 * N_ITEMS) * D, N_ITEMS * D);
}

// Round 14
// 1143.236 us; speedup vs baseline: 3.0758x; 1.0519x over previous
//
#include <hip/hip_runtime.h>
#include <hip/hip_bf16.h>
#include <math.h>

#define N_USERS 2500
#define N_ITEMS 3000
#define N_ENT   2500
#define NTOT    8000
#define D       128
#define NEDGE   256000
#define NSLICE  8
#define NMAT    12

typedef unsigned short u16;
typedef unsigned int u32;
typedef unsigned long long u64;
typedef __attribute__((ext_vector_type(8))) short short8;
typedef __attribute__((ext_vector_type(4))) float f32x4;

static __device__ __forceinline__ u16 bf16bits(float x) {
  __hip_bfloat16 h = __float2bfloat16(x);
  return *reinterpret_cast<u16*>(&h);
}

// ---------------------------------------------------------------------------
// One-shot W pre-split of all 12 weight matrices into a u16 arena.
// Per matrix i: arena[ofs_i + p*128*K_i + j*K_i + k], p in {0,1,2} (3-way
// exact bf16 split, transposed). useks -> multiply row k by relmean[k].
// ---------------------------------------------------------------------------
struct WsplitArgs {
  const float* w[NMAT];
  int useks[NMAT];
  int K[NMAT];
  int cum[NMAT + 1];   // prefix sums of K_i*128 (elements)
  int ofs[NMAT];       // arena offsets (u16 elements)
};

__global__ void k_wsplit_all(WsplitArgs a, const float* __restrict__ relmean,
                             u16* __restrict__ arena) {
  const int e = blockIdx.x * 256 + threadIdx.x;
  if (e >= a.cum[NMAT]) return;
  int i = 0;
  while (e >= a.cum[i + 1]) ++i;
  const int local = e - a.cum[i];
  const int k = local >> 7, j = local & 127;
  const int K = a.K[i];
  float x = a.w[i][(size_t)k * 128 + j];
  if (a.useks[i]) x *= relmean[k];
  const __hip_bfloat16 h1 = __float2bfloat16(x);
  const float r1 = x - __bfloat162float(h1);
  const __hip_bfloat16 h2 = __float2bfloat16(r1);
  const float r2 = r1 - __bfloat162float(h2);
  const __hip_bfloat16 h3 = __float2bfloat16(r2);
  u16* __restrict__ base = arena + a.ofs[i] + (size_t)j * K + k;
  base[0]                 = *(const u16*)&h1;
  base[(size_t)128 * K]   = *(const u16*)&h2;
  base[(size_t)256 * K * 1 + (size_t)0] = base[(size_t)256 * K]; // keep addr form simple
  base[(size_t)256 * K]   = *(const u16*)&h3;
}

// ---------------------------------------------------------------------------
// MFMA GEMM, f32-accurate via 3xbf16 splits (byte-identical to r13 gemm3)
// ---------------------------------------------------------------------------
__global__ __launch_bounds__(256) void k_gemm3(const float* __restrict__ A,
                                               const u16* __restrict__ wsg,
                                               const float* __restrict__ b,
                                               float* __restrict__ out,
                                               u16* __restrict__ ob,
                                               int M, int K, int mode) {
  const int tid  = threadIdx.x;
  const int lane = tid & 63;
  const int wave = tid >> 6;
  const int rbase = blockIdx.x * 64 + wave * 16;
  const int colL = lane & 15;
  const int kofs = (lane >> 4) * 8;

  f32x4 acc[8];
#pragma unroll
  for (int ct = 0; ct < 8; ++ct) acc[ct] = (f32x4){0.f, 0.f, 0.f, 0.f};

  const int arow = (rbase + colL < M) ? (rbase + colL) : (M - 1);
  const float* __restrict__ arp = A + (size_t)arow * K;

  for (int k0 = 0; k0 < K; k0 += 32) {
    const float4 f0 = *(const float4*)(arp + k0 + kofs);
    const float4 f1 = *(const float4*)(arp + k0 + kofs + 4);
    float av[8] = {f0.x, f0.y, f0.z, f0.w, f1.x, f1.y, f1.z, f1.w};
    short8 a1, a2, a3;
#pragma unroll
    for (int e = 0; e < 8; ++e) {
      const float x = av[e];
      const __hip_bfloat16 h1 = __float2bfloat16(x);
      const float r1 = x - __bfloat162float(h1);
      const __hip_bfloat16 h2 = __float2bfloat16(r1);
      const float r2 = r1 - __bfloat162float(h2);
      const __hip_bfloat16 h3 = __float2bfloat16(r2);
      a1[e] = *(const short*)&h1;
      a2[e] = *(const short*)&h2;
      a3[e] = *(const short*)&h3;
    }
#pragma unroll
    for (int ct = 0; ct < 8; ++ct) {
      const int j = ct * 16 + colL;
      const u16* wp = wsg + (size_t)j * K + k0 + kofs;
      const short8 b1 = *(const short8*)wp;
      const short8 b2 = *(const short8*)(wp + (size_t)128 * K);
      const short8 b3 = *(const short8*)(wp + (size_t)256 * K);
      acc[ct] = __builtin_amdgcn_mfma_f32_16x16x32_bf16(a1, b1, acc[ct], 0, 0, 0);
      acc[ct] = __builtin_amdgcn_mfma_f32_16x16x32_bf16(a1, b2, acc[ct], 0, 0, 0);
      acc[ct] = __builtin_amdgcn_mfma_f32_16x16x32_bf16(a2, b1, acc[ct], 0, 0, 0);
      acc[ct] = __builtin_amdgcn_mfma_f32_16x16x32_bf16(a2, b2, acc[ct], 0, 0, 0);
      acc[ct] = __builtin_amdgcn_mfma_f32_16x16x32_bf16(a1, b3, acc[ct], 0, 0, 0);
      acc[ct] = __builtin_amdgcn_mfma_f32_16x16x32_bf16(a3, b1, acc[ct], 0, 0, 0);
    }
  }

#pragma unroll
  for (int ct = 0; ct < 8; ++ct) {
    const int j = ct * 16 + colL;
    const float bj = b[j];
#pragma unroll
    for (int r = 0; r < 4; ++r) {
      const int row = rbase + (lane >> 4) * 4 + r;
      if (row < M) {
        float c = acc[ct][r] + bj;
        if (mode == 1) c = fmaxf(c, 0.f);
        else if (mode == 2) c *= 2.f;
        out[(size_t)row * 128 + j] = c;
        if (ob) ob[(size_t)row * 128 + j] = bf16bits(c);
      }
    }
  }
}

// ---------------------------------------------------------------------------
// Dual-B MFMA GEMM: two outputs sharing the same A (kn+vn). A split done once.
// outA gets bf16 mirror obA; outB has none. K=128 fixed caller-side semantics.
// ---------------------------------------------------------------------------
__global__ __launch_bounds__(256) void k_gemm3x2(const float* __restrict__ A,
                                                 const u16* __restrict__ wsgA,
                                                 const float* __restrict__ bA,
                                                 float* __restrict__ outA,
                                                 u16* __restrict__ obA,
                                                 const u16* __restrict__ wsgB,
                                                 const float* __restrict__ bB,
                                                 float* __restrict__ outB,
                                                 int M, int K) {
  const int tid  = threadIdx.x;
  const int lane = tid & 63;
  const int wave = tid >> 6;
  const int rbase = blockIdx.x * 64 + wave * 16;
  const int colL = lane & 15;
  const int kofs = (lane >> 4) * 8;

  f32x4 accA[8], accB[8];
#pragma unroll
  for (int ct = 0; ct < 8; ++ct) {
    accA[ct] = (f32x4){0.f, 0.f, 0.f, 0.f};
    accB[ct] = (f32x4){0.f, 0.f, 0.f, 0.f};
  }

  const int arow = (rbase + colL < M) ? (rbase + colL) : (M - 1);
  const float* __restrict__ arp = A + (size_t)arow * K;

  for (int k0 = 0; k0 < K; k0 += 32) {
    const float4 f0 = *(const float4*)(arp + k0 + kofs);
    const float4 f1 = *(const float4*)(arp + k0 + kofs + 4);
    float av[8] = {f0.x, f0.y, f0.z, f0.w, f1.x, f1.y, f1.z, f1.w};
    short8 a1, a2, a3;
#pragma unroll
    for (int e = 0; e < 8; ++e) {
      const float x = av[e];
      const __hip_bfloat16 h1 = __float2bfloat16(x);
      const float r1 = x - __bfloat162float(h1);
      const __hip_bfloat16 h2 = __float2bfloat16(r1);
      const float r2 = r1 - __bfloat162float(h2);
      const __hip_bfloat16 h3 = __float2bfloat16(r2);
      a1[e] = *(const short*)&h1;
      a2[e] = *(const short*)&h2;
      a3[e] = *(const short*)&h3;
    }
#pragma unroll
    for (int ct = 0; ct < 8; ++ct) {
      const int j = ct * 16 + colL;
      {
        const u16* wp = wsgA + (size_t)j * K + k0 + kofs;
        const short8 b1 = *(const short8*)wp;
        const short8 b2 = *(const short8*)(wp + (size_t)128 * K);
        const short8 b3 = *(const short8*)(wp + (size_t)256 * K);
        accA[ct] = __builtin_amdgcn_mfma_f32_16x16x32_bf16(a1, b1, accA[ct], 0, 0, 0);
        accA[ct] = __builtin_amdgcn_mfma_f32_16x16x32_bf16(a1, b2, accA[ct], 0, 0, 0);
        accA[ct] = __builtin_amdgcn_mfma_f32_16x16x32_bf16(a2, b1, accA[ct], 0, 0, 0);
        accA[ct] = __builtin_amdgcn_mfma_f32_16x16x32_bf16(a2, b2, accA[ct], 0, 0, 0);
        accA[ct] = __builtin_amdgcn_mfma_f32_16x16x32_bf16(a1, b3, accA[ct], 0, 0, 0);
        accA[ct] = __builtin_amdgcn_mfma_f32_16x16x32_bf16(a3, b1, accA[ct], 0, 0, 0);
      }
      {
        const u16* wp = wsgB + (size_t)j * K + k0 + kofs;
        const short8 b1 = *(const short8*)wp;
        const short8 b2 = *(const short8*)(wp + (size_t)128 * K);
        const short8 b3 = *(const short8*)(wp + (size_t)256 * K);
        accB[ct] = __builtin_amdgcn_mfma_f32_16x16x32_bf16(a1, b1, accB[ct], 0, 0, 0);
        accB[ct] = __builtin_amdgcn_mfma_f32_16x16x32_bf16(a1, b2, accB[ct], 0, 0, 0);
        accB[ct] = __builtin_amdgcn_mfma_f32_16x16x32_bf16(a2, b1, accB[ct], 0, 0, 0);
        accB[ct] = __builtin_amdgcn_mfma_f32_16x16x32_bf16(a2, b2, accB[ct], 0, 0, 0);
        accB[ct] = __builtin_amdgcn_mfma_f32_16x16x32_bf16(a1, b3, accB[ct], 0, 0, 0);
        accB[ct] = __builtin_amdgcn_mfma_f32_16x16x32_bf16(a3, b1, accB[ct], 0, 0, 0);
      }
    }
  }

#pragma unroll
  for (int ct = 0; ct < 8; ++ct) {
    const int j = ct * 16 + colL;
    const float bjA = bA[j];
    const float bjB = bB[j];
#pragma unroll
    for (int r = 0; r < 4; ++r) {
      const int row = rbase + (lane >> 4) * 4 + r;
      if (row < M) {
        const float cA = accA[ct][r] + bjA;
        outA[(size_t)row * 128 + j] = cA;
        obA[(size_t)row * 128 + j] = bf16bits(cA);
        outB[(size_t)row * 128 + j] = accB[ct][r] + bjB;
      }
    }
  }
}

// ---------------------------------------------------------------------------
// Gated fusion (unchanged)
// ---------------------------------------------------------------------------
__global__ void k_gatefuse(const float* __restrict__ base, const float* __restrict__ mm,
                           const float* __restrict__ gw, const float* __restrict__ gb,
                           float* __restrict__ embout) {
  const int r = blockIdx.x;
  const int j = threadIdx.x;
  const float* __restrict__ b0 = base + (size_t)r * D;
  const float* __restrict__ m0 = mm + (size_t)r * D;
  float acc = 0.f;
  for (int k = 0; k < D; ++k) acc = fmaf(b0[k], gw[(size_t)k * D + j], acc);
  for (int k = 0; k < D; ++k) acc = fmaf(m0[k], gw[(size_t)(D + k) * D + j], acc);
  acc += gb[j];
  const float s1 = 1.f / (1.f + expf(-acc));
  const float g  = 1.f / (1.f + expf(-(s1 * 2.f)));
  const float bv = b0[j], mv = m0[j];
  embout[(size_t)r * D + j] = g * bv + (1.f - g) * mv + 0.1f * bv;
}

__global__ void k_relmean(const float* __restrict__ rel, float* __restrict__ out) {
  const int j = threadIdx.x;
  float s = 0.f;
  for (int i = 0; i < 32; ++i) s += rel[i * D + j];
  out[j] = s * (1.f / 32.f);
}

// ent_w -> emb0 tail, item_w -> out seg, mm_item -> out seg (one launch)
__global__ void k_copy3(const float* __restrict__ ent, const float* __restrict__ item,
                        const float* __restrict__ mm, float* __restrict__ emb0ent,
                        float* __restrict__ outItem, float* __restrict__ outMM) {
  const int t = blockIdx.x * 256 + threadIdx.x;
  const int nEnt = N_ENT * D;        // 320000
  const int nIt  = N_ITEMS * D;      // 384000
  if (t < nEnt) emb0ent[t] = ent[t];
  if (t < nIt) {
    outItem[t] = item[t];
    outMM[t]   = mm[t];
  }
}

// ---------------------------------------------------------------------------
// CSR build (unchanged from r13)
// ---------------------------------------------------------------------------
__global__ void k_hist(const int* __restrict__ rw, int* __restrict__ cnt) {
  const int e = blockIdx.x * 256 + threadIdx.x;
  if (e < NEDGE) atomicAdd(&cnt[rw[e]], 1);
}

__global__ __launch_bounds__(1024) void k_scan(int* __restrict__ cnt,
                                               int* __restrict__ rowptr,
                                               int* __restrict__ cursor) {
  __shared__ int part[1024];
  const int t = threadIdx.x;
  const int base = t * 8;
  int loc[8];
  int s = 0;
#pragma unroll
  for (int j = 0; j < 8; ++j) {
    const int v = (base + j < NTOT) ? cnt[base + j] : 0;
    loc[j] = s; s += v;
  }
  part[t] = s;
  __syncthreads();
  for (int off = 1; off < 1024; off <<= 1) {
    const int v = (t >= off) ? part[t - off] : 0;
    __syncthreads();
    part[t] += v;
    __syncthreads();
  }
  const int pre = (t == 0) ? 0 : part[t - 1];
#pragma unroll
  for (int j = 0; j < 8; ++j) {
    if (base + j < NTOT) {
      const int p = pre + loc[j];
      rowptr[base + j] = p;
      cursor[base + j] = p;
    }
  }
  if (t == 1023) rowptr[NTOT] = part[1023];
}

__global__ void k_scatter(const int* __restrict__ rw, int* __restrict__ cursor,
                          int* __restrict__ perm) {
  const int e = blockIdx.x * 256 + threadIdx.x;
  if (e >= NEDGE) return;
  const int pos = atomicAdd(&cursor[rw[e]], 1);
  perm[pos] = e;
}

__global__ __launch_bounds__(128) void k_spmm_csr(const float* __restrict__ dat,
                                                  const int* __restrict__ cl,
                                                  const int* __restrict__ perm,
                                                  const int* __restrict__ rowptr,
                                                  const float* __restrict__ emb,
                                                  float* __restrict__ side) {
  const int r = blockIdx.x;
  const int d = threadIdx.x;
  const int beg = rowptr[r], end = rowptr[r + 1];
  float acc = 0.f;
  for (int i = beg; i < end; ++i) {
    const int ei = perm[i];
    acc = fmaf(dat[ei], emb[(size_t)cl[ei] * D + d], acc);
  }
  side[(size_t)r * D + d] = acc;
}

// ---------------------------------------------------------------------------
// bf16-MFMA score scan + shuffle-free top selection (r12 version, PROVEN)
// ---------------------------------------------------------------------------
__global__ __launch_bounds__(256) void k_topk6v(const u16* __restrict__ qb,
                                                const u16* __restrict__ kb,
                                                int* __restrict__ cand) {
  __shared__ u64 km[4][8][97];
  const int tid  = threadIdx.x;
  const int lane = tid & 63;
  const int wave = tid >> 6;
  const int rbase = blockIdx.x * 16;
  const int sl   = blockIdx.y * 4 + wave;
  const int colL = lane & 15;
  const int g    = lane >> 4;
  const int kofs = g * 8;

  short8 aF[4];
  {
    const u16* ap = qb + (size_t)(rbase + colL) * D + kofs;
#pragma unroll
    for (int t = 0; t < 4; ++t) aF[t] = *reinterpret_cast<const short8*>(ap + t * 32);
  }

  float s[4][6]; int c[4][6];
#pragma unroll
  for (int r = 0; r < 4; ++r)
#pragma unroll
    for (int j = 0; j < 6; ++j) { s[r][j] = -3.0e38f; c[r][j] = 0x40000000 + colL * 6 + j; }

  const int tile0  = sl * 62 + (sl < 4 ? sl : 4);
  const int ntiles = 62 + (sl < 4 ? 1 : 0);
  const u16* bb = kb + (size_t)(tile0 * 16 + colL) * D + kofs;

  short8 bF[4];
#pragma unroll
  for (int t = 0; t < 4; ++t) bF[t] = *reinterpret_cast<const short8*>(bb + t * 32);

  for (int ct = 0; ct < ntiles; ++ct) {
    const int cn = (ct + 1 < ntiles) ? ct + 1 : ct;
    const u16* nb = bb + (size_t)cn * 16 * D;
    short8 bN[4];
#pragma unroll
    for (int t = 0; t < 4; ++t) bN[t] = *reinterpret_cast<const short8*>(nb + t * 32);

    f32x4 acc = {0.f, 0.f, 0.f, 0.f};
#pragma unroll
    for (int t = 0; t < 4; ++t)
      acc = __builtin_amdgcn_mfma_f32_16x16x32_bf16(aF[t], bF[t], acc, 0, 0, 0);

    const int colIdx = (tile0 + ct) * 16 + colL;
#pragma unroll
    for (int r = 0; r < 4; ++r) {
      float ks = acc[r]; int kc = colIdx;
      if (ks > s[r][5]) {
#pragma unroll
        for (int i = 0; i < 6; ++i) {
          const bool bgt = ks > s[r][i];
          const float os = s[r][i]; const int oc = c[r][i];
          s[r][i] = bgt ? ks : os;  c[r][i] = bgt ? kc : oc;
          ks      = bgt ? os : ks;  kc      = bgt ? oc : kc;
        }
      }
    }

#pragma unroll
    for (int t = 0; t < 4; ++t) bF[t] = bN[t];
  }

  u64 kk[4][6];
#pragma unroll
  for (int r = 0; r < 4; ++r)
#pragma unroll
    for (int j = 0; j < 6; ++j) {
      const u32 b = __builtin_bit_cast(u32, s[r][j]);
      const u32 mono = b ^ ((u32)(((int)b) >> 31) | 0x80000000u);
      kk[r][j] = ((u64)mono << 32) | (u64)(0xFFFFFFFFu - (u32)c[r][j]);
    }

  if (g < 2) {
#pragma unroll
    for (int r = 0; r < 4; ++r)
#pragma unroll
      for (int j = 0; j < 6; ++j)
        km[wave][4 * g + r][colL * 6 + j] = kk[r][j];
  }
  __syncthreads();
  if (g < 2) {
#pragma unroll
    for (int r = 0; r < 4; ++r) {
      int cnt[6] = {0, 0, 0, 0, 0, 0};
      for (int q2 = 0; q2 < 96; ++q2) {
        const u64 o = km[wave][4 * g + r][q2];
#pragma unroll
        for (int j = 0; j < 6; ++j) cnt[j] += (o > kk[r][j]) ? 1 : 0;
      }
      const int row = rbase + 4 * g + r;
#pragma unroll
      for (int j = 0; j < 6; ++j)
        if (cnt[j] < 16)
          cand[(size_t)row * 128 + sl * 16 + cnt[j]] = c[r][j];
    }
  }
  __syncthreads();
  if (g >= 2) {
#pragma unroll
    for (int r = 0; r < 4; ++r)
#pragma unroll
      for (int j = 0; j < 6; ++j)
        km[wave][4 * (g - 2) + r][colL * 6 + j] = kk[r][j];
  }
  __syncthreads();
  if (g >= 2) {
#pragma unroll
    for (int r = 0; r < 4; ++r) {
      int cnt[6] = {0, 0, 0, 0, 0, 0};
      for (int q2 = 0; q2 < 96; ++q2) {
        const u64 o = km[wave][4 * (g - 2) + r][q2];
#pragma unroll
        for (int j = 0; j < 6; ++j) cnt[j] += (o > kk[r][j]) ? 1 : 0;
      }
      const int row = rbase + 4 * g + r;
#pragma unroll
      for (int j = 0; j < 6; ++j)
        if (cnt[j] < 16)
          cand[(size_t)row * 128 + sl * 16 + cnt[j]] = c[r][j];
    }
  }
}

// ---------------------------------------------------------------------------
// Exact f32 rescore of 128 candidates (unchanged)
// ---------------------------------------------------------------------------
__global__ __launch_bounds__(64) void k_rescore128(const float* __restrict__ qn,
                                                   const float* __restrict__ kn,
                                                   const float* __restrict__ vn,
                                                   const int* __restrict__ cand,
                                                   float* __restrict__ enext) {
  const int row = blockIdx.x;
  const int lane = threadIdx.x;
  const int* cr = cand + (size_t)row * 128;
  const int c0 = cr[lane];
  const int c1 = cr[64 + lane];

  const float4* __restrict__ q4  = (const float4*)(qn + (size_t)row * D);
  const float4* __restrict__ k40 = (const float4*)(kn + (size_t)c0 * D);
  const float4* __restrict__ k41 = (const float4*)(kn + (size_t)c1 * D);
  float s0 = 0.f, s1 = 0.f;
#pragma unroll 8
  for (int j = 0; j < 32; ++j) {
    const float4 qv = q4[j];
    const float4 a = k40[j], b = k41[j];
    s0 = fmaf(qv.x, a.x, s0); s0 = fmaf(qv.y, a.y, s0);
    s0 = fmaf(qv.z, a.z, s0); s0 = fmaf(qv.w, a.w, s0);
    s1 = fmaf(qv.x, b.x, s1); s1 = fmaf(qv.y, b.y, s1);
    s1 = fmaf(qv.z, b.z, s1); s1 = fmaf(qv.w, b.w, s1);
  }
  const float inv = 0.088388347648318447f;   // 1/sqrt(128)
  s0 *= inv; s1 *= inv;

  int r0 = 0, r1 = 0;
  for (int j = 0; j < 64; ++j) {
    const float t0 = __shfl(s0, j), t1 = __shfl(s1, j);
    const int   u0 = __shfl(c0, j), u1 = __shfl(c1, j);
    r0 += (t0 > s0 || (t0 == s0 && u0 < c0)) ? 1 : 0;
    r0 += (t1 > s0 || (t1 == s0 && u1 < c0)) ? 1 : 0;
    r1 += (t0 > s1 || (t0 == s1 && u0 < c1)) ? 1 : 0;
    r1 += (t1 > s1 || (t1 == s1 && u1 < c1)) ? 1 : 0;
  }
  const bool sel0 = r0 < 16, sel1 = r1 < 16;

  float v = fmaxf(sel0 ? s0 : -3.0e38f, sel1 ? s1 : -3.0e38f);
#pragma unroll
  for (int d2 = 1; d2 < 64; d2 <<= 1) v = fmaxf(v, __shfl_xor(v, d2));
  const float e0 = sel0 ? expf(s0 - v) : 0.f;
  const float e1 = sel1 ? expf(s1 - v) : 0.f;
  float Z = e0 + e1;
#pragma unroll
  for (int d2 = 1; d2 < 64; d2 <<= 1) Z += __shfl_xor(Z, d2);
  const float w0 = e0 / Z, w1 = e1 / Z;

  float a0 = 0.f, a1 = 0.f;
  unsigned long long b0 = __ballot(sel0);
  while (b0) {
    const int src = __ffsll(b0) - 1; b0 &= b0 - 1;
    const float wj = __shfl(w0, src);
    const int   cj = __shfl(c0, src);
    const float* __restrict__ vr = vn + (size_t)cj * D;
    a0 = fmaf(wj, vr[lane], a0);
    a1 = fmaf(wj, vr[64 + lane], a1);
  }
  unsigned long long b1 = __ballot(sel1);
  while (b1) {
    const int src = __ffsll(b1) - 1; b1 &= b1 - 1;
    const float wj = __shfl(w1, src);
    const int   cj = __shfl(c1, src);
    const float* __restrict__ vr = vn + (size_t)cj * D;
    a0 = fmaf(wj, vr[lane], a0);
    a1 = fmaf(wj, vr[64 + lane], a1);
  }
  enext[(size_t)row * D + lane]      = fmaxf(a0, 0.f);
  enext[(size_t)row * D + 64 + lane] = fmaxf(a1, 0.f);
}

// ---------------------------------------------------------------------------
// final = [e0|e1|e2] @ la_w + la_b, row-L2-normalized (unchanged)
// ---------------------------------------------------------------------------
__global__ void k_final_norm(const float* __restrict__ e0, const float* __restrict__ e1,
                             const float* __restrict__ e2, const float* __restrict__ law,
                             const float* __restrict__ lab, float* __restrict__ out) {
  __shared__ float red[128];
  const int r = blockIdx.x;
  const int j = threadIdx.x;
  const float* __restrict__ a0 = e0 + (size_t)r * D;
  const float* __restrict__ a1 = e1 + (size_t)r * D;
  const float* __restrict__ a2 = e2 + (size_t)r * D;
  float acc = lab[j];
  for (int k = 0; k < D; ++k) acc = fmaf(a0[k], law[(size_t)k * D + j], acc);
  for (int k = 0; k < D; ++k) acc = fmaf(a1[k], law[(size_t)(D + k) * D + j], acc);
  for (int k = 0; k < D; ++k) acc = fmaf(a2[k], law[(size_t)(2 * D + k) * D + j], acc);
  red[j] = acc * acc;
  __syncthreads();
  for (int st = 64; st > 0; st >>= 1) {
    if (j < st) red[j] += red[j + st];
    __syncthreads();
  }
  const float nrm = fmaxf(sqrtf(red[0]), 1e-12f);
  const float o = acc / nrm;
  if (r < N_USERS) out[(size_t)r * D + j] = o;
  else             out[(size_t)N_USERS * D + (size_t)(r - N_USERS) * D + j] = o;
}

// ---------------------------------------------------------------------------
extern "C" void kernel_launch(void* const* d_in, const int* in_sizes, int n_in,
                              void* d_out, int out_size, void* d_ws, size_t ws_size,
                              hipStream_t stream) {
  const float* user_w = (const float*)d_in[0];
  const float* item_w = (const float*)d_in[1];
  const float* ent_w  = (const float*)d_in[2];
  const float* rel_w  = (const float*)d_in[3];
  const float* mfeat  = (const float*)d_in[4];
  const float* ufeat  = (const float*)d_in[5];
  const float* me_w1  = (const float*)d_in[6];
  const float* me_b1  = (const float*)d_in[7];
  const float* me_w2  = (const float*)d_in[8];
  const float* me_b2  = (const float*)d_in[9];
  const float* ue_w1  = (const float*)d_in[10];
  const float* ue_b1  = (const float*)d_in[11];
  const float* ue_w2  = (const float*)d_in[12];
  const float* ue_b2  = (const float*)d_in[13];
  const float* cm_vw  = (const float*)d_in[18];
  const float* cm_vb  = (const float*)d_in[19];
  const float* cm_ow  = (const float*)d_in[20];
  const float* cm_ob  = (const float*)d_in[21];
  const float* mg_w   = (const float*)d_in[22];
  const float* mg_b   = (const float*)d_in[23];
  const float* ug_w   = (const float*)d_in[24];
  const float* ug_b   = (const float*)d_in[25];
  const float* gnn_qw = (const float*)d_in[26];
  const float* gnn_qb = (const float*)d_in[27];
  const float* gnn_kw = (const float*)d_in[28];
  const float* gnn_kb = (const float*)d_in[29];
  const float* gnn_vw = (const float*)d_in[30];
  const float* gnn_vb = (const float*)d_in[31];
  const float* la_w   = (const float*)d_in[32];
  const float* la_b   = (const float*)d_in[33];
  const float* adj_d  = (const float*)d_in[34];
  const int*   adj_r  = (const int*)d_in[35];
  const int*   adj_c  = (const int*)d_in[36];
  float* out = (float*)d_out;
  float* ws  = (float*)d_ws;

  // ---- workspace layout (floats) ----
  size_t off = 0;
  float* mm_item = ws + off; off += (size_t)N_ITEMS * D;
  float* mm_user = ws + off; off += (size_t)N_USERS * D;
  float* enc     = ws + off; off += (size_t)N_ITEMS * D;
  float* tmp     = ws + off; off += (size_t)N_ITEMS * D;
  float* emb0    = ws + off; off += (size_t)NTOT * D;
  float* emb1    = ws + off; off += (size_t)NTOT * D;
  float* emb2    = ws + off; off += (size_t)NTOT * D;
  float* side    = ws + off; off += (size_t)NTOT * D;
  float* qn      = ws + off; off += (size_t)NTOT * D;
  float* kn      = ws + off; off += (size_t)NTOT * D;
  float* vn      = ws + off; off += (size_t)NTOT * D;
  float* relmean = ws + off; off += D;
  // W-split arena: 12 matrices, 2560*128*3 u16 = 983040 u16 = 491520 f32
  u16* arena = (u16*)(ws + off); off += 491520;
  // bf16 mirrors overlay mm_user/enc/tmp (dead after the fusion stage)
  u16* qb = (u16*)mm_user;
  u16* kb = qb + (size_t)NTOT * D;
  // candidate indices overlay `side` (dead after kn/vn are computed)
  int* cand = (int*)side;
  // CSR overlays emb2 (dead until layer-1's rescore writes it)
  int* rowptr = (int*)emb2;
  int* cursor = rowptr + 8064;
  int* permB  = cursor + 8064;

  // ---- arena offsets (u16 elems) / K per matrix ----
  // order: me_w1, me_w2, ue_w1, ue_w2, cm_vw, cm_ow, qw0, kw0, vw0, qw1, kw1, vw1
  static const int Ks[NMAT]  = {768, 128, 512, 128, 128, 128, 128, 128, 128, 128, 128, 128};
  int ofs[NMAT], cum[NMAT + 1];
  {
    int o = 0, cc = 0;
    for (int i = 0; i < NMAT; ++i) {
      ofs[i] = o; o += 3 * Ks[i] * 128;
      cum[i] = cc; cc += Ks[i] * 128;
    }
    cum[NMAT] = cc;   // 327680
  }

  WsplitArgs wa;
  const float* wptr[NMAT] = {me_w1, me_w2, ue_w1, ue_w2, cm_vw, cm_ow,
                             gnn_qw, gnn_kw, gnn_vw,
                             gnn_qw + (size_t)D * D, gnn_kw + (size_t)D * D,
                             gnn_vw + (size_t)D * D};
  for (int i = 0; i < NMAT; ++i) {
    wa.w[i] = wptr[i];
    wa.useks[i] = (i == 7 || i == 10) ? 1 : 0;   // kw0, kw1 get relmean
    wa.K[i] = Ks[i];
    wa.cum[i] = cum[i];
    wa.ofs[i] = ofs[i];
  }
  wa.cum[NMAT] = cum[NMAT];

  // ---- relmean, then one-shot weight split ----
  k_relmean<<<1, D, 0, stream>>>(rel_w, relmean);
  k_wsplit_all<<<(cum[NMAT] + 255) / 256, 256, 0, stream>>>(wa, relmean, arena);

  // ---- modality encoders (MFMA 3xbf16 GEMMs) ----
  k_gemm3<<<(3000 + 63) / 64, 256, 0, stream>>>(mfeat, arena + ofs[0], me_b1, tmp, nullptr, 3000, 768, 1);
  k_gemm3<<<(3000 + 63) / 64, 256, 0, stream>>>(tmp, arena + ofs[1], me_b2, enc, nullptr, 3000, 128, 1);
  k_gemm3<<<(2500 + 63) / 64, 256, 0, stream>>>(ufeat, arena + ofs[2], ue_b1, tmp, nullptr, 2500, 512, 1);
  k_gemm3<<<(2500 + 63) / 64, 256, 0, stream>>>(tmp, arena + ofs[3], ue_b2, mm_user, nullptr, 2500, 128, 1);
  // ---- collapsed cross-modal attention: mm_item = 2*((enc@vw+vb)@ow+ob) ----
  k_gemm3<<<(3000 + 63) / 64, 256, 0, stream>>>(enc, arena + ofs[4], cm_vb, tmp, nullptr, 3000, 128, 0);
  k_gemm3<<<(3000 + 63) / 64, 256, 0, stream>>>(tmp, arena + ofs[5], cm_ob, mm_item, nullptr, 3000, 128, 2);
  // ---- gated fusion -> emb0; ent copy + passthroughs in one launch ----
  k_gatefuse<<<N_ITEMS, D, 0, stream>>>(item_w, mm_item, mg_w, mg_b, emb0 + (size_t)N_USERS * D);
  k_gatefuse<<<N_USERS, D, 0, stream>>>(user_w, mm_user, ug_w, ug_b, emb0);
  k_copy3<<<(N_ITEMS * D + 255) / 256, 256, 0, stream>>>(
      ent_w, item_w, mm_item,
      emb0 + (size_t)(N_USERS + N_ITEMS) * D,
      out + (size_t)(N_USERS + N_ITEMS) * D,
      out + (size_t)(N_USERS + 2 * N_ITEMS) * D);

  // ---- CSR build (once; adj static across layers) ----
  hipMemsetAsync(cursor, 0, NTOT * sizeof(int), stream);
  k_hist<<<(NEDGE + 255) / 256, 256, 0, stream>>>(adj_r, cursor);
  k_scan<<<1, 1024, 0, stream>>>(cursor, rowptr, cursor);
  k_scatter<<<(NEDGE + 255) / 256, 256, 0, stream>>>(adj_r, cursor, permB);

  // ---- GNN layers ----
  const float* eml[3] = {emb0, emb1, emb2};
  for (int l = 0; l < 2; ++l) {
    const float* e = eml[l];
    float* enext   = (float*)eml[l + 1];
    k_spmm_csr<<<NTOT, 128, 0, stream>>>(adj_d, adj_c, permB, rowptr, e, side);
    k_gemm3<<<(NTOT + 63) / 64, 256, 0, stream>>>(e, arena + ofs[6 + 3 * l],
                                                  gnn_qb + (size_t)l * D, qn, qb, NTOT, 128, 0);
    k_gemm3x2<<<(NTOT + 63) / 64, 256, 0, stream>>>(side,
                                                    arena + ofs[7 + 3 * l], gnn_kb + (size_t)l * D, kn, kb,
                                                    arena + ofs[8 + 3 * l], gnn_vb + (size_t)l * D, vn,
                                                    NTOT, 128);
    dim3 tkgrid(NTOT / 16, 2);
    k_topk6v<<<tkgrid, 256, 0, stream>>>(qb, kb, cand);
    k_rescore128<<<NTOT, 64, 0, stream>>>(qn, kn, vn, cand, enext);
  }

  // ---- layer aggregation + normalize -> d_out ----
  k_final_norm<<<N_USERS + N_ITEMS, D, 0, stream>>>(emb0, emb1, emb2, la_w, la_b, out);
}